// Round 1
// baseline (8044.591 us; speedup 1.0000x reference)
//
#include <hip/hip_runtime.h>
#include <math.h>

// ---------------------------------------------------------------------------
// DHYPR hyperbolic GNN encoder, MI355X (gfx950).
// Strategy: features stored f32; ALL row-scalar math (norms, tanh, artanh,
// Mobius scalars) in f64; pre-rounding row norms passed via f64 aux arrays to
// avoid artanh amplification of f32 storage rounding near the ball boundary.
// ---------------------------------------------------------------------------

constexpr double kMaxNorm = 1.0 - 1e-5;   // (1-PROJ_EPS)/sqrt(c), c=1
constexpr double kMinNorm = 1e-15;

__device__ inline double wsum64(double v) {
#pragma unroll
  for (int o = 32; o > 0; o >>= 1) v += __shfl_xor(v, o, 64);
  return v;
}

__device__ inline double artanh_c(double x) {  // x >= 0
  x = fmin(x, 1.0 - 1e-7);
  return 0.5 * (log1p(x) - log1p(-x));
}

// ------------------------- weight transpose: Wt[b][k][d] = W[b][d][k] -------
__global__ __launch_bounds__(256) void k_transpose(const float* __restrict__ W,
                                                   float* __restrict__ Wt,
                                                   int DIN, int tot) {
  int idx = blockIdx.x * 256 + threadIdx.x;
  if (idx >= tot) return;
  int d = idx & 63;
  int t = idx >> 6;      // b*DIN + k
  int k = t % DIN;
  int b = t / DIN;
  Wt[idx] = W[((size_t)(b * 64 + d)) * DIN + k];
}

// ------------------------- hb = proj(expmap0(bias)) in f64 ------------------
__global__ __launch_bounds__(512) void k_bias(const float* __restrict__ b1,
                                              const float* __restrict__ b2,
                                              double* __restrict__ hb1,
                                              double* __restrict__ hb2,
                                              double* __restrict__ y21,
                                              double* __restrict__ y22) {
  int w = threadIdx.x >> 6, lane = threadIdx.x & 63;
  const float* bs = (w < 4) ? (b1 + w * 64) : (b2 + (w - 4) * 64);
  double v = (double)bs[lane];
  double un = fmax(sqrt(wsum64(v * v)), kMinNorm);
  double pn = tanh(un);
  double pf = pn > kMaxNorm ? kMaxNorm / pn : 1.0;
  double p = v * (pn / un) * pf;
  double* hb = (w < 4) ? hb1 + w * 64 : hb2 + (w - 4) * 64;
  hb[lane] = p;
  if (lane == 0) {
    double n = pn * pf;
    double* y2 = (w < 4) ? (y21 + w) : (y22 + (w - 4));
    *y2 = n * n;
  }
}

// ---- fused: [expmap0(x) if FIRST] -> mobius_matvec -> proj -> mobius_add(hb)
//      -> proj -> logmap0  ; one wave per row, lane = output dim -------------
template <int DIN, bool FIRST>
__global__ __launch_bounds__(256) void k_matvec(
    const float* __restrict__ X, const float* __restrict__ Wt,
    const double* __restrict__ hb, const double* __restrict__ hby2,
    const double* __restrict__ aux_in, float* __restrict__ out_ht, int nrows) {
  __shared__ float wt[DIN * 64];
  for (int i = threadIdx.x; i < DIN * 64; i += 256) wt[i] = Wt[i];
  __syncthreads();
  const int wave = threadIdx.x >> 6, lane = threadIdx.x & 63;
  const double hbd = hb[lane];
  const double y2 = hby2[0];
  const int ROWS = 16;
  int row0 = (blockIdx.x * 4 + wave) * ROWS;
  for (int r = 0; r < ROWS; ++r) {
    int row = row0 + r;
    if (row >= nrows) return;  // wave-uniform
    double s, sart;
    double dotd = 0.0;
    if constexpr (FIRST) {
      const float4 xr =
          *reinterpret_cast<const float4*>(X + (size_t)row * 256 + lane * 4);
      double ss = (double)xr.x * xr.x + (double)xr.y * xr.y +
                  (double)xr.z * xr.z + (double)xr.w * xr.w;
      ss = wsum64(ss);
      double un = fmax(sqrt(ss), kMinNorm);
      double pn = tanh(un);
      double pf = pn > kMaxNorm ? kMaxNorm / pn : 1.0;
      s = (pn / un) * pf;                    // expmap0+proj combined scale
      double xn = fmax(pn * pf, kMinNorm);   // |x_hyp| exactly (f64)
      sart = artanh_c(xn) / xn;
      float acc = 0.f;
#pragma unroll 8
      for (int k0 = 0; k0 < 64; ++k0) {
        float bx0 = __shfl(xr.x, k0, 64);
        float bx1 = __shfl(xr.y, k0, 64);
        float bx2 = __shfl(xr.z, k0, 64);
        float bx3 = __shfl(xr.w, k0, 64);
        int kb = k0 * 4;
        acc = fmaf(bx0, wt[(kb + 0) * 64 + lane], acc);
        acc = fmaf(bx1, wt[(kb + 1) * 64 + lane], acc);
        acc = fmaf(bx2, wt[(kb + 2) * 64 + lane], acc);
        acc = fmaf(bx3, wt[(kb + 3) * 64 + lane], acc);
        if ((k0 & 15) == 15) { dotd += (double)acc; acc = 0.f; }
      }
    } else {
      s = 1.0;
      double xn = aux_in[row];               // pre-rounding |h| (f64)
      sart = artanh_c(xn) / xn;
      const float xr = X[(size_t)row * 64 + lane];
      float acc = 0.f;
#pragma unroll 8
      for (int k0 = 0; k0 < 64; ++k0) {
        float bx = __shfl(xr, k0, 64);
        acc = fmaf(bx, wt[k0 * 64 + lane], acc);
        if ((k0 & 15) == 15) { dotd += (double)acc; acc = 0.f; }
      }
    }
    // mobius_matvec tail (all f64, lane holds one output dim)
    double mx = s * dotd;
    double mxn = fmax(sqrt(wsum64(mx * mx)), kMinNorm);
    double nmv = tanh(mxn * sart);           // = |mv| analytically
    double mv = (nmv / mxn) * mx;
    double pf1 = nmv > kMaxNorm ? kMaxNorm / nmv : 1.0;  // proj
    mv *= pf1;
    double x2 = (nmv * pf1) * (nmv * pf1);
    // mobius_add(mv, hb)
    double xy = wsum64(mv * hbd);
    double num = (1.0 + 2.0 * xy + y2) * mv + (1.0 - x2) * hbd;
    double den = fmax(1.0 + 2.0 * xy + x2 * y2, kMinNorm);
    double h = num / den;
    // proj + logmap0
    double hn = fmax(sqrt(wsum64(h * h)), kMinNorm);
    double pf2 = hn > kMaxNorm ? kMaxNorm / hn : 1.0;
    h *= pf2;
    hn = fmax(hn * pf2, kMinNorm);
    double ht = (artanh_c(hn) / hn) * h;
    out_ht[(size_t)row * 64 + lane] = (float)ht;
  }
}

// ------------------------- SpMM scatter: agg[dst] += v * ht[src] ------------
__global__ __launch_bounds__(256) void k_spmm(const float* __restrict__ ht,
                                              const float* __restrict__ vals,
                                              const int* __restrict__ src,
                                              const int* __restrict__ dst,
                                              float* __restrict__ agg, int E) {
  int idx = blockIdx.x * 256 + threadIdx.x;  // (edge, quarter-row)
  if (idx >= E * 16) return;
  int e = idx >> 4, q = idx & 15;
  int s = src[e], d = dst[e];
  float v = vals[e];
  const float4 f =
      *reinterpret_cast<const float4*>(ht + (size_t)s * 64 + q * 4);
  float* o = agg + (size_t)d * 64 + q * 4;
  atomicAdd(o + 0, v * f.x);
  atomicAdd(o + 1, v * f.y);
  atomicAdd(o + 2, v * f.z);
  atomicAdd(o + 3, v * f.w);
}

// ---- fused: proj(expmap0(agg)) -> relu(logmap0) -> proj(expmap0) ; f64 ----
__global__ __launch_bounds__(256) void k_postagg(const float* __restrict__ agg,
                                                 float* __restrict__ hout,
                                                 double* __restrict__ aux,
                                                 int nrows) {
  int wave = threadIdx.x >> 6, lane = threadIdx.x & 63;
  int row = blockIdx.x * 4 + wave;
  if (row >= nrows) return;
  double a = (double)agg[(size_t)row * 64 + lane];
  double an = fmax(sqrt(wsum64(a * a)), kMinNorm);
  double hn = tanh(an);
  double pf = hn > kMaxNorm ? kMaxNorm / hn : 1.0;
  double h = a * (hn / an) * pf;
  double hnn = fmax(hn * pf, kMinNorm);
  double t = (artanh_c(hnn) / hnn) * h;
  t = fmax(t, 0.0);                       // relu in tangent space
  double tn = fmax(sqrt(wsum64(t * t)), kMinNorm);
  double h2n = tanh(tn);
  double pf2 = h2n > kMaxNorm ? kMaxNorm / h2n : 1.0;
  double h2 = t * (h2n / tn) * pf2;
  hout[(size_t)row * 64 + lane] = (float)h2;
  if (lane == 0) aux[row] = fmax(h2n * pf2, kMinNorm);  // pre-rounding |h2|
}

// ---- combine: mulscaler(1/8) -> mobius_add chain -> mean(logmap0) -> out ---
__global__ __launch_bounds__(256) void k_combine(const float* __restrict__ F,
                                                 const double* __restrict__ auxF,
                                                 float* __restrict__ out,
                                                 int nrows, int N) {
  int wave = threadIdx.x >> 6, lane = threadIdx.x & 63;
  int row = blockIdx.x * 4 + wave;
  if (row >= nrows) return;
  double f[4], nb[4];
#pragma unroll
  for (int b = 0; b < 4; b++) {
    f[b] = (double)F[((size_t)b * N + row) * 64 + lane];
    nb[b] = auxF[(size_t)b * N + row];
  }
  double w[4], wn2[4];
#pragma unroll
  for (int b = 0; b < 4; b++) {
    double art = artanh_c(nb[b]);
    double wn = tanh(art * 0.125);          // |w| analytically
    w[b] = (wn / nb[b]) * f[b];
    wn2[b] = wn * wn;
  }
  double tgt = w[0], tx2 = wn2[0];
#pragma unroll
  for (int i = 1; i < 4; i++) {
    double xy = wsum64(tgt * w[i]);
    double num = (1.0 + 2.0 * xy + wn2[i]) * tgt + (1.0 - tx2) * w[i];
    double den = fmax(1.0 + 2.0 * xy + tx2 * wn2[i], kMinNorm);
    tgt = num / den;
    tx2 = wsum64(tgt * tgt);
  }
  double tn = fmax(sqrt(tx2), kMinNorm);
  double m = 0.0;
#pragma unroll
  for (int b = 0; b < 4; b++) m += (artanh_c(nb[b]) / nb[b]) * f[b];
  m += (artanh_c(tn) / tn) * tgt;
  m *= 0.2;                                 // mean over 5 representations
  double mn = fmax(sqrt(wsum64(m * m)), kMinNorm);
  double on = tanh(mn);
  double pf = on > kMaxNorm ? kMaxNorm / on : 1.0;
  out[(size_t)row * 64 + lane] = (float)(m * (on / mn) * pf);
}

// ---------------------------------------------------------------------------
extern "C" void kernel_launch(void* const* d_in, const int* in_sizes, int n_in,
                              void* d_out, int out_size, void* d_ws,
                              size_t ws_size, hipStream_t stream) {
  const int FIN = 256, NB = 4;
  const int N = in_sizes[0] / FIN;       // 50000
  const int E = in_sizes[5] / NB;        // 800000
  const float* x = (const float*)d_in[0];
  const float* W1 = (const float*)d_in[1];
  const float* b1 = (const float*)d_in[2];
  const float* W2 = (const float*)d_in[3];
  const float* b2 = (const float*)d_in[4];
  const float* vals = (const float*)d_in[5];
  const int* src = (const int*)d_in[6];
  const int* dst = (const int*)d_in[7];
  float* out = (float*)d_out;

  char* w = (char*)d_ws;
  auto alloc = [&](size_t bytes) -> char* {
    char* p = w;
    w += (bytes + 255) & ~size_t(255);
    return p;
  };
  float* Wt1 = (float*)alloc((size_t)NB * FIN * 64 * 4);
  float* Wt2 = (float*)alloc((size_t)NB * 64 * 64 * 4);
  double* hb1 = (double*)alloc(NB * 64 * 8);
  double* hb2 = (double*)alloc(NB * 64 * 8);
  double* y21 = (double*)alloc(NB * 8);
  double* y22 = (double*)alloc(NB * 8);
  double* auxT = (double*)alloc((size_t)N * 8);
  double* auxF = (double*)alloc((size_t)NB * N * 8);
  float* A = (float*)alloc((size_t)N * 64 * 4);
  float* B = (float*)alloc((size_t)N * 64 * 4);
  float* F = (float*)alloc((size_t)NB * N * 64 * 4);

  k_transpose<<<(NB * FIN * 64 + 255) / 256, 256, 0, stream>>>(
      W1, Wt1, FIN, NB * FIN * 64);
  k_transpose<<<(NB * 64 * 64 + 255) / 256, 256, 0, stream>>>(
      W2, Wt2, 64, NB * 64 * 64);
  k_bias<<<1, 512, 0, stream>>>(b1, b2, hb1, hb2, y21, y22);

  const int mvblocks = (N + 63) / 64;
  const int paBlocks = (N + 3) / 4;
  const int spBlocks = (E * 16 + 255) / 256;
  const size_t featB = (size_t)N * 64 * 4;

  for (int b = 0; b < NB; ++b) {
    k_matvec<256, true><<<mvblocks, 256, 0, stream>>>(
        x, Wt1 + (size_t)b * FIN * 64, hb1 + b * 64, y21 + b, nullptr, A, N);
    hipMemsetAsync(B, 0, featB, stream);
    k_spmm<<<spBlocks, 256, 0, stream>>>(A, vals + (size_t)b * E,
                                         src + (size_t)b * E,
                                         dst + (size_t)b * E, B, E);
    k_postagg<<<paBlocks, 256, 0, stream>>>(B, A, auxT, N);
    k_matvec<64, false><<<mvblocks, 256, 0, stream>>>(
        A, Wt2 + (size_t)b * 64 * 64, hb2 + b * 64, y22 + b, auxT, B, N);
    hipMemsetAsync(A, 0, featB, stream);
    k_spmm<<<spBlocks, 256, 0, stream>>>(B, vals + (size_t)b * E,
                                         src + (size_t)b * E,
                                         dst + (size_t)b * E, A, E);
    k_postagg<<<paBlocks, 256, 0, stream>>>(A, F + (size_t)b * N * 64,
                                            auxF + (size_t)b * N, N);
  }
  k_combine<<<paBlocks, 256, 0, stream>>>(F, auxF, out, N, N);
}

// Round 2
// 3163.744 us; speedup vs baseline: 2.5427x; 2.5427x over previous
//
#include <hip/hip_runtime.h>
#include <math.h>

// ---------------------------------------------------------------------------
// DHYPR hyperbolic GNN encoder, MI355X (gfx950).  Round 2: CSR gather SpMM
// (replaces 51M-atomic scatter) with fused post-aggregation epilogue.
// Row-scalar math (norms, tanh, artanh, Mobius scalars) stays in f64.
// ---------------------------------------------------------------------------

constexpr double kMaxNorm = 1.0 - 1e-5;   // (1-PROJ_EPS)/sqrt(c), c=1
constexpr double kMinNorm = 1e-15;

__device__ inline double wsum64(double v) {
#pragma unroll
  for (int o = 32; o > 0; o >>= 1) v += __shfl_xor(v, o, 64);
  return v;
}

__device__ inline double artanh_c(double x) {  // x >= 0
  x = fmin(x, 1.0 - 1e-7);
  return 0.5 * (log1p(x) - log1p(-x));
}

// ------------------------- weight transpose: Wt[b][k][d] = W[b][d][k] -------
__global__ __launch_bounds__(256) void k_transpose(const float* __restrict__ W,
                                                   float* __restrict__ Wt,
                                                   int DIN, int tot) {
  int idx = blockIdx.x * 256 + threadIdx.x;
  if (idx >= tot) return;
  int d = idx & 63;
  int t = idx >> 6;      // b*DIN + k
  int k = t % DIN;
  int b = t / DIN;
  Wt[idx] = W[((size_t)(b * 64 + d)) * DIN + k];
}

// ------------------------- hb = proj(expmap0(bias)) in f64 ------------------
__global__ __launch_bounds__(512) void k_bias(const float* __restrict__ b1,
                                              const float* __restrict__ b2,
                                              double* __restrict__ hb1,
                                              double* __restrict__ hb2,
                                              double* __restrict__ y21,
                                              double* __restrict__ y22) {
  int w = threadIdx.x >> 6, lane = threadIdx.x & 63;
  const float* bs = (w < 4) ? (b1 + w * 64) : (b2 + (w - 4) * 64);
  double v = (double)bs[lane];
  double un = fmax(sqrt(wsum64(v * v)), kMinNorm);
  double pn = tanh(un);
  double pf = pn > kMaxNorm ? kMaxNorm / pn : 1.0;
  double p = v * (pn / un) * pf;
  double* hb = (w < 4) ? hb1 + w * 64 : hb2 + (w - 4) * 64;
  hb[lane] = p;
  if (lane == 0) {
    double n = pn * pf;
    double* y2 = (w < 4) ? (y21 + w) : (y22 + (w - 4));
    *y2 = n * n;
  }
}

// ---- fused: [expmap0(x) if FIRST] -> mobius_matvec -> proj -> mobius_add(hb)
//      -> proj -> logmap0  ; one wave per row, lane = output dim -------------
template <int DIN, bool FIRST>
__global__ __launch_bounds__(256) void k_matvec(
    const float* __restrict__ X, const float* __restrict__ Wt,
    const double* __restrict__ hb, const double* __restrict__ hby2,
    const double* __restrict__ aux_in, float* __restrict__ out_ht, int nrows) {
  __shared__ float wt[DIN * 64];
  for (int i = threadIdx.x; i < DIN * 64; i += 256) wt[i] = Wt[i];
  __syncthreads();
  const int wave = threadIdx.x >> 6, lane = threadIdx.x & 63;
  const double hbd = hb[lane];
  const double y2 = hby2[0];
  const int ROWS = 16;
  int row0 = (blockIdx.x * 4 + wave) * ROWS;
  for (int r = 0; r < ROWS; ++r) {
    int row = row0 + r;
    if (row >= nrows) return;  // wave-uniform
    double s, sart;
    double dotd = 0.0;
    if constexpr (FIRST) {
      const float4 xr =
          *reinterpret_cast<const float4*>(X + (size_t)row * 256 + lane * 4);
      double ss = (double)xr.x * xr.x + (double)xr.y * xr.y +
                  (double)xr.z * xr.z + (double)xr.w * xr.w;
      ss = wsum64(ss);
      double un = fmax(sqrt(ss), kMinNorm);
      double pn = tanh(un);
      double pf = pn > kMaxNorm ? kMaxNorm / pn : 1.0;
      s = (pn / un) * pf;                    // expmap0+proj combined scale
      double xn = fmax(pn * pf, kMinNorm);   // |x_hyp| exactly (f64)
      sart = artanh_c(xn) / xn;
      float acc = 0.f;
#pragma unroll 8
      for (int k0 = 0; k0 < 64; ++k0) {
        float bx0 = __shfl(xr.x, k0, 64);
        float bx1 = __shfl(xr.y, k0, 64);
        float bx2 = __shfl(xr.z, k0, 64);
        float bx3 = __shfl(xr.w, k0, 64);
        int kb = k0 * 4;
        acc = fmaf(bx0, wt[(kb + 0) * 64 + lane], acc);
        acc = fmaf(bx1, wt[(kb + 1) * 64 + lane], acc);
        acc = fmaf(bx2, wt[(kb + 2) * 64 + lane], acc);
        acc = fmaf(bx3, wt[(kb + 3) * 64 + lane], acc);
        if ((k0 & 15) == 15) { dotd += (double)acc; acc = 0.f; }
      }
    } else {
      s = 1.0;
      double xn = aux_in[row];               // pre-rounding |h| (f64)
      sart = artanh_c(xn) / xn;
      const float xr = X[(size_t)row * 64 + lane];
      float acc = 0.f;
#pragma unroll 8
      for (int k0 = 0; k0 < 64; ++k0) {
        float bx = __shfl(xr, k0, 64);
        acc = fmaf(bx, wt[k0 * 64 + lane], acc);
        if ((k0 & 15) == 15) { dotd += (double)acc; acc = 0.f; }
      }
    }
    // mobius_matvec tail (all f64, lane holds one output dim)
    double mx = s * dotd;
    double mxn = fmax(sqrt(wsum64(mx * mx)), kMinNorm);
    double nmv = tanh(mxn * sart);           // = |mv| analytically
    double mv = (nmv / mxn) * mx;
    double pf1 = nmv > kMaxNorm ? kMaxNorm / nmv : 1.0;  // proj
    mv *= pf1;
    double x2 = (nmv * pf1) * (nmv * pf1);
    // mobius_add(mv, hb)
    double xy = wsum64(mv * hbd);
    double num = (1.0 + 2.0 * xy + y2) * mv + (1.0 - x2) * hbd;
    double den = fmax(1.0 + 2.0 * xy + x2 * y2, kMinNorm);
    double h = num / den;
    // proj + logmap0
    double hn = fmax(sqrt(wsum64(h * h)), kMinNorm);
    double pf2 = hn > kMaxNorm ? kMaxNorm / hn : 1.0;
    h *= pf2;
    hn = fmax(hn * pf2, kMinNorm);
    double ht = (artanh_c(hn) / hn) * h;
    out_ht[(size_t)row * 64 + lane] = (float)ht;
  }
}

// ------------------------- CSR build --------------------------------------
__global__ __launch_bounds__(256) void k_hist(const int* __restrict__ dst,
                                              int* __restrict__ cnt, int E) {
  int e = blockIdx.x * 256 + threadIdx.x;
  if (e < E) atomicAdd(&cnt[dst[e]], 1);
}

// exclusive scan over n ints, TILE=2048 per block (256 thr x 8 items)
__global__ __launch_bounds__(256) void k_scan1(const int* __restrict__ cnt,
                                               int* __restrict__ rp,
                                               int* __restrict__ bsum, int n) {
  __shared__ int wsums[4];
  int base = blockIdx.x * 2048;
  int t = threadIdx.x;
  int lane = t & 63, wv = t >> 6;
  int vals[8];
  int s = 0;
#pragma unroll
  for (int i = 0; i < 8; ++i) {
    int idx = base + t * 8 + i;
    int v = (idx < n) ? cnt[idx] : 0;
    vals[i] = s;        // local exclusive prefix
    s += v;
  }
  int incl = s;
#pragma unroll
  for (int o = 1; o < 64; o <<= 1) {
    int u = __shfl_up(incl, o, 64);
    if (lane >= o) incl += u;
  }
  if (lane == 63) wsums[wv] = incl;
  __syncthreads();
  int woff = 0;
  for (int i = 0; i < wv; ++i) woff += wsums[i];
  int texcl = woff + incl - s;  // exclusive prefix of this thread
#pragma unroll
  for (int i = 0; i < 8; ++i) {
    int idx = base + t * 8 + i;
    if (idx < n) rp[idx] = texcl + vals[i];
  }
  if (t == 255) bsum[blockIdx.x] = woff + incl;  // block total
}

__global__ __launch_bounds__(64) void k_scan2(int* __restrict__ bsum, int nb) {
  int t = threadIdx.x;
  int v = (t < nb) ? bsum[t] : 0;
  int incl = v;
#pragma unroll
  for (int o = 1; o < 64; o <<= 1) {
    int u = __shfl_up(incl, o, 64);
    if (t >= o) incl += u;
  }
  if (t < nb) bsum[t] = incl - v;  // exclusive
}

__global__ __launch_bounds__(256) void k_scan3(int* __restrict__ rp,
                                               const int* __restrict__ bsum,
                                               int* __restrict__ work, int n,
                                               int E) {
  int i = blockIdx.x * 256 + threadIdx.x;
  if (i >= n) return;
  int v = rp[i] + bsum[i >> 11];
  rp[i] = v;
  work[i] = v;
  if (i == 0) rp[n] = E;
}

__global__ __launch_bounds__(256) void k_scatter(const int* __restrict__ src,
                                                 const int* __restrict__ dst,
                                                 const float* __restrict__ val,
                                                 int* __restrict__ work,
                                                 int* __restrict__ psrc,
                                                 float* __restrict__ pval,
                                                 int E) {
  int e = blockIdx.x * 256 + threadIdx.x;
  if (e >= E) return;
  int d = dst[e];
  int pos = atomicAdd(&work[d], 1);
  psrc[pos] = src[e];
  pval[pos] = val[e];
}

// ---- fused gather SpMM + postagg: one wave per destination row ------------
// acc = sum_j v_j * ht[src_j]  (f64), then proj(expmap0) -> relu(logmap0)
// -> proj(expmap0), write hout + pre-rounding |h2| aux.
__global__ __launch_bounds__(256) void k_spmm_post(
    const float* __restrict__ ht, const int* __restrict__ rp,
    const int* __restrict__ psrc, const float* __restrict__ pval,
    float* __restrict__ hout, double* __restrict__ aux, int nrows) {
  int wave = threadIdx.x >> 6, lane = threadIdx.x & 63;
  int row = blockIdx.x * 4 + wave;
  if (row >= nrows) return;
  int beg = rp[row], end = rp[row + 1];
  double acc = 0.0;
  for (int j0 = beg; j0 < end; j0 += 64) {
    int nj = min(64, end - j0);
    int sj = 0;
    float vj = 0.f;
    if (lane < nj) {
      sj = psrc[j0 + lane];
      vj = pval[j0 + lane];
    }
#pragma unroll 4
    for (int k = 0; k < nj; ++k) {
      int s = __shfl(sj, k, 64);
      float v = __shfl(vj, k, 64);
      acc += (double)v * (double)ht[(size_t)s * 64 + lane];
    }
  }
  // postagg chain (f64)
  double an = fmax(sqrt(wsum64(acc * acc)), kMinNorm);
  double hn = tanh(an);
  double pf = hn > kMaxNorm ? kMaxNorm / hn : 1.0;
  double h = acc * (hn / an) * pf;
  double hnn = fmax(hn * pf, kMinNorm);
  double t = (artanh_c(hnn) / hnn) * h;
  t = fmax(t, 0.0);  // relu in tangent space
  double tn = fmax(sqrt(wsum64(t * t)), kMinNorm);
  double h2n = tanh(tn);
  double pf2 = h2n > kMaxNorm ? kMaxNorm / h2n : 1.0;
  double h2 = t * (h2n / tn) * pf2;
  hout[(size_t)row * 64 + lane] = (float)h2;
  if (lane == 0) aux[row] = fmax(h2n * pf2, kMinNorm);
}

// ---- combine: mulscaler(1/8) -> mobius_add chain -> mean(logmap0) -> out ---
__global__ __launch_bounds__(256) void k_combine(const float* __restrict__ F,
                                                 const double* __restrict__ auxF,
                                                 float* __restrict__ out,
                                                 int nrows, int N) {
  int wave = threadIdx.x >> 6, lane = threadIdx.x & 63;
  int row = blockIdx.x * 4 + wave;
  if (row >= nrows) return;
  double f[4], nb[4];
#pragma unroll
  for (int b = 0; b < 4; b++) {
    f[b] = (double)F[((size_t)b * N + row) * 64 + lane];
    nb[b] = auxF[(size_t)b * N + row];
  }
  double w[4], wn2[4];
#pragma unroll
  for (int b = 0; b < 4; b++) {
    double art = artanh_c(nb[b]);
    double wn = tanh(art * 0.125);          // |w| analytically
    w[b] = (wn / nb[b]) * f[b];
    wn2[b] = wn * wn;
  }
  double tgt = w[0], tx2 = wn2[0];
#pragma unroll
  for (int i = 1; i < 4; i++) {
    double xy = wsum64(tgt * w[i]);
    double num = (1.0 + 2.0 * xy + wn2[i]) * tgt + (1.0 - tx2) * w[i];
    double den = fmax(1.0 + 2.0 * xy + tx2 * wn2[i], kMinNorm);
    tgt = num / den;
    tx2 = wsum64(tgt * tgt);
  }
  double tn = fmax(sqrt(tx2), kMinNorm);
  double m = 0.0;
#pragma unroll
  for (int b = 0; b < 4; b++) m += (artanh_c(nb[b]) / nb[b]) * f[b];
  m += (artanh_c(tn) / tn) * tgt;
  m *= 0.2;                                 // mean over 5 representations
  double mn = fmax(sqrt(wsum64(m * m)), kMinNorm);
  double on = tanh(mn);
  double pf = on > kMaxNorm ? kMaxNorm / on : 1.0;
  out[(size_t)row * 64 + lane] = (float)(m * (on / mn) * pf);
}

// ---------------------------------------------------------------------------
extern "C" void kernel_launch(void* const* d_in, const int* in_sizes, int n_in,
                              void* d_out, int out_size, void* d_ws,
                              size_t ws_size, hipStream_t stream) {
  const int FIN = 256, NB = 4;
  const int N = in_sizes[0] / FIN;       // 50000
  const int E = in_sizes[5] / NB;        // 800000
  const float* x = (const float*)d_in[0];
  const float* W1 = (const float*)d_in[1];
  const float* b1 = (const float*)d_in[2];
  const float* W2 = (const float*)d_in[3];
  const float* b2 = (const float*)d_in[4];
  const float* vals = (const float*)d_in[5];
  const int* src = (const int*)d_in[6];
  const int* dst = (const int*)d_in[7];
  float* out = (float*)d_out;

  char* w = (char*)d_ws;
  auto alloc = [&](size_t bytes) -> char* {
    char* p = w;
    w += (bytes + 255) & ~size_t(255);
    return p;
  };
  float* Wt1 = (float*)alloc((size_t)NB * FIN * 64 * 4);
  float* Wt2 = (float*)alloc((size_t)NB * 64 * 64 * 4);
  double* hb1 = (double*)alloc(NB * 64 * 8);
  double* hb2 = (double*)alloc(NB * 64 * 8);
  double* y21 = (double*)alloc(NB * 8);
  double* y22 = (double*)alloc(NB * 8);
  double* auxT = (double*)alloc((size_t)N * 8);
  double* auxF = (double*)alloc((size_t)NB * N * 8);
  float* A = (float*)alloc((size_t)N * 64 * 4);
  float* B = (float*)alloc((size_t)N * 64 * 4);
  float* F = (float*)alloc((size_t)NB * N * 64 * 4);
  int* cnt = (int*)alloc((size_t)N * 4);
  int* rp = (int*)alloc(((size_t)N + 1) * 4);
  int* work = (int*)alloc((size_t)N * 4);
  int* bsum = (int*)alloc(64 * 4);
  int* psrc = (int*)alloc((size_t)E * 4);
  float* pval = (float*)alloc((size_t)E * 4);

  k_transpose<<<(NB * FIN * 64 + 255) / 256, 256, 0, stream>>>(
      W1, Wt1, FIN, NB * FIN * 64);
  k_transpose<<<(NB * 64 * 64 + 255) / 256, 256, 0, stream>>>(
      W2, Wt2, 64, NB * 64 * 64);
  k_bias<<<1, 512, 0, stream>>>(b1, b2, hb1, hb2, y21, y22);

  const int mvblocks = (N + 63) / 64;
  const int rowBlocks = (N + 3) / 4;
  const int eBlocks = (E + 255) / 256;
  const int scanBlocks = (N + 2047) / 2048;   // 25

  for (int b = 0; b < NB; ++b) {
    const int* sb = src + (size_t)b * E;
    const int* db = dst + (size_t)b * E;
    const float* vb = vals + (size_t)b * E;
    // ---- CSR build for this branch ----
    hipMemsetAsync(cnt, 0, (size_t)N * 4, stream);
    k_hist<<<eBlocks, 256, 0, stream>>>(db, cnt, E);
    k_scan1<<<scanBlocks, 256, 0, stream>>>(cnt, rp, bsum, N);
    k_scan2<<<1, 64, 0, stream>>>(bsum, scanBlocks);
    k_scan3<<<(N + 255) / 256, 256, 0, stream>>>(rp, bsum, work, N, E);
    k_scatter<<<eBlocks, 256, 0, stream>>>(sb, db, vb, work, psrc, pval, E);
    // ---- layer 1 ----
    k_matvec<256, true><<<mvblocks, 256, 0, stream>>>(
        x, Wt1 + (size_t)b * FIN * 64, hb1 + b * 64, y21 + b, nullptr, A, N);
    k_spmm_post<<<rowBlocks, 256, 0, stream>>>(A, rp, psrc, pval, B, auxT, N);
    // ---- layer 2 ----
    k_matvec<64, false><<<mvblocks, 256, 0, stream>>>(
        B, Wt2 + (size_t)b * 64 * 64, hb2 + b * 64, y22 + b, auxT, A, N);
    k_spmm_post<<<rowBlocks, 256, 0, stream>>>(A, rp, psrc, pval,
                                               F + (size_t)b * N * 64,
                                               auxF + (size_t)b * N, N);
  }
  k_combine<<<rowBlocks, 256, 0, stream>>>(F, auxF, out, N, N);
}

// Round 3
// 2017.849 us; speedup vs baseline: 3.9867x; 1.5679x over previous
//
#include <hip/hip_runtime.h>
#include <math.h>

// ---------------------------------------------------------------------------
// DHYPR hyperbolic GNN encoder, MI355X (gfx950).  Round 3: MFMA bf16-split
// GEMMs (hi/lo x hi/lo, 4 mfma per K-step) replace VALU shuffle matvecs.
// f64 Mobius tails split into high-occupancy wave-per-row kernels.
// ---------------------------------------------------------------------------

constexpr double kMaxNorm = 1.0 - 1e-5;   // (1-PROJ_EPS)/sqrt(c), c=1
constexpr double kMinNorm = 1e-15;

typedef __attribute__((ext_vector_type(8))) short short8v;   // 8 bf16
typedef __attribute__((ext_vector_type(4))) float f32x4;

__device__ inline double wsum64(double v) {
#pragma unroll
  for (int o = 32; o > 0; o >>= 1) v += __shfl_xor(v, o, 64);
  return v;
}

__device__ inline double artanh_c(double x) {  // x >= 0
  x = fmin(x, 1.0 - 1e-7);
  return 0.5 * (log1p(x) - log1p(-x));
}

__device__ inline unsigned short f2bf(float f) {  // RN-even f32->bf16
  union { float f; unsigned int u; } v{f};
  unsigned int r = v.u + 0x7fffu + ((v.u >> 16) & 1u);
  return (unsigned short)(r >> 16);
}
__device__ inline float bf2f(unsigned short h) {
  union { unsigned int u; float f; } v{(unsigned int)h << 16};
  return v.f;
}

// ------------------------- hb = proj(expmap0(bias)) in f64 ------------------
__global__ __launch_bounds__(512) void k_bias(const float* __restrict__ b1,
                                              const float* __restrict__ b2,
                                              double* __restrict__ hb1,
                                              double* __restrict__ hb2,
                                              double* __restrict__ y21,
                                              double* __restrict__ y22) {
  int w = threadIdx.x >> 6, lane = threadIdx.x & 63;
  const float* bs = (w < 4) ? (b1 + w * 64) : (b2 + (w - 4) * 64);
  double v = (double)bs[lane];
  double un = fmax(sqrt(wsum64(v * v)), kMinNorm);
  double pn = tanh(un);
  double pf = pn > kMaxNorm ? kMaxNorm / pn : 1.0;
  double p = v * (pn / un) * pf;
  double* hb = (w < 4) ? hb1 + w * 64 : hb2 + (w - 4) * 64;
  hb[lane] = p;
  if (lane == 0) {
    double n = pn * pf;
    double* y2 = (w < 4) ? (y21 + w) : (y22 + (w - 4));
    *y2 = n * n;
  }
}

// ---- weight prep: fragment-ready bf16 hi/lo tables -------------------------
// Wf[((b*KSTEPS + s)*4 + f)*64 + lane][j] = bf16(W[b][c][k]),
//   c = f*16 + (lane&15), k = s*32 + (lane>>4)*8 + j   (B-frag layout)
__global__ __launch_bounds__(256) void k_wprep(const float* __restrict__ W,
                                               unsigned short* __restrict__ Wfh,
                                               unsigned short* __restrict__ Wfl,
                                               int DIN, int tot) {
  int idx = blockIdx.x * 256 + threadIdx.x;
  if (idx >= tot) return;
  int lane = idx & 63;
  int t = idx >> 6;
  int f = t & 3; t >>= 2;
  int ks = DIN >> 5;
  int s = t % ks;
  int b = t / ks;
  int c = f * 16 + (lane & 15);
  int k = s * 32 + (lane >> 4) * 8;
  const float* wp = W + ((size_t)(b * 64 + c)) * DIN + k;
#pragma unroll
  for (int j = 0; j < 8; ++j) {
    float v = wp[j];
    unsigned short h = f2bf(v);
    unsigned short l = f2bf(v - bf2f(h));
    Wfh[(size_t)idx * 8 + j] = h;
    Wfl[(size_t)idx * 8 + j] = l;
  }
}

// ---- per-row expmap0(x) scale (branch-invariant, computed once) ------------
__global__ __launch_bounds__(256) void k_prescale(const float* __restrict__ x,
                                                  double* __restrict__ s_arr,
                                                  double* __restrict__ sart_arr,
                                                  int nrows) {
  int wave = threadIdx.x >> 6, lane = threadIdx.x & 63;
  int row = blockIdx.x * 4 + wave;
  if (row >= nrows) return;
  const float4 xr =
      *reinterpret_cast<const float4*>(x + (size_t)row * 256 + lane * 4);
  double ss = (double)xr.x * xr.x + (double)xr.y * xr.y +
              (double)xr.z * xr.z + (double)xr.w * xr.w;
  ss = wsum64(ss);
  double un = fmax(sqrt(ss), kMinNorm);
  double pn = tanh(un);
  double pf = pn > kMaxNorm ? kMaxNorm / pn : 1.0;
  double s = (pn / un) * pf;                  // expmap0+proj combined scale
  double xn = fmax(pn * pf, kMinNorm);        // |x_hyp| exact in f64
  if (lane == 0) {
    s_arr[row] = s;
    sart_arr[row] = artanh_c(xn) / xn;
  }
}

// ---- MFMA GEMM: C[N][64] = X[N][DIN] @ Wf (bf16 split, 4 mfma/K-step) ------
template <int DIN>
__global__ __launch_bounds__(256) void k_gemm(const float* __restrict__ X,
                                              const unsigned short* __restrict__ Wfh,
                                              const unsigned short* __restrict__ Wfl,
                                              float* __restrict__ C, int nrows) {
  const int wave = threadIdx.x >> 6, lane = threadIdx.x & 63;
  const int r0 = blockIdx.x * 64 + wave * 16;
  const int arow = min(r0 + (lane & 15), nrows - 1);
  const int kbase = (lane >> 4) * 8;
  f32x4 acc[4] = {{0, 0, 0, 0}, {0, 0, 0, 0}, {0, 0, 0, 0}, {0, 0, 0, 0}};
  const int KSTEPS = DIN / 32;
  for (int s = 0; s < KSTEPS; ++s) {
    const float* ap = X + (size_t)arow * DIN + s * 32 + kbase;
    const float4 a0 = *reinterpret_cast<const float4*>(ap);
    const float4 a1 = *reinterpret_cast<const float4*>(ap + 4);
    float av[8] = {a0.x, a0.y, a0.z, a0.w, a1.x, a1.y, a1.z, a1.w};
    short8v ah, al;
#pragma unroll
    for (int j = 0; j < 8; ++j) {
      unsigned short h = f2bf(av[j]);
      ah[j] = (short)h;
      al[j] = (short)f2bf(av[j] - bf2f(h));
    }
#pragma unroll
    for (int f = 0; f < 4; ++f) {
      size_t wi = (((size_t)s * 4 + f) * 64 + lane) * 8;
      short8v bh = *reinterpret_cast<const short8v*>(Wfh + wi);
      short8v bl = *reinterpret_cast<const short8v*>(Wfl + wi);
      acc[f] = __builtin_amdgcn_mfma_f32_16x16x32_bf16(al, bl, acc[f], 0, 0, 0);
      acc[f] = __builtin_amdgcn_mfma_f32_16x16x32_bf16(ah, bl, acc[f], 0, 0, 0);
      acc[f] = __builtin_amdgcn_mfma_f32_16x16x32_bf16(al, bh, acc[f], 0, 0, 0);
      acc[f] = __builtin_amdgcn_mfma_f32_16x16x32_bf16(ah, bh, acc[f], 0, 0, 0);
    }
  }
  // C/D layout: col = lane&15, row = (lane>>4)*4 + j   [m89-verified]
  const int orow0 = r0 + (lane >> 4) * 4;
#pragma unroll
  for (int f = 0; f < 4; ++f)
#pragma unroll
    for (int j = 0; j < 4; ++j) {
      int row = orow0 + j;
      if (row < nrows)
        C[(size_t)row * 64 + f * 16 + (lane & 15)] = acc[f][j];
    }
}

// ---- f64 Mobius tail: mx=s*dot -> mobius_matvec norm chain -> proj ->
//      mobius_add(hb) -> proj -> logmap0 ; wave per row ----------------------
template <bool FIRST>
__global__ __launch_bounds__(256) void k_tail(const float* __restrict__ C,
                                              const double* __restrict__ a1,
                                              const double* __restrict__ a2,
                                              const double* __restrict__ hb,
                                              const double* __restrict__ hby2,
                                              float* __restrict__ out_ht,
                                              int nrows) {
  int wave = threadIdx.x >> 6, lane = threadIdx.x & 63;
  int row = blockIdx.x * 4 + wave;
  if (row >= nrows) return;
  double dotd = (double)C[(size_t)row * 64 + lane];
  double s, sart;
  if constexpr (FIRST) {
    s = a1[row];
    sart = a2[row];
  } else {
    s = 1.0;
    double xn = a1[row];  // pre-rounding |h| (f64)
    sart = artanh_c(xn) / xn;
  }
  double mx = s * dotd;
  double mxn = fmax(sqrt(wsum64(mx * mx)), kMinNorm);
  double nmv = tanh(mxn * sart);               // = |mv| analytically
  double mv = (nmv / mxn) * mx;
  double pf1 = nmv > kMaxNorm ? kMaxNorm / nmv : 1.0;  // proj
  mv *= pf1;
  double x2 = (nmv * pf1) * (nmv * pf1);
  // mobius_add(mv, hb)
  double hbd = hb[lane];
  double y2 = hby2[0];
  double xy = wsum64(mv * hbd);
  double num = (1.0 + 2.0 * xy + y2) * mv + (1.0 - x2) * hbd;
  double den = fmax(1.0 + 2.0 * xy + x2 * y2, kMinNorm);
  double h = num / den;
  // proj + logmap0
  double hn = fmax(sqrt(wsum64(h * h)), kMinNorm);
  double pf2 = hn > kMaxNorm ? kMaxNorm / hn : 1.0;
  h *= pf2;
  hn = fmax(hn * pf2, kMinNorm);
  double ht = (artanh_c(hn) / hn) * h;
  out_ht[(size_t)row * 64 + lane] = (float)ht;
}

// ------------------------- CSR build --------------------------------------
__global__ __launch_bounds__(256) void k_hist(const int* __restrict__ dst,
                                              int* __restrict__ cnt, int E) {
  int e = blockIdx.x * 256 + threadIdx.x;
  if (e < E) atomicAdd(&cnt[dst[e]], 1);
}

__global__ __launch_bounds__(256) void k_scan1(const int* __restrict__ cnt,
                                               int* __restrict__ rp,
                                               int* __restrict__ bsum, int n) {
  __shared__ int wsums[4];
  int base = blockIdx.x * 2048;
  int t = threadIdx.x;
  int lane = t & 63, wv = t >> 6;
  int vals[8];
  int s = 0;
#pragma unroll
  for (int i = 0; i < 8; ++i) {
    int idx = base + t * 8 + i;
    int v = (idx < n) ? cnt[idx] : 0;
    vals[i] = s;
    s += v;
  }
  int incl = s;
#pragma unroll
  for (int o = 1; o < 64; o <<= 1) {
    int u = __shfl_up(incl, o, 64);
    if (lane >= o) incl += u;
  }
  if (lane == 63) wsums[wv] = incl;
  __syncthreads();
  int woff = 0;
  for (int i = 0; i < wv; ++i) woff += wsums[i];
  int texcl = woff + incl - s;
#pragma unroll
  for (int i = 0; i < 8; ++i) {
    int idx = base + t * 8 + i;
    if (idx < n) rp[idx] = texcl + vals[i];
  }
  if (t == 255) bsum[blockIdx.x] = woff + incl;
}

__global__ __launch_bounds__(64) void k_scan2(int* __restrict__ bsum, int nb) {
  int t = threadIdx.x;
  int v = (t < nb) ? bsum[t] : 0;
  int incl = v;
#pragma unroll
  for (int o = 1; o < 64; o <<= 1) {
    int u = __shfl_up(incl, o, 64);
    if (t >= o) incl += u;
  }
  if (t < nb) bsum[t] = incl - v;
}

__global__ __launch_bounds__(256) void k_scan3(int* __restrict__ rp,
                                               const int* __restrict__ bsum,
                                               int* __restrict__ work, int n,
                                               int E) {
  int i = blockIdx.x * 256 + threadIdx.x;
  if (i >= n) return;
  int v = rp[i] + bsum[i >> 11];
  rp[i] = v;
  work[i] = v;
  if (i == 0) rp[n] = E;
}

__global__ __launch_bounds__(256) void k_scatter(const int* __restrict__ src,
                                                 const int* __restrict__ dst,
                                                 const float* __restrict__ val,
                                                 int* __restrict__ work,
                                                 int* __restrict__ psrc,
                                                 float* __restrict__ pval,
                                                 int E) {
  int e = blockIdx.x * 256 + threadIdx.x;
  if (e >= E) return;
  int d = dst[e];
  int pos = atomicAdd(&work[d], 1);
  psrc[pos] = src[e];
  pval[pos] = val[e];
}

// ---- fused gather SpMM + postagg: one wave per destination row ------------
__global__ __launch_bounds__(256) void k_spmm_post(
    const float* __restrict__ ht, const int* __restrict__ rp,
    const int* __restrict__ psrc, const float* __restrict__ pval,
    float* __restrict__ hout, double* __restrict__ aux, int nrows) {
  int wave = threadIdx.x >> 6, lane = threadIdx.x & 63;
  int row = blockIdx.x * 4 + wave;
  if (row >= nrows) return;
  int beg = rp[row], end = rp[row + 1];
  double acc = 0.0;
  for (int j0 = beg; j0 < end; j0 += 64) {
    int nj = min(64, end - j0);
    int sj = 0;
    float vj = 0.f;
    if (lane < nj) {
      sj = psrc[j0 + lane];
      vj = pval[j0 + lane];
    }
#pragma unroll 4
    for (int k = 0; k < nj; ++k) {
      int s = __shfl(sj, k, 64);
      float v = __shfl(vj, k, 64);
      acc += (double)v * (double)ht[(size_t)s * 64 + lane];
    }
  }
  double an = fmax(sqrt(wsum64(acc * acc)), kMinNorm);
  double hn = tanh(an);
  double pf = hn > kMaxNorm ? kMaxNorm / hn : 1.0;
  double h = acc * (hn / an) * pf;
  double hnn = fmax(hn * pf, kMinNorm);
  double t = (artanh_c(hnn) / hnn) * h;
  t = fmax(t, 0.0);  // relu in tangent space
  double tn = fmax(sqrt(wsum64(t * t)), kMinNorm);
  double h2n = tanh(tn);
  double pf2 = h2n > kMaxNorm ? kMaxNorm / h2n : 1.0;
  double h2 = t * (h2n / tn) * pf2;
  hout[(size_t)row * 64 + lane] = (float)h2;
  if (lane == 0) aux[row] = fmax(h2n * pf2, kMinNorm);
}

// ---- combine: mulscaler(1/8) -> mobius_add chain -> mean(logmap0) -> out ---
__global__ __launch_bounds__(256) void k_combine(const float* __restrict__ F,
                                                 const double* __restrict__ auxF,
                                                 float* __restrict__ out,
                                                 int nrows, int N) {
  int wave = threadIdx.x >> 6, lane = threadIdx.x & 63;
  int row = blockIdx.x * 4 + wave;
  if (row >= nrows) return;
  double f[4], nb[4];
#pragma unroll
  for (int b = 0; b < 4; b++) {
    f[b] = (double)F[((size_t)b * N + row) * 64 + lane];
    nb[b] = auxF[(size_t)b * N + row];
  }
  double w[4], wn2[4];
#pragma unroll
  for (int b = 0; b < 4; b++) {
    double art = artanh_c(nb[b]);
    double wn = tanh(art * 0.125);
    w[b] = (wn / nb[b]) * f[b];
    wn2[b] = wn * wn;
  }
  double tgt = w[0], tx2 = wn2[0];
#pragma unroll
  for (int i = 1; i < 4; i++) {
    double xy = wsum64(tgt * w[i]);
    double num = (1.0 + 2.0 * xy + wn2[i]) * tgt + (1.0 - tx2) * w[i];
    double den = fmax(1.0 + 2.0 * xy + tx2 * wn2[i], kMinNorm);
    tgt = num / den;
    tx2 = wsum64(tgt * tgt);
  }
  double tn = fmax(sqrt(tx2), kMinNorm);
  double m = 0.0;
#pragma unroll
  for (int b = 0; b < 4; b++) m += (artanh_c(nb[b]) / nb[b]) * f[b];
  m += (artanh_c(tn) / tn) * tgt;
  m *= 0.2;
  double mn = fmax(sqrt(wsum64(m * m)), kMinNorm);
  double on = tanh(mn);
  double pf = on > kMaxNorm ? kMaxNorm / on : 1.0;
  out[(size_t)row * 64 + lane] = (float)(m * (on / mn) * pf);
}

// ---------------------------------------------------------------------------
extern "C" void kernel_launch(void* const* d_in, const int* in_sizes, int n_in,
                              void* d_out, int out_size, void* d_ws,
                              size_t ws_size, hipStream_t stream) {
  const int FIN = 256, NB = 4;
  const int N = in_sizes[0] / FIN;       // 50000
  const int E = in_sizes[5] / NB;        // 800000
  const float* x = (const float*)d_in[0];
  const float* W1 = (const float*)d_in[1];
  const float* b1 = (const float*)d_in[2];
  const float* W2 = (const float*)d_in[3];
  const float* b2 = (const float*)d_in[4];
  const float* vals = (const float*)d_in[5];
  const int* src = (const int*)d_in[6];
  const int* dst = (const int*)d_in[7];
  float* out = (float*)d_out;

  char* w = (char*)d_ws;
  auto alloc = [&](size_t bytes) -> char* {
    char* p = w;
    w += (bytes + 255) & ~size_t(255);
    return p;
  };
  const int WF1 = NB * (FIN / 32) * 4 * 64 * 8;   // 65536 ushorts
  const int WF2 = NB * (64 / 32) * 4 * 64 * 8;    // 16384 ushorts
  unsigned short* Wf1h = (unsigned short*)alloc((size_t)WF1 * 2);
  unsigned short* Wf1l = (unsigned short*)alloc((size_t)WF1 * 2);
  unsigned short* Wf2h = (unsigned short*)alloc((size_t)WF2 * 2);
  unsigned short* Wf2l = (unsigned short*)alloc((size_t)WF2 * 2);
  double* hb1 = (double*)alloc(NB * 64 * 8);
  double* hb2 = (double*)alloc(NB * 64 * 8);
  double* y21 = (double*)alloc(NB * 8);
  double* y22 = (double*)alloc(NB * 8);
  double* auxS = (double*)alloc((size_t)N * 8);
  double* auxSa = (double*)alloc((size_t)N * 8);
  double* auxT = (double*)alloc((size_t)N * 8);
  double* auxF = (double*)alloc((size_t)NB * N * 8);
  float* A = (float*)alloc((size_t)N * 64 * 4);
  float* B = (float*)alloc((size_t)N * 64 * 4);
  float* Cb = (float*)alloc((size_t)N * 64 * 4);
  float* F = (float*)alloc((size_t)NB * N * 64 * 4);
  int* cnt = (int*)alloc((size_t)N * 4);
  int* rp = (int*)alloc(((size_t)N + 1) * 4);
  int* work = (int*)alloc((size_t)N * 4);
  int* bsum = (int*)alloc(64 * 4);
  int* psrc = (int*)alloc((size_t)E * 4);
  float* pval = (float*)alloc((size_t)E * 4);

  const int rowBlocks = (N + 3) / 4;          // wave-per-row kernels
  const int gemmBlocks = (N + 63) / 64;       // 64 rows/block
  const int eBlocks = (E + 255) / 256;
  const int scanBlocks = (N + 2047) / 2048;

  k_wprep<<<(WF1 / 8 + 255) / 256, 256, 0, stream>>>(W1, Wf1h, Wf1l, FIN,
                                                     WF1 / 8);
  k_wprep<<<(WF2 / 8 + 255) / 256, 256, 0, stream>>>(W2, Wf2h, Wf2l, 64,
                                                     WF2 / 8);
  k_bias<<<1, 512, 0, stream>>>(b1, b2, hb1, hb2, y21, y22);
  k_prescale<<<rowBlocks, 256, 0, stream>>>(x, auxS, auxSa, N);

  const int wf1b = WF1 / NB;   // per-branch ushort count
  const int wf2b = WF2 / NB;

  for (int b = 0; b < NB; ++b) {
    const int* sb = src + (size_t)b * E;
    const int* db = dst + (size_t)b * E;
    const float* vb = vals + (size_t)b * E;
    // ---- CSR build for this branch ----
    hipMemsetAsync(cnt, 0, (size_t)N * 4, stream);
    k_hist<<<eBlocks, 256, 0, stream>>>(db, cnt, E);
    k_scan1<<<scanBlocks, 256, 0, stream>>>(cnt, rp, bsum, N);
    k_scan2<<<1, 64, 0, stream>>>(bsum, scanBlocks);
    k_scan3<<<(N + 255) / 256, 256, 0, stream>>>(rp, bsum, work, N, E);
    k_scatter<<<eBlocks, 256, 0, stream>>>(sb, db, vb, work, psrc, pval, E);
    // ---- layer 1 ----
    k_gemm<256><<<gemmBlocks, 256, 0, stream>>>(x, Wf1h + (size_t)b * wf1b,
                                                Wf1l + (size_t)b * wf1b, Cb, N);
    k_tail<true><<<rowBlocks, 256, 0, stream>>>(Cb, auxS, auxSa, hb1 + b * 64,
                                                y21 + b, A, N);
    k_spmm_post<<<rowBlocks, 256, 0, stream>>>(A, rp, psrc, pval, B, auxT, N);
    // ---- layer 2 ----
    k_gemm<64><<<gemmBlocks, 256, 0, stream>>>(B, Wf2h + (size_t)b * wf2b,
                                               Wf2l + (size_t)b * wf2b, Cb, N);
    k_tail<false><<<rowBlocks, 256, 0, stream>>>(Cb, auxT, nullptr,
                                                 hb2 + b * 64, y22 + b, A, N);
    k_spmm_post<<<rowBlocks, 256, 0, stream>>>(A, rp, psrc, pval,
                                               F + (size_t)b * N * 64,
                                               auxF + (size_t)b * N, N);
  }
  k_combine<<<rowBlocks, 256, 0, stream>>>(F, auxF, out, N, N);
}

// Round 4
// 1510.006 us; speedup vs baseline: 5.3275x; 1.3363x over previous
//
#include <hip/hip_runtime.h>
#include <math.h>

// ---------------------------------------------------------------------------
// DHYPR hyperbolic GNN encoder, MI355X (gfx950).  Round 4:
//  - postagg exp/log identity:  logmap0(proj(expmap0(a))) = a*min(1, K/|a|)
//  - k_combine f32-ified (f64 only for norm-argument prep)
//  - all 4 branches batched per dispatch (53 -> 16 launches), x read once,
//    prescale fused into gemm1 epilogue, tails run in-place.
// ---------------------------------------------------------------------------

constexpr double kMaxNorm = 1.0 - 1e-5;   // (1-PROJ_EPS)/sqrt(c), c=1
constexpr double kMinNorm = 1e-15;
constexpr double kArtMax  = 6.1030338227611066;  // artanh(kMaxNorm)

typedef __attribute__((ext_vector_type(8))) short short8v;   // 8 bf16
typedef __attribute__((ext_vector_type(4))) float f32x4;

__device__ inline double wsum64(double v) {
#pragma unroll
  for (int o = 32; o > 0; o >>= 1) v += __shfl_xor(v, o, 64);
  return v;
}
__device__ inline float wsum32f(float v) {
#pragma unroll
  for (int o = 32; o > 0; o >>= 1) v += __shfl_xor(v, o, 64);
  return v;
}

__device__ inline double artanh_c(double x) {  // x >= 0
  x = fmin(x, 1.0 - 1e-7);
  return 0.5 * (log1p(x) - log1p(-x));
}

__device__ inline unsigned short f2bf(float f) {  // RN-even f32->bf16
  union { float f; unsigned int u; } v{f};
  unsigned int r = v.u + 0x7fffu + ((v.u >> 16) & 1u);
  return (unsigned short)(r >> 16);
}
__device__ inline float bf2f(unsigned short h) {
  union { unsigned int u; float f; } v{(unsigned int)h << 16};
  return v.f;
}

// ------------------------- hb = proj(expmap0(bias)) in f64 ------------------
__global__ __launch_bounds__(512) void k_bias(const float* __restrict__ b1,
                                              const float* __restrict__ b2,
                                              double* __restrict__ hb1,
                                              double* __restrict__ hb2,
                                              double* __restrict__ y21,
                                              double* __restrict__ y22) {
  int w = threadIdx.x >> 6, lane = threadIdx.x & 63;
  const float* bs = (w < 4) ? (b1 + w * 64) : (b2 + (w - 4) * 64);
  double v = (double)bs[lane];
  double un = fmax(sqrt(wsum64(v * v)), kMinNorm);
  double pn = tanh(un);
  double pf = pn > kMaxNorm ? kMaxNorm / pn : 1.0;
  double p = v * (pn / un) * pf;
  double* hb = (w < 4) ? hb1 + w * 64 : hb2 + (w - 4) * 64;
  hb[lane] = p;
  if (lane == 0) {
    double n = pn * pf;
    double* y2 = (w < 4) ? (y21 + w) : (y22 + (w - 4));
    *y2 = n * n;
  }
}

// ---- weight prep: fragment-ready bf16 hi/lo, layout [s][b][f][lane][8] -----
__global__ __launch_bounds__(256) void k_wprep(const float* __restrict__ W,
                                               unsigned short* __restrict__ Wfh,
                                               unsigned short* __restrict__ Wfl,
                                               int DIN, int tot) {
  int idx = blockIdx.x * 256 + threadIdx.x;
  if (idx >= tot) return;
  int lane = idx & 63;
  int t = idx >> 6;
  int f = t & 3; t >>= 2;
  int ks = DIN >> 5;
  int s = t % ks;
  int b = t / ks;
  int c = f * 16 + (lane & 15);
  int k = s * 32 + (lane >> 4) * 8;
  const float* wp = W + ((size_t)(b * 64 + c)) * DIN + k;
  size_t dst = (((size_t)(s * 4 + b) * 4 + f) * 64 + lane) * 8;
#pragma unroll
  for (int j = 0; j < 8; ++j) {
    float v = wp[j];
    unsigned short h = f2bf(v);
    unsigned short l = f2bf(v - bf2f(h));
    Wfh[dst + j] = h;
    Wfl[dst + j] = l;
  }
}

// ---- layer-1 GEMM, all 4 branches batched, prescale fused ------------------
__global__ __launch_bounds__(256) void k_gemm1(const float* __restrict__ X,
                                               const unsigned short* __restrict__ Wfh,
                                               const unsigned short* __restrict__ Wfl,
                                               float* __restrict__ C4,
                                               double* __restrict__ auxS,
                                               double* __restrict__ auxSa,
                                               int N) {
  const int wave = threadIdx.x >> 6, lane = threadIdx.x & 63;
  const int r0 = blockIdx.x * 64 + wave * 16;
  const int arow = min(r0 + (lane & 15), N - 1);
  const int kbase = (lane >> 4) * 8;
  f32x4 acc[4][4] = {};
  double ss = 0.0;
#pragma unroll
  for (int s = 0; s < 8; ++s) {
    const float* ap = X + (size_t)arow * 256 + s * 32 + kbase;
    const float4 a0 = *reinterpret_cast<const float4*>(ap);
    const float4 a1 = *reinterpret_cast<const float4*>(ap + 4);
    float av[8] = {a0.x, a0.y, a0.z, a0.w, a1.x, a1.y, a1.z, a1.w};
    short8v ah, al;
#pragma unroll
    for (int j = 0; j < 8; ++j) {
      ss += (double)av[j] * av[j];
      unsigned short h = f2bf(av[j]);
      ah[j] = (short)h;
      al[j] = (short)f2bf(av[j] - bf2f(h));
    }
#pragma unroll
    for (int bb = 0; bb < 4; ++bb)
#pragma unroll
      for (int f = 0; f < 4; ++f) {
        size_t wi = (((size_t)(s * 4 + bb) * 4 + f) * 64 + lane) * 8;
        short8v bh = *reinterpret_cast<const short8v*>(Wfh + wi);
        short8v bl = *reinterpret_cast<const short8v*>(Wfl + wi);
        acc[bb][f] = __builtin_amdgcn_mfma_f32_16x16x32_bf16(al, bl, acc[bb][f], 0, 0, 0);
        acc[bb][f] = __builtin_amdgcn_mfma_f32_16x16x32_bf16(ah, bl, acc[bb][f], 0, 0, 0);
        acc[bb][f] = __builtin_amdgcn_mfma_f32_16x16x32_bf16(al, bh, acc[bb][f], 0, 0, 0);
        acc[bb][f] = __builtin_amdgcn_mfma_f32_16x16x32_bf16(ah, bh, acc[bb][f], 0, 0, 0);
      }
  }
  // fused prescale: row sumsq = reduce over the 4 k-lane groups (same lane&15)
  ss += __shfl_xor(ss, 16, 64);
  ss += __shfl_xor(ss, 32, 64);
  if (lane < 16) {
    int row = r0 + lane;
    if (row < N) {
      double un = fmax(sqrt(ss), kMinNorm);
      double pn = tanh(un);
      double pf = pn > kMaxNorm ? kMaxNorm / pn : 1.0;
      auxS[row] = (pn / un) * pf;
      double xn = fmax(pn * pf, kMinNorm);
      auxSa[row] = artanh_c(xn) / xn;
    }
  }
  // C/D layout: col = lane&15, row = (lane>>4)*4 + j
  const int orow0 = r0 + (lane >> 4) * 4;
#pragma unroll
  for (int bb = 0; bb < 4; ++bb)
#pragma unroll
    for (int f = 0; f < 4; ++f)
#pragma unroll
      for (int j = 0; j < 4; ++j) {
        int row = orow0 + j;
        if (row < N)
          C4[((size_t)bb * N + row) * 64 + f * 16 + (lane & 15)] = acc[bb][f][j];
      }
}

// ---- layer-2 GEMM: per-branch (blockIdx.y), DIN=64 -------------------------
__global__ __launch_bounds__(256) void k_gemm2(const float* __restrict__ X4,
                                               const unsigned short* __restrict__ Wfh,
                                               const unsigned short* __restrict__ Wfl,
                                               float* __restrict__ C4, int N) {
  const int wave = threadIdx.x >> 6, lane = threadIdx.x & 63;
  const int b = blockIdx.y;
  const int r0 = blockIdx.x * 64 + wave * 16;
  const int arow = min(r0 + (lane & 15), N - 1);
  const int kbase = (lane >> 4) * 8;
  const float* X = X4 + (size_t)b * N * 64;
  f32x4 acc[4] = {};
#pragma unroll
  for (int s = 0; s < 2; ++s) {
    const float* ap = X + (size_t)arow * 64 + s * 32 + kbase;
    const float4 a0 = *reinterpret_cast<const float4*>(ap);
    const float4 a1 = *reinterpret_cast<const float4*>(ap + 4);
    float av[8] = {a0.x, a0.y, a0.z, a0.w, a1.x, a1.y, a1.z, a1.w};
    short8v ah, al;
#pragma unroll
    for (int j = 0; j < 8; ++j) {
      unsigned short h = f2bf(av[j]);
      ah[j] = (short)h;
      al[j] = (short)f2bf(av[j] - bf2f(h));
    }
#pragma unroll
    for (int f = 0; f < 4; ++f) {
      size_t wi = (((size_t)(s * 4 + b) * 4 + f) * 64 + lane) * 8;
      short8v bh = *reinterpret_cast<const short8v*>(Wfh + wi);
      short8v bl = *reinterpret_cast<const short8v*>(Wfl + wi);
      acc[f] = __builtin_amdgcn_mfma_f32_16x16x32_bf16(al, bl, acc[f], 0, 0, 0);
      acc[f] = __builtin_amdgcn_mfma_f32_16x16x32_bf16(ah, bl, acc[f], 0, 0, 0);
      acc[f] = __builtin_amdgcn_mfma_f32_16x16x32_bf16(al, bh, acc[f], 0, 0, 0);
      acc[f] = __builtin_amdgcn_mfma_f32_16x16x32_bf16(ah, bh, acc[f], 0, 0, 0);
    }
  }
  const int orow0 = r0 + (lane >> 4) * 4;
#pragma unroll
  for (int f = 0; f < 4; ++f)
#pragma unroll
    for (int j = 0; j < 4; ++j) {
      int row = orow0 + j;
      if (row < N)
        C4[((size_t)b * N + row) * 64 + f * 16 + (lane & 15)] = acc[f][j];
    }
}

// ---- f64 Mobius tail, batched over branches, IN-PLACE on C -----------------
template <bool FIRST>
__global__ __launch_bounds__(256) void k_tail(float* __restrict__ C4,
                                              const double* __restrict__ a1,
                                              const double* __restrict__ a2,
                                              const double* __restrict__ hbAll,
                                              const double* __restrict__ y2All,
                                              int N) {
  int wave = threadIdx.x >> 6, lane = threadIdx.x & 63;
  int row = blockIdx.x * 4 + wave;
  if (row >= N) return;
  int b = blockIdx.y;
  size_t R = (size_t)b * N + row;
  double dotd = (double)C4[R * 64 + lane];
  double s, sart;
  if constexpr (FIRST) {
    s = a1[row];          // branch-invariant expmap0(x) scale
    sart = a2[row];
  } else {
    s = 1.0;
    double xn = a1[R];    // pre-rounding |h| (f64)
    sart = artanh_c(xn) / xn;
  }
  double mx = s * dotd;
  double mxn = fmax(sqrt(wsum64(mx * mx)), kMinNorm);
  double nmv = tanh(mxn * sart);               // = |mv| analytically
  double mv = (nmv / mxn) * mx;
  double pf1 = nmv > kMaxNorm ? kMaxNorm / nmv : 1.0;  // proj
  mv *= pf1;
  double x2 = (nmv * pf1) * (nmv * pf1);
  double hbd = hbAll[b * 64 + lane];
  double y2 = y2All[b];
  double xy = wsum64(mv * hbd);
  double num = (1.0 + 2.0 * xy + y2) * mv + (1.0 - x2) * hbd;
  double den = fmax(1.0 + 2.0 * xy + x2 * y2, kMinNorm);
  double h = num / den;
  double hn = fmax(sqrt(wsum64(h * h)), kMinNorm);
  double pf2 = hn > kMaxNorm ? kMaxNorm / hn : 1.0;
  h *= pf2;
  hn = fmax(hn * pf2, kMinNorm);
  double ht = (artanh_c(hn) / hn) * h;
  C4[R * 64 + lane] = (float)ht;   // in-place (row-local)
}

// ------------------------- CSR build (all 4 branches flat) ------------------
__global__ __launch_bounds__(256) void k_hist(const int* __restrict__ dst,
                                              int* __restrict__ cnt4, int E,
                                              int N) {
  int e = blockIdx.x * 256 + threadIdx.x;
  int b = blockIdx.y;
  if (e < E) atomicAdd(&cnt4[b * N + dst[(size_t)b * E + e]], 1);
}

// exclusive scan, TILE=4096 per block (256 thr x 16 items)
__global__ __launch_bounds__(256) void k_scan1(const int* __restrict__ cnt,
                                               int* __restrict__ rp,
                                               int* __restrict__ bsum, int n) {
  __shared__ int wsums[4];
  int base = blockIdx.x * 4096;
  int t = threadIdx.x;
  int lane = t & 63, wv = t >> 6;
  int vals[16];
  int s = 0;
#pragma unroll
  for (int i = 0; i < 16; ++i) {
    int idx = base + t * 16 + i;
    int v = (idx < n) ? cnt[idx] : 0;
    vals[i] = s;
    s += v;
  }
  int incl = s;
#pragma unroll
  for (int o = 1; o < 64; o <<= 1) {
    int u = __shfl_up(incl, o, 64);
    if (lane >= o) incl += u;
  }
  if (lane == 63) wsums[wv] = incl;
  __syncthreads();
  int woff = 0;
  for (int i = 0; i < wv; ++i) woff += wsums[i];
  int texcl = woff + incl - s;
#pragma unroll
  for (int i = 0; i < 16; ++i) {
    int idx = base + t * 16 + i;
    if (idx < n) rp[idx] = texcl + vals[i];
  }
  if (t == 255) bsum[blockIdx.x] = woff + incl;
}

__global__ __launch_bounds__(64) void k_scan2(int* __restrict__ bsum, int nb) {
  int t = threadIdx.x;
  int v = (t < nb) ? bsum[t] : 0;
  int incl = v;
#pragma unroll
  for (int o = 1; o < 64; o <<= 1) {
    int u = __shfl_up(incl, o, 64);
    if (t >= o) incl += u;
  }
  if (t < nb) bsum[t] = incl - v;
}

__global__ __launch_bounds__(256) void k_scan3(int* __restrict__ rp,
                                               const int* __restrict__ bsum,
                                               int* __restrict__ cursor, int n,
                                               int Etot) {
  int i = blockIdx.x * 256 + threadIdx.x;
  if (i >= n) return;
  int v = rp[i] + bsum[i >> 12];
  rp[i] = v;
  cursor[i] = v;
  if (i == 0) rp[n] = Etot;
}

__global__ __launch_bounds__(256) void k_scatter(const int* __restrict__ src,
                                                 const int* __restrict__ dst,
                                                 const float* __restrict__ val,
                                                 int* __restrict__ cursor,
                                                 int2* __restrict__ pvedge,
                                                 int E, int N) {
  int e = blockIdx.x * 256 + threadIdx.x;
  if (e >= E) return;
  int b = blockIdx.y;
  size_t ge = (size_t)b * E + e;
  int d = dst[ge];
  int pos = atomicAdd(&cursor[b * N + d], 1);
  pvedge[pos] = make_int2(src[ge], __float_as_int(val[ge]));
}

// ---- gather SpMM + identity postagg, batched:  t = relu(acc*min(1,K/|acc|)),
//      h2 = proj(expmap0(t)).  f64 acc for replay stability. ----------------
__global__ __launch_bounds__(256) void k_spmm_post(
    const float* __restrict__ ht4, const int* __restrict__ rp4,
    const int2* __restrict__ pvedge, float* __restrict__ out4,
    double* __restrict__ aux4, int N) {
  int wave = threadIdx.x >> 6, lane = threadIdx.x & 63;
  int row = blockIdx.x * 4 + wave;
  if (row >= N) return;
  int b = blockIdx.y;
  size_t R = (size_t)b * N + row;
  const float* ht = ht4 + (size_t)b * N * 64;
  int beg = rp4[R], end = rp4[R + 1];
  double acc = 0.0;
  for (int j0 = beg; j0 < end; j0 += 64) {
    int nj = min(64, end - j0);
    int2 ev = make_int2(0, 0);
    if (lane < nj) ev = pvedge[j0 + lane];
#pragma unroll 4
    for (int k = 0; k < nj; ++k) {
      int s = __shfl(ev.x, k, 64);
      float v = __int_as_float(__shfl(ev.y, k, 64));
      acc = fma((double)v, (double)ht[(size_t)s * 64 + lane], acc);
    }
  }
  double an = fmax(sqrt(wsum64(acc * acc)), kMinNorm);
  double t = acc * (an > kArtMax ? kArtMax / an : 1.0);
  t = fmax(t, 0.0);  // relu in tangent space
  double tn = fmax(sqrt(wsum64(t * t)), kMinNorm);
  double h2n = tanh(tn);
  double pf2 = h2n > kMaxNorm ? kMaxNorm / h2n : 1.0;
  double h2 = t * (h2n / tn) * pf2;
  out4[R * 64 + lane] = (float)h2;
  if (lane == 0) aux4[R] = fmax(h2n * pf2, kMinNorm);
}

// ---- combine (f32 math; artanh from f64-prepped arguments) -----------------
__global__ __launch_bounds__(256) void k_combine(const float* __restrict__ F4,
                                                 const double* __restrict__ auxF4,
                                                 float* __restrict__ out, int N) {
  int wave = threadIdx.x >> 6, lane = threadIdx.x & 63;
  int row = blockIdx.x * 4 + wave;
  if (row >= N) return;
  float f[4], art[4], w[4], wn2[4];
  double nbd[4];
#pragma unroll
  for (int b = 0; b < 4; b++) {
    f[b] = F4[((size_t)b * N + row) * 64 + lane];
    nbd[b] = auxF4[(size_t)b * N + row];
    art[b] = 0.5f * (logf((float)(1.0 + nbd[b])) - logf((float)(1.0 - nbd[b])));
    float wn = tanhf(art[b] * 0.125f);
    w[b] = (wn / (float)nbd[b]) * f[b];
    wn2[b] = wn * wn;
  }
  float tgt = w[0], tx2 = wn2[0];
#pragma unroll
  for (int i = 1; i < 4; i++) {
    float xy = wsum32f(tgt * w[i]);
    float num = (1.f + 2.f * xy + wn2[i]) * tgt + (1.f - tx2) * w[i];
    float den = fmaxf(1.f + 2.f * xy + tx2 * wn2[i], 1e-15f);
    tgt = num / den;
    tx2 = wsum32f(tgt * tgt);
  }
  float tn = fmaxf(sqrtf(tx2), 1e-15f);
  float artt = 0.5f * (logf(1.f + tn) - logf(1.f - tn));
  float m = (artt / tn) * tgt;
#pragma unroll
  for (int b = 0; b < 4; b++) m += (art[b] / (float)nbd[b]) * f[b];
  m *= 0.2f;
  float mn = fmaxf(sqrtf(wsum32f(m * m)), 1e-15f);
  float on = tanhf(mn);
  float pf = on > 0.99999f ? 0.99999f / on : 1.f;
  out[(size_t)row * 64 + lane] = m * (on / mn) * pf;
}

// ---------------------------------------------------------------------------
extern "C" void kernel_launch(void* const* d_in, const int* in_sizes, int n_in,
                              void* d_out, int out_size, void* d_ws,
                              size_t ws_size, hipStream_t stream) {
  const int FIN = 256, NB = 4;
  const int N = in_sizes[0] / FIN;       // 50000
  const int E = in_sizes[5] / NB;        // 800000
  const float* x = (const float*)d_in[0];
  const float* W1 = (const float*)d_in[1];
  const float* b1 = (const float*)d_in[2];
  const float* W2 = (const float*)d_in[3];
  const float* b2 = (const float*)d_in[4];
  const float* vals = (const float*)d_in[5];
  const int* src = (const int*)d_in[6];
  const int* dst = (const int*)d_in[7];
  float* out = (float*)d_out;
  const int n4 = NB * N;

  char* w = (char*)d_ws;
  auto alloc = [&](size_t bytes) -> char* {
    char* p = w;
    w += (bytes + 255) & ~size_t(255);
    return p;
  };
  const int WF1 = NB * (FIN / 32) * 4 * 64 * 8;   // 65536 ushorts
  const int WF2 = NB * (64 / 32) * 4 * 64 * 8;    // 16384 ushorts
  unsigned short* Wf1h = (unsigned short*)alloc((size_t)WF1 * 2);
  unsigned short* Wf1l = (unsigned short*)alloc((size_t)WF1 * 2);
  unsigned short* Wf2h = (unsigned short*)alloc((size_t)WF2 * 2);
  unsigned short* Wf2l = (unsigned short*)alloc((size_t)WF2 * 2);
  double* hb1 = (double*)alloc(NB * 64 * 8);
  double* hb2 = (double*)alloc(NB * 64 * 8);
  double* y21 = (double*)alloc(NB * 8);
  double* y22 = (double*)alloc(NB * 8);
  double* auxS = (double*)alloc((size_t)N * 8);
  double* auxSa = (double*)alloc((size_t)N * 8);
  double* auxT4 = (double*)alloc((size_t)n4 * 8);
  double* auxF4 = (double*)alloc((size_t)n4 * 8);
  float* Cb4 = (float*)alloc((size_t)n4 * 64 * 4);   // gemm out / tail inplace
  float* A4 = (float*)alloc((size_t)n4 * 64 * 4);    // spmm out
  int* cnt4 = (int*)alloc((size_t)n4 * 4);           // hist, then cursor
  int* rp4 = (int*)alloc(((size_t)n4 + 1) * 4);
  int* bsum = (int*)alloc(64 * 4);
  int2* pvedge = (int2*)alloc((size_t)NB * E * 8);

  const int rowBlocks = (N + 3) / 4;
  const int gemmBlocks = (N + 63) / 64;
  const int eBlocks = (E + 255) / 256;
  const int scanBlocks = (n4 + 4095) / 4096;   // 49

  k_wprep<<<(WF1 / 8 + 255) / 256, 256, 0, stream>>>(W1, Wf1h, Wf1l, FIN, WF1 / 8);
  k_wprep<<<(WF2 / 8 + 255) / 256, 256, 0, stream>>>(W2, Wf2h, Wf2l, 64, WF2 / 8);
  k_bias<<<1, 512, 0, stream>>>(b1, b2, hb1, hb2, y21, y22);

  // ---- batched CSR over all 4 branches ----
  hipMemsetAsync(cnt4, 0, (size_t)n4 * 4, stream);
  k_hist<<<dim3(eBlocks, NB), 256, 0, stream>>>(dst, cnt4, E, N);
  k_scan1<<<scanBlocks, 256, 0, stream>>>(cnt4, rp4, bsum, n4);
  k_scan2<<<1, 64, 0, stream>>>(bsum, scanBlocks);
  k_scan3<<<(n4 + 255) / 256, 256, 0, stream>>>(rp4, bsum, cnt4, n4, NB * E);
  k_scatter<<<dim3(eBlocks, NB), 256, 0, stream>>>(src, dst, vals, cnt4, pvedge, E, N);

  // ---- layer 1 (batched) ----
  k_gemm1<<<gemmBlocks, 256, 0, stream>>>(x, Wf1h, Wf1l, Cb4, auxS, auxSa, N);
  k_tail<true><<<dim3(rowBlocks, NB), 256, 0, stream>>>(Cb4, auxS, auxSa, hb1, y21, N);
  k_spmm_post<<<dim3(rowBlocks, NB), 256, 0, stream>>>(Cb4, rp4, pvedge, A4, auxT4, N);
  // ---- layer 2 (batched) ----
  k_gemm2<<<dim3(gemmBlocks, NB), 256, 0, stream>>>(A4, Wf2h, Wf2l, Cb4, N);
  k_tail<false><<<dim3(rowBlocks, NB), 256, 0, stream>>>(Cb4, auxT4, nullptr, hb2, y22, N);
  k_spmm_post<<<dim3(rowBlocks, NB), 256, 0, stream>>>(Cb4, rp4, pvedge, A4, auxF4, N);

  k_combine<<<rowBlocks, 256, 0, stream>>>(A4, auxF4, out, N);
}

// Round 5
// 1049.163 us; speedup vs baseline: 7.6676x; 1.4392x over previous
//
#include <hip/hip_runtime.h>
#include <math.h>

// ---------------------------------------------------------------------------
// DHYPR hyperbolic GNN encoder, MI355X (gfx950).  Round 5: f32-ified Mobius
// tails using cancellation-free gyro-identities:
//   1-|x(+)y|^2 = (1-|x|^2)(1-|y|^2)/den ,  |x(+)y|^2 = (x2+2xy+y2)/den
//   1-tanh^2 z  = 4e/(1+e)^2 with e=exp(-2z)
//   artanh(|expmap0(t)|) = min(|t|, K)  (exact; carried as 'atn' aux, f32)
// All f64 libm removed from the hot path; f64 remains only in tiny prep
// kernels (bias, gemm1 row-prescale).
// ---------------------------------------------------------------------------

constexpr double kMaxNorm = 1.0 - 1e-5;   // (1-PROJ_EPS)/sqrt(c), c=1
constexpr double kMinNorm = 1e-15;
constexpr double kArtMax  = 6.1030338227611066;  // artanh(kMaxNorm)
#define kMaxNormF 0.99999f
#define kArtMaxF  6.1030338f
#define kOmMaxF   1.99999e-5f                    // 1 - kMaxNorm^2

typedef __attribute__((ext_vector_type(8))) short short8v;   // 8 bf16
typedef __attribute__((ext_vector_type(4))) float f32x4;

__device__ inline double wsum64(double v) {
#pragma unroll
  for (int o = 32; o > 0; o >>= 1) v += __shfl_xor(v, o, 64);
  return v;
}
__device__ inline float wsum32f(float v) {
#pragma unroll
  for (int o = 32; o > 0; o >>= 1) v += __shfl_xor(v, o, 64);
  return v;
}

__device__ inline double artanh_c(double x) {  // x >= 0
  x = fmin(x, 1.0 - 1e-7);
  return 0.5 * (log1p(x) - log1p(-x));
}

__device__ inline unsigned short f2bf(float f) {  // RN-even f32->bf16
  union { float f; unsigned int u; } v{f};
  unsigned int r = v.u + 0x7fffu + ((v.u >> 16) & 1u);
  return (unsigned short)(r >> 16);
}
__device__ inline float bf2f(unsigned short h) {
  union { unsigned int u; float f; } v{(unsigned int)h << 16};
  return v.f;
}

// ---- hb = proj(expmap0(bias)) ; outputs f32 (+ y2, 1-y2 scalars) -----------
__global__ __launch_bounds__(512) void k_bias(const float* __restrict__ b1,
                                              const float* __restrict__ b2,
                                              float* __restrict__ hb1,
                                              float* __restrict__ hb2,
                                              float* __restrict__ y21,
                                              float* __restrict__ y22,
                                              float* __restrict__ omy1,
                                              float* __restrict__ omy2) {
  int w = threadIdx.x >> 6, lane = threadIdx.x & 63;
  const float* bs = (w < 4) ? (b1 + w * 64) : (b2 + (w - 4) * 64);
  double v = (double)bs[lane];
  double un = fmax(sqrt(wsum64(v * v)), kMinNorm);
  double pn = tanh(un);
  double pf = pn > kMaxNorm ? kMaxNorm / pn : 1.0;
  double p = v * (pn / un) * pf;
  float* hb = (w < 4) ? hb1 + w * 64 : hb2 + (w - 4) * 64;
  hb[lane] = (float)p;
  if (lane == 0) {
    double n = pn * pf;
    int i = (w < 4) ? w : w - 4;
    float* y2 = (w < 4) ? y21 : y22;
    float* omy = (w < 4) ? omy1 : omy2;
    y2[i] = (float)(n * n);
    omy[i] = (float)(1.0 - n * n);
  }
}

// ---- weight prep: fragment-ready bf16 hi/lo, layout [s][b][f][lane][8] -----
__global__ __launch_bounds__(256) void k_wprep(const float* __restrict__ W,
                                               unsigned short* __restrict__ Wfh,
                                               unsigned short* __restrict__ Wfl,
                                               int DIN, int tot) {
  int idx = blockIdx.x * 256 + threadIdx.x;
  if (idx >= tot) return;
  int lane = idx & 63;
  int t = idx >> 6;
  int f = t & 3; t >>= 2;
  int ks = DIN >> 5;
  int s = t % ks;
  int b = t / ks;
  int c = f * 16 + (lane & 15);
  int k = s * 32 + (lane >> 4) * 8;
  const float* wp = W + ((size_t)(b * 64 + c)) * DIN + k;
  size_t dst = (((size_t)(s * 4 + b) * 4 + f) * 64 + lane) * 8;
#pragma unroll
  for (int j = 0; j < 8; ++j) {
    float v = wp[j];
    unsigned short h = f2bf(v);
    unsigned short l = f2bf(v - bf2f(h));
    Wfh[dst + j] = h;
    Wfl[dst + j] = l;
  }
}

// ---- layer-1 GEMM, all 4 branches batched, prescale fused (f64 prep) -------
__global__ __launch_bounds__(256) void k_gemm1(const float* __restrict__ X,
                                               const unsigned short* __restrict__ Wfh,
                                               const unsigned short* __restrict__ Wfl,
                                               float* __restrict__ C4,
                                               float* __restrict__ auxS,
                                               float* __restrict__ auxSa,
                                               int N) {
  const int wave = threadIdx.x >> 6, lane = threadIdx.x & 63;
  const int r0 = blockIdx.x * 64 + wave * 16;
  const int arow = min(r0 + (lane & 15), N - 1);
  const int kbase = (lane >> 4) * 8;
  f32x4 acc[4][4] = {};
  double ss = 0.0;
#pragma unroll
  for (int s = 0; s < 8; ++s) {
    const float* ap = X + (size_t)arow * 256 + s * 32 + kbase;
    const float4 a0 = *reinterpret_cast<const float4*>(ap);
    const float4 a1 = *reinterpret_cast<const float4*>(ap + 4);
    float av[8] = {a0.x, a0.y, a0.z, a0.w, a1.x, a1.y, a1.z, a1.w};
    short8v ah, al;
#pragma unroll
    for (int j = 0; j < 8; ++j) {
      ss += (double)av[j] * av[j];
      unsigned short h = f2bf(av[j]);
      ah[j] = (short)h;
      al[j] = (short)f2bf(av[j] - bf2f(h));
    }
#pragma unroll
    for (int bb = 0; bb < 4; ++bb)
#pragma unroll
      for (int f = 0; f < 4; ++f) {
        size_t wi = (((size_t)(s * 4 + bb) * 4 + f) * 64 + lane) * 8;
        short8v bh = *reinterpret_cast<const short8v*>(Wfh + wi);
        short8v bl = *reinterpret_cast<const short8v*>(Wfl + wi);
        acc[bb][f] = __builtin_amdgcn_mfma_f32_16x16x32_bf16(al, bl, acc[bb][f], 0, 0, 0);
        acc[bb][f] = __builtin_amdgcn_mfma_f32_16x16x32_bf16(ah, bl, acc[bb][f], 0, 0, 0);
        acc[bb][f] = __builtin_amdgcn_mfma_f32_16x16x32_bf16(al, bh, acc[bb][f], 0, 0, 0);
        acc[bb][f] = __builtin_amdgcn_mfma_f32_16x16x32_bf16(ah, bh, acc[bb][f], 0, 0, 0);
      }
  }
  // fused prescale: row sumsq = reduce over the 4 k-lane groups
  ss += __shfl_xor(ss, 16, 64);
  ss += __shfl_xor(ss, 32, 64);
  if (lane < 16) {
    int row = r0 + lane;
    if (row < N) {
      double un = fmax(sqrt(ss), kMinNorm);
      double pn = tanh(un);
      double pf = pn > kMaxNorm ? kMaxNorm / pn : 1.0;
      double xn = fmax(pn * pf, kMinNorm);
      auxS[row] = (float)((pn / un) * pf);
      auxSa[row] = (float)(fmin(un, kArtMax) / xn);  // artanh(xn)/xn exactly
    }
  }
  // C/D layout: col = lane&15, row = (lane>>4)*4 + j
  const int orow0 = r0 + (lane >> 4) * 4;
#pragma unroll
  for (int bb = 0; bb < 4; ++bb)
#pragma unroll
    for (int f = 0; f < 4; ++f)
#pragma unroll
      for (int j = 0; j < 4; ++j) {
        int row = orow0 + j;
        if (row < N)
          C4[((size_t)bb * N + row) * 64 + f * 16 + (lane & 15)] = acc[bb][f][j];
      }
}

// ---- layer-2 GEMM: per-branch (blockIdx.y), DIN=64 -------------------------
__global__ __launch_bounds__(256) void k_gemm2(const float* __restrict__ X4,
                                               const unsigned short* __restrict__ Wfh,
                                               const unsigned short* __restrict__ Wfl,
                                               float* __restrict__ C4, int N) {
  const int wave = threadIdx.x >> 6, lane = threadIdx.x & 63;
  const int b = blockIdx.y;
  const int r0 = blockIdx.x * 64 + wave * 16;
  const int arow = min(r0 + (lane & 15), N - 1);
  const int kbase = (lane >> 4) * 8;
  const float* X = X4 + (size_t)b * N * 64;
  f32x4 acc[4] = {};
#pragma unroll
  for (int s = 0; s < 2; ++s) {
    const float* ap = X + (size_t)arow * 64 + s * 32 + kbase;
    const float4 a0 = *reinterpret_cast<const float4*>(ap);
    const float4 a1 = *reinterpret_cast<const float4*>(ap + 4);
    float av[8] = {a0.x, a0.y, a0.z, a0.w, a1.x, a1.y, a1.z, a1.w};
    short8v ah, al;
#pragma unroll
    for (int j = 0; j < 8; ++j) {
      unsigned short h = f2bf(av[j]);
      ah[j] = (short)h;
      al[j] = (short)f2bf(av[j] - bf2f(h));
    }
#pragma unroll
    for (int f = 0; f < 4; ++f) {
      size_t wi = (((size_t)(s * 4 + b) * 4 + f) * 64 + lane) * 8;
      short8v bh = *reinterpret_cast<const short8v*>(Wfh + wi);
      short8v bl = *reinterpret_cast<const short8v*>(Wfl + wi);
      acc[f] = __builtin_amdgcn_mfma_f32_16x16x32_bf16(al, bl, acc[f], 0, 0, 0);
      acc[f] = __builtin_amdgcn_mfma_f32_16x16x32_bf16(ah, bl, acc[f], 0, 0, 0);
      acc[f] = __builtin_amdgcn_mfma_f32_16x16x32_bf16(al, bh, acc[f], 0, 0, 0);
      acc[f] = __builtin_amdgcn_mfma_f32_16x16x32_bf16(ah, bh, acc[f], 0, 0, 0);
    }
  }
  const int orow0 = r0 + (lane >> 4) * 4;
#pragma unroll
  for (int f = 0; f < 4; ++f)
#pragma unroll
    for (int j = 0; j < 4; ++j) {
      int row = orow0 + j;
      if (row < N)
        C4[((size_t)b * N + row) * 64 + f * 16 + (lane & 15)] = acc[f][j];
    }
}

// ---- f32 Mobius tail (stable forms), batched, IN-PLACE on C ----------------
// mx = s*dot -> mobius_matvec -> proj -> mobius_add(hb) -> proj -> logmap0
template <bool FIRST>
__global__ __launch_bounds__(256) void k_tail(float* __restrict__ C4,
                                              const float* __restrict__ a1,
                                              const float* __restrict__ a2,
                                              const float* __restrict__ hbAll,
                                              const float* __restrict__ y2All,
                                              const float* __restrict__ omyAll,
                                              int N) {
  int wave = threadIdx.x >> 6, lane = threadIdx.x & 63;
  int row = blockIdx.x * 4 + wave;
  if (row >= N) return;
  int b = blockIdx.y;
  size_t R = (size_t)b * N + row;
  float dot = C4[R * 64 + lane];
  float s, sart;
  if constexpr (FIRST) {
    s = a1[row];
    sart = a2[row];
  } else {
    s = 1.0f;
    float atn = a1[R];                        // artanh(|h_in|) exactly
    float xn = fmaxf(tanhf(atn), 1e-30f);
    sart = atn / xn;
  }
  float mx = s * dot;
  float mxn = fmaxf(sqrtf(wsum32f(mx * mx)), 1e-30f);
  float z = mxn * sart;
  // nmv = tanh(z), om = 1-tanh^2(z), both cancellation-free
  float e = __expf(-2.0f * z);
  float r1 = 1.0f / (1.0f + e);
  float nmv = (1.0f - e) * r1;
  float om = 4.0f * e * r1 * r1;
  float pf1 = nmv > kMaxNormF ? kMaxNormF / nmv : 1.0f;   // proj
  float nmvc = nmv * pf1;
  float x2 = nmvc * nmvc;
  float omx = (pf1 < 1.0f) ? kOmMaxF : om;                // 1 - x2, stable
  float mvscale = nmvc / mxn;
  float mv = mvscale * mx;
  // mobius_add(mv, hb): h = (A*mv + B*hb)/den
  float hbd = hbAll[b * 64 + lane];
  float y2 = y2All[b], omy = omyAll[b];
  float xy = wsum32f(mv * hbd);
  float A = 1.0f + 2.0f * xy + y2;
  float den = fmaxf(1.0f + 2.0f * xy + x2 * y2, 1e-15f);
  float rden = 1.0f / den;
  float h = (A * mv + omx * hbd) * rden;
  // norms via gyro-identities (no third reduction, no cancellation)
  float hn2 = (x2 + 2.0f * xy + y2) * rden;
  float omh = omx * omy * rden;                           // 1 - hn^2
  float hn = fmaxf(sqrtf(fmaxf(hn2, 0.0f)), 1e-30f);
  float pf2 = 1.0f;
  if (hn > kMaxNormF) {                                   // proj
    pf2 = kMaxNormF / hn;
    hn = kMaxNormF;
    omh = kOmMaxF;
  }
  // logmap0: artanh(hn)/hn * h ; artanh = 0.5*log((1+hn)^2/(1-hn^2))
  float art = 0.5f * __logf((1.0f + hn) * (1.0f + hn) / omh);
  float htscale = (art / hn) * pf2;
  C4[R * 64 + lane] = htscale * h;   // in-place (row-local)
}

// ------------------------- CSR build (all 4 branches flat) ------------------
__global__ __launch_bounds__(256) void k_hist(const int* __restrict__ dst,
                                              int* __restrict__ cnt4, int E,
                                              int N) {
  int e = blockIdx.x * 256 + threadIdx.x;
  int b = blockIdx.y;
  if (e < E) atomicAdd(&cnt4[b * N + dst[(size_t)b * E + e]], 1);
}

// exclusive scan, TILE=4096 per block (256 thr x 16 items)
__global__ __launch_bounds__(256) void k_scan1(const int* __restrict__ cnt,
                                               int* __restrict__ rp,
                                               int* __restrict__ bsum, int n) {
  __shared__ int wsums[4];
  int base = blockIdx.x * 4096;
  int t = threadIdx.x;
  int lane = t & 63, wv = t >> 6;
  int vals[16];
  int s = 0;
#pragma unroll
  for (int i = 0; i < 16; ++i) {
    int idx = base + t * 16 + i;
    int v = (idx < n) ? cnt[idx] : 0;
    vals[i] = s;
    s += v;
  }
  int incl = s;
#pragma unroll
  for (int o = 1; o < 64; o <<= 1) {
    int u = __shfl_up(incl, o, 64);
    if (lane >= o) incl += u;
  }
  if (lane == 63) wsums[wv] = incl;
  __syncthreads();
  int woff = 0;
  for (int i = 0; i < wv; ++i) woff += wsums[i];
  int texcl = woff + incl - s;
#pragma unroll
  for (int i = 0; i < 16; ++i) {
    int idx = base + t * 16 + i;
    if (idx < n) rp[idx] = texcl + vals[i];
  }
  if (t == 255) bsum[blockIdx.x] = woff + incl;
}

__global__ __launch_bounds__(64) void k_scan2(int* __restrict__ bsum, int nb) {
  int t = threadIdx.x;
  int v = (t < nb) ? bsum[t] : 0;
  int incl = v;
#pragma unroll
  for (int o = 1; o < 64; o <<= 1) {
    int u = __shfl_up(incl, o, 64);
    if (t >= o) incl += u;
  }
  if (t < nb) bsum[t] = incl - v;
}

__global__ __launch_bounds__(256) void k_scan3(int* __restrict__ rp,
                                               const int* __restrict__ bsum,
                                               int* __restrict__ cursor, int n,
                                               int Etot) {
  int i = blockIdx.x * 256 + threadIdx.x;
  if (i >= n) return;
  int v = rp[i] + bsum[i >> 12];
  rp[i] = v;
  cursor[i] = v;
  if (i == 0) rp[n] = Etot;
}

__global__ __launch_bounds__(256) void k_scatter(const int* __restrict__ src,
                                                 const int* __restrict__ dst,
                                                 const float* __restrict__ val,
                                                 int* __restrict__ cursor,
                                                 int2* __restrict__ pvedge,
                                                 int E, int N) {
  int e = blockIdx.x * 256 + threadIdx.x;
  if (e >= E) return;
  int b = blockIdx.y;
  size_t ge = (size_t)b * E + e;
  int d = dst[ge];
  int pos = atomicAdd(&cursor[b * N + d], 1);
  pvedge[pos] = make_int2(src[ge], __float_as_int(val[ge]));
}

// ---- gather SpMM + identity postagg (f32):
//  t = relu(acc*min(1,K/|acc|)); h2 = proj(expmap0(t)); aux = min(|t|,K) -----
__global__ __launch_bounds__(256) void k_spmm_post(
    const float* __restrict__ ht4, const int* __restrict__ rp4,
    const int2* __restrict__ pvedge, float* __restrict__ out4,
    float* __restrict__ aux4, int N) {
  int wave = threadIdx.x >> 6, lane = threadIdx.x & 63;
  int row = blockIdx.x * 4 + wave;
  if (row >= N) return;
  int b = blockIdx.y;
  size_t R = (size_t)b * N + row;
  const float* ht = ht4 + (size_t)b * N * 64;
  int beg = rp4[R], end = rp4[R + 1];
  float acc = 0.0f;
  for (int j0 = beg; j0 < end; j0 += 64) {
    int nj = min(64, end - j0);
    int2 ev = make_int2(0, 0);
    if (lane < nj) ev = pvedge[j0 + lane];
#pragma unroll 4
    for (int k = 0; k < nj; ++k) {
      int s = __shfl(ev.x, k, 64);
      float v = __int_as_float(__shfl(ev.y, k, 64));
      acc = fmaf(v, ht[(size_t)s * 64 + lane], acc);
    }
  }
  float an = fmaxf(sqrtf(wsum32f(acc * acc)), 1e-30f);
  float t = acc * (an > kArtMaxF ? kArtMaxF / an : 1.0f);
  t = fmaxf(t, 0.0f);  // relu in tangent space
  float tn = fmaxf(sqrtf(wsum32f(t * t)), 1e-30f);
  float h2n = tanhf(tn);
  float scale = fminf(h2n, kMaxNormF) / tn;   // expmap0 + proj
  out4[R * 64 + lane] = t * scale;
  if (lane == 0) aux4[R] = fminf(tn, kArtMaxF);  // artanh(|h2|) exactly
}

// ---- combine (f32, om-tracked mobius chain; aux = atn = artanh(|f|)) -------
__global__ __launch_bounds__(256) void k_combine(const float* __restrict__ F4,
                                                 const float* __restrict__ auxF4,
                                                 float* __restrict__ out, int N) {
  int wave = threadIdx.x >> 6, lane = threadIdx.x & 63;
  int row = blockIdx.x * 4 + wave;
  if (row >= N) return;
  float f[4], art[4], w[4], wn2[4], omw[4];
#pragma unroll
  for (int b = 0; b < 4; b++) {
    f[b] = F4[((size_t)b * N + row) * 64 + lane];
    float atn = auxF4[(size_t)b * N + row];
    art[b] = atn;
    float nb = fmaxf(tanhf(atn), 1e-30f);
    float wn = tanhf(atn * 0.125f);
    w[b] = (wn / nb) * f[b];
    wn2[b] = wn * wn;
    omw[b] = 1.0f - wn2[b];
  }
  float tgt = w[0], tx2 = wn2[0], omt = omw[0];
#pragma unroll
  for (int i = 1; i < 4; i++) {
    float xy = wsum32f(tgt * w[i]);
    float A = 1.f + 2.f * xy + wn2[i];
    float den = fmaxf(1.f + 2.f * xy + tx2 * wn2[i], 1e-15f);
    float rden = 1.0f / den;
    tgt = (A * tgt + omt * w[i]) * rden;     // B = 1 - tx2 = omt
    omt = omt * omw[i] * rden;               // 1-|tgt|^2, stable
    tx2 = 1.0f - omt;
  }
  float tn = fmaxf(sqrtf(fmaxf(tx2, 0.0f)), 1e-30f);
  float artt = 0.5f * __logf((1.f + tn) * (1.f + tn) / fmaxf(omt, 1e-30f));
  float m = (artt / tn) * tgt;
#pragma unroll
  for (int b = 0; b < 4; b++)
    m += (art[b] / fmaxf(tanhf(art[b]), 1e-30f)) * f[b];
  m *= 0.2f;
  float mn = fmaxf(sqrtf(wsum32f(m * m)), 1e-30f);
  float on = tanhf(mn);
  float pf = on > kMaxNormF ? kMaxNormF / on : 1.f;
  out[(size_t)row * 64 + lane] = m * (on / mn) * pf;
}

// ---------------------------------------------------------------------------
extern "C" void kernel_launch(void* const* d_in, const int* in_sizes, int n_in,
                              void* d_out, int out_size, void* d_ws,
                              size_t ws_size, hipStream_t stream) {
  const int FIN = 256, NB = 4;
  const int N = in_sizes[0] / FIN;       // 50000
  const int E = in_sizes[5] / NB;        // 800000
  const float* x = (const float*)d_in[0];
  const float* W1 = (const float*)d_in[1];
  const float* b1 = (const float*)d_in[2];
  const float* W2 = (const float*)d_in[3];
  const float* b2 = (const float*)d_in[4];
  const float* vals = (const float*)d_in[5];
  const int* src = (const int*)d_in[6];
  const int* dst = (const int*)d_in[7];
  float* out = (float*)d_out;
  const int n4 = NB * N;

  char* w = (char*)d_ws;
  auto alloc = [&](size_t bytes) -> char* {
    char* p = w;
    w += (bytes + 255) & ~size_t(255);
    return p;
  };
  const int WF1 = NB * (FIN / 32) * 4 * 64 * 8;   // 65536 ushorts
  const int WF2 = NB * (64 / 32) * 4 * 64 * 8;    // 16384 ushorts
  unsigned short* Wf1h = (unsigned short*)alloc((size_t)WF1 * 2);
  unsigned short* Wf1l = (unsigned short*)alloc((size_t)WF1 * 2);
  unsigned short* Wf2h = (unsigned short*)alloc((size_t)WF2 * 2);
  unsigned short* Wf2l = (unsigned short*)alloc((size_t)WF2 * 2);
  float* hb1 = (float*)alloc(NB * 64 * 4);
  float* hb2 = (float*)alloc(NB * 64 * 4);
  float* y21 = (float*)alloc(NB * 4);
  float* y22 = (float*)alloc(NB * 4);
  float* omy1 = (float*)alloc(NB * 4);
  float* omy2 = (float*)alloc(NB * 4);
  float* auxS = (float*)alloc((size_t)N * 4);
  float* auxSa = (float*)alloc((size_t)N * 4);
  float* auxT4 = (float*)alloc((size_t)n4 * 4);
  float* auxF4 = (float*)alloc((size_t)n4 * 4);
  float* Cb4 = (float*)alloc((size_t)n4 * 64 * 4);   // gemm out / tail inplace
  float* A4 = (float*)alloc((size_t)n4 * 64 * 4);    // spmm out
  int* cnt4 = (int*)alloc((size_t)n4 * 4);           // hist, then cursor
  int* rp4 = (int*)alloc(((size_t)n4 + 1) * 4);
  int* bsum = (int*)alloc(64 * 4);
  int2* pvedge = (int2*)alloc((size_t)NB * E * 8);

  const int rowBlocks = (N + 3) / 4;
  const int gemmBlocks = (N + 63) / 64;
  const int eBlocks = (E + 255) / 256;
  const int scanBlocks = (n4 + 4095) / 4096;   // 49

  k_wprep<<<(WF1 / 8 + 255) / 256, 256, 0, stream>>>(W1, Wf1h, Wf1l, FIN, WF1 / 8);
  k_wprep<<<(WF2 / 8 + 255) / 256, 256, 0, stream>>>(W2, Wf2h, Wf2l, 64, WF2 / 8);
  k_bias<<<1, 512, 0, stream>>>(b1, b2, hb1, hb2, y21, y22, omy1, omy2);

  // ---- batched CSR over all 4 branches ----
  hipMemsetAsync(cnt4, 0, (size_t)n4 * 4, stream);
  k_hist<<<dim3(eBlocks, NB), 256, 0, stream>>>(dst, cnt4, E, N);
  k_scan1<<<scanBlocks, 256, 0, stream>>>(cnt4, rp4, bsum, n4);
  k_scan2<<<1, 64, 0, stream>>>(bsum, scanBlocks);
  k_scan3<<<(n4 + 255) / 256, 256, 0, stream>>>(rp4, bsum, cnt4, n4, NB * E);
  k_scatter<<<dim3(eBlocks, NB), 256, 0, stream>>>(src, dst, vals, cnt4, pvedge, E, N);

  // ---- layer 1 (batched) ----
  k_gemm1<<<gemmBlocks, 256, 0, stream>>>(x, Wf1h, Wf1l, Cb4, auxS, auxSa, N);
  k_tail<true><<<dim3(rowBlocks, NB), 256, 0, stream>>>(Cb4, auxS, auxSa, hb1, y21, omy1, N);
  k_spmm_post<<<dim3(rowBlocks, NB), 256, 0, stream>>>(Cb4, rp4, pvedge, A4, auxT4, N);
  // ---- layer 2 (batched) ----
  k_gemm2<<<dim3(gemmBlocks, NB), 256, 0, stream>>>(A4, Wf2h, Wf2l, Cb4, N);
  k_tail<false><<<dim3(rowBlocks, NB), 256, 0, stream>>>(Cb4, auxT4, nullptr, hb2, y22, omy2, N);
  k_spmm_post<<<dim3(rowBlocks, NB), 256, 0, stream>>>(Cb4, rp4, pvedge, A4, auxF4, N);

  k_combine<<<rowBlocks, 256, 0, stream>>>(A4, auxF4, out, N);
}

// Round 6
// 740.979 us; speedup vs baseline: 10.8567x; 1.4159x over previous
//
#include <hip/hip_runtime.h>
#include <math.h>

// ---------------------------------------------------------------------------
// DHYPR hyperbolic GNN encoder, MI355X (gfx950).  Round 6: CSR build rebuilt
// as a two-level bucketed counting sort (buckets of 128 dst nodes):
//   A) k_bhist : LDS-aggregated bucket histogram (153K atomics, not 3.2M)
//   B) k_bpart : block partition into buckets; ~21-edge runs -> ~1.3x line
//      inflation on writes (was 8x in the old random scatter)
//   C) k_bfine : per-bucket fine CSR + permute inside a contiguous ~16KB
//      region (XCD-L2-local, full-line writebacks)
// Mobius math unchanged from round 5 (f32 gyro-stable forms).
// ---------------------------------------------------------------------------

constexpr double kMaxNorm = 1.0 - 1e-5;   // (1-PROJ_EPS)/sqrt(c), c=1
constexpr double kMinNorm = 1e-15;
constexpr double kArtMax  = 6.1030338227611066;  // artanh(kMaxNorm)
#define kMaxNormF 0.99999f
#define kArtMaxF  6.1030338f
#define kOmMaxF   1.99999e-5f                    // 1 - kMaxNorm^2

typedef __attribute__((ext_vector_type(8))) short short8v;   // 8 bf16
typedef __attribute__((ext_vector_type(4))) float f32x4;

__device__ inline double wsum64(double v) {
#pragma unroll
  for (int o = 32; o > 0; o >>= 1) v += __shfl_xor(v, o, 64);
  return v;
}
__device__ inline float wsum32f(float v) {
#pragma unroll
  for (int o = 32; o > 0; o >>= 1) v += __shfl_xor(v, o, 64);
  return v;
}

__device__ inline unsigned short f2bf(float f) {  // RN-even f32->bf16
  union { float f; unsigned int u; } v{f};
  unsigned int r = v.u + 0x7fffu + ((v.u >> 16) & 1u);
  return (unsigned short)(r >> 16);
}
__device__ inline float bf2f(unsigned short h) {
  union { unsigned int u; float f; } v{(unsigned int)h << 16};
  return v.f;
}

// ---- hb = proj(expmap0(bias)) ; outputs f32 (+ y2, 1-y2 scalars) -----------
__global__ __launch_bounds__(512) void k_bias(const float* __restrict__ b1,
                                              const float* __restrict__ b2,
                                              float* __restrict__ hb1,
                                              float* __restrict__ hb2,
                                              float* __restrict__ y21,
                                              float* __restrict__ y22,
                                              float* __restrict__ omy1,
                                              float* __restrict__ omy2) {
  int w = threadIdx.x >> 6, lane = threadIdx.x & 63;
  const float* bs = (w < 4) ? (b1 + w * 64) : (b2 + (w - 4) * 64);
  double v = (double)bs[lane];
  double un = fmax(sqrt(wsum64(v * v)), kMinNorm);
  double pn = tanh(un);
  double pf = pn > kMaxNorm ? kMaxNorm / pn : 1.0;
  double p = v * (pn / un) * pf;
  float* hb = (w < 4) ? hb1 + w * 64 : hb2 + (w - 4) * 64;
  hb[lane] = (float)p;
  if (lane == 0) {
    double n = pn * pf;
    int i = (w < 4) ? w : w - 4;
    float* y2 = (w < 4) ? y21 : y22;
    float* omy = (w < 4) ? omy1 : omy2;
    y2[i] = (float)(n * n);
    omy[i] = (float)(1.0 - n * n);
  }
}

// ---- weight prep: fragment-ready bf16 hi/lo, layout [s][b][f][lane][8] -----
__global__ __launch_bounds__(256) void k_wprep(const float* __restrict__ W,
                                               unsigned short* __restrict__ Wfh,
                                               unsigned short* __restrict__ Wfl,
                                               int DIN, int tot) {
  int idx = blockIdx.x * 256 + threadIdx.x;
  if (idx >= tot) return;
  int lane = idx & 63;
  int t = idx >> 6;
  int f = t & 3; t >>= 2;
  int ks = DIN >> 5;
  int s = t % ks;
  int b = t / ks;
  int c = f * 16 + (lane & 15);
  int k = s * 32 + (lane >> 4) * 8;
  const float* wp = W + ((size_t)(b * 64 + c)) * DIN + k;
  size_t dst = (((size_t)(s * 4 + b) * 4 + f) * 64 + lane) * 8;
#pragma unroll
  for (int j = 0; j < 8; ++j) {
    float v = wp[j];
    unsigned short h = f2bf(v);
    unsigned short l = f2bf(v - bf2f(h));
    Wfh[dst + j] = h;
    Wfl[dst + j] = l;
  }
}

// ---- layer-1 GEMM, all 4 branches batched, prescale fused (f64 prep) -------
__global__ __launch_bounds__(256) void k_gemm1(const float* __restrict__ X,
                                               const unsigned short* __restrict__ Wfh,
                                               const unsigned short* __restrict__ Wfl,
                                               float* __restrict__ C4,
                                               float* __restrict__ auxS,
                                               float* __restrict__ auxSa,
                                               int N) {
  const int wave = threadIdx.x >> 6, lane = threadIdx.x & 63;
  const int r0 = blockIdx.x * 64 + wave * 16;
  const int arow = min(r0 + (lane & 15), N - 1);
  const int kbase = (lane >> 4) * 8;
  f32x4 acc[4][4] = {};
  double ss = 0.0;
#pragma unroll
  for (int s = 0; s < 8; ++s) {
    const float* ap = X + (size_t)arow * 256 + s * 32 + kbase;
    const float4 a0 = *reinterpret_cast<const float4*>(ap);
    const float4 a1 = *reinterpret_cast<const float4*>(ap + 4);
    float av[8] = {a0.x, a0.y, a0.z, a0.w, a1.x, a1.y, a1.z, a1.w};
    short8v ah, al;
#pragma unroll
    for (int j = 0; j < 8; ++j) {
      ss += (double)av[j] * av[j];
      unsigned short h = f2bf(av[j]);
      ah[j] = (short)h;
      al[j] = (short)f2bf(av[j] - bf2f(h));
    }
#pragma unroll
    for (int bb = 0; bb < 4; ++bb)
#pragma unroll
      for (int f = 0; f < 4; ++f) {
        size_t wi = (((size_t)(s * 4 + bb) * 4 + f) * 64 + lane) * 8;
        short8v bh = *reinterpret_cast<const short8v*>(Wfh + wi);
        short8v bl = *reinterpret_cast<const short8v*>(Wfl + wi);
        acc[bb][f] = __builtin_amdgcn_mfma_f32_16x16x32_bf16(al, bl, acc[bb][f], 0, 0, 0);
        acc[bb][f] = __builtin_amdgcn_mfma_f32_16x16x32_bf16(ah, bl, acc[bb][f], 0, 0, 0);
        acc[bb][f] = __builtin_amdgcn_mfma_f32_16x16x32_bf16(al, bh, acc[bb][f], 0, 0, 0);
        acc[bb][f] = __builtin_amdgcn_mfma_f32_16x16x32_bf16(ah, bh, acc[bb][f], 0, 0, 0);
      }
  }
  // fused prescale: row sumsq = reduce over the 4 k-lane groups
  ss += __shfl_xor(ss, 16, 64);
  ss += __shfl_xor(ss, 32, 64);
  if (lane < 16) {
    int row = r0 + lane;
    if (row < N) {
      double un = fmax(sqrt(ss), kMinNorm);
      double pn = tanh(un);
      double pf = pn > kMaxNorm ? kMaxNorm / pn : 1.0;
      double xn = fmax(pn * pf, kMinNorm);
      auxS[row] = (float)((pn / un) * pf);
      auxSa[row] = (float)(fmin(un, kArtMax) / xn);  // artanh(xn)/xn exactly
    }
  }
  // C/D layout: col = lane&15, row = (lane>>4)*4 + j
  const int orow0 = r0 + (lane >> 4) * 4;
#pragma unroll
  for (int bb = 0; bb < 4; ++bb)
#pragma unroll
    for (int f = 0; f < 4; ++f)
#pragma unroll
      for (int j = 0; j < 4; ++j) {
        int row = orow0 + j;
        if (row < N)
          C4[((size_t)bb * N + row) * 64 + f * 16 + (lane & 15)] = acc[bb][f][j];
      }
}

// ---- layer-2 GEMM: per-branch (blockIdx.y), DIN=64 -------------------------
__global__ __launch_bounds__(256) void k_gemm2(const float* __restrict__ X4,
                                               const unsigned short* __restrict__ Wfh,
                                               const unsigned short* __restrict__ Wfl,
                                               float* __restrict__ C4, int N) {
  const int wave = threadIdx.x >> 6, lane = threadIdx.x & 63;
  const int b = blockIdx.y;
  const int r0 = blockIdx.x * 64 + wave * 16;
  const int arow = min(r0 + (lane & 15), N - 1);
  const int kbase = (lane >> 4) * 8;
  const float* X = X4 + (size_t)b * N * 64;
  f32x4 acc[4] = {};
#pragma unroll
  for (int s = 0; s < 2; ++s) {
    const float* ap = X + (size_t)arow * 64 + s * 32 + kbase;
    const float4 a0 = *reinterpret_cast<const float4*>(ap);
    const float4 a1 = *reinterpret_cast<const float4*>(ap + 4);
    float av[8] = {a0.x, a0.y, a0.z, a0.w, a1.x, a1.y, a1.z, a1.w};
    short8v ah, al;
#pragma unroll
    for (int j = 0; j < 8; ++j) {
      unsigned short h = f2bf(av[j]);
      ah[j] = (short)h;
      al[j] = (short)f2bf(av[j] - bf2f(h));
    }
#pragma unroll
    for (int f = 0; f < 4; ++f) {
      size_t wi = (((size_t)(s * 4 + b) * 4 + f) * 64 + lane) * 8;
      short8v bh = *reinterpret_cast<const short8v*>(Wfh + wi);
      short8v bl = *reinterpret_cast<const short8v*>(Wfl + wi);
      acc[f] = __builtin_amdgcn_mfma_f32_16x16x32_bf16(al, bl, acc[f], 0, 0, 0);
      acc[f] = __builtin_amdgcn_mfma_f32_16x16x32_bf16(ah, bl, acc[f], 0, 0, 0);
      acc[f] = __builtin_amdgcn_mfma_f32_16x16x32_bf16(al, bh, acc[f], 0, 0, 0);
      acc[f] = __builtin_amdgcn_mfma_f32_16x16x32_bf16(ah, bh, acc[f], 0, 0, 0);
    }
  }
  const int orow0 = r0 + (lane >> 4) * 4;
#pragma unroll
  for (int f = 0; f < 4; ++f)
#pragma unroll
    for (int j = 0; j < 4; ++j) {
      int row = orow0 + j;
      if (row < N)
        C4[((size_t)b * N + row) * 64 + f * 16 + (lane & 15)] = acc[f][j];
    }
}

// ---- f32 Mobius tail (stable forms), batched, IN-PLACE on C ----------------
template <bool FIRST>
__global__ __launch_bounds__(256) void k_tail(float* __restrict__ C4,
                                              const float* __restrict__ a1,
                                              const float* __restrict__ a2,
                                              const float* __restrict__ hbAll,
                                              const float* __restrict__ y2All,
                                              const float* __restrict__ omyAll,
                                              int N) {
  int wave = threadIdx.x >> 6, lane = threadIdx.x & 63;
  int row = blockIdx.x * 4 + wave;
  if (row >= N) return;
  int b = blockIdx.y;
  size_t R = (size_t)b * N + row;
  float dot = C4[R * 64 + lane];
  float s, sart;
  if constexpr (FIRST) {
    s = a1[row];
    sart = a2[row];
  } else {
    s = 1.0f;
    float atn = a1[R];                        // artanh(|h_in|) exactly
    float xn = fmaxf(tanhf(atn), 1e-30f);
    sart = atn / xn;
  }
  float mx = s * dot;
  float mxn = fmaxf(sqrtf(wsum32f(mx * mx)), 1e-30f);
  float z = mxn * sart;
  float e = __expf(-2.0f * z);
  float r1 = 1.0f / (1.0f + e);
  float nmv = (1.0f - e) * r1;
  float om = 4.0f * e * r1 * r1;
  float pf1 = nmv > kMaxNormF ? kMaxNormF / nmv : 1.0f;   // proj
  float nmvc = nmv * pf1;
  float x2 = nmvc * nmvc;
  float omx = (pf1 < 1.0f) ? kOmMaxF : om;                // 1 - x2, stable
  float mvscale = nmvc / mxn;
  float mv = mvscale * mx;
  float hbd = hbAll[b * 64 + lane];
  float y2 = y2All[b], omy = omyAll[b];
  float xy = wsum32f(mv * hbd);
  float A = 1.0f + 2.0f * xy + y2;
  float den = fmaxf(1.0f + 2.0f * xy + x2 * y2, 1e-15f);
  float rden = 1.0f / den;
  float h = (A * mv + omx * hbd) * rden;
  float hn2 = (x2 + 2.0f * xy + y2) * rden;
  float omh = omx * omy * rden;                           // 1 - hn^2
  float hn = fmaxf(sqrtf(fmaxf(hn2, 0.0f)), 1e-30f);
  float pf2 = 1.0f;
  if (hn > kMaxNormF) {                                   // proj
    pf2 = kMaxNormF / hn;
    hn = kMaxNormF;
    omh = kOmMaxF;
  }
  float art = 0.5f * __logf((1.0f + hn) * (1.0f + hn) / omh);
  float htscale = (art / hn) * pf2;
  C4[R * 64 + lane] = htscale * h;   // in-place (row-local)
}

// ===================== CSR build: bucketed counting sort ====================
// bucket = dst >> 7 (128 nodes); nbuck per branch; buckets branch-major.

// A) bucket histogram, LDS-aggregated.  grid (ceil(E/8192), NB) x 512
__global__ __launch_bounds__(512) void k_bhist(const int* __restrict__ dst,
                                               int* __restrict__ bcnt, int E,
                                               int nbuck) {
  __shared__ int lcnt[512];
  int tid = threadIdx.x;
  for (int k = tid; k < nbuck; k += 512) lcnt[k] = 0;
  __syncthreads();
  int b = blockIdx.y;
  int e0 = blockIdx.x * 8192;
  const int* db = dst + (size_t)b * E;
#pragma unroll
  for (int i = 0; i < 16; ++i) {
    int e = e0 + i * 512 + tid;
    if (e < E) atomicAdd(&lcnt[db[e] >> 7], 1);
  }
  __syncthreads();
  for (int k = tid; k < nbuck; k += 512) {
    int c = lcnt[k];
    if (c) atomicAdd(&bcnt[b * nbuck + k], c);
  }
}

// A2) single-block exclusive scan of bcnt[TB] -> boff, bcur; sentinels.
__global__ __launch_bounds__(256) void k_bscan(const int* __restrict__ bcnt,
                                               int* __restrict__ boff,
                                               int* __restrict__ bcur,
                                               int* __restrict__ rp4, int TB,
                                               int n4, int Etot) {
  __shared__ int wsums[4];
  int t = threadIdx.x;
  int lane = t & 63, wv = t >> 6;
  int vals[8];
  int s = 0;
#pragma unroll
  for (int i = 0; i < 8; ++i) {
    int idx = t * 8 + i;
    int v = (idx < TB) ? bcnt[idx] : 0;
    vals[i] = s;
    s += v;
  }
  int incl = s;
#pragma unroll
  for (int o = 1; o < 64; o <<= 1) {
    int u = __shfl_up(incl, o, 64);
    if (lane >= o) incl += u;
  }
  if (lane == 63) wsums[wv] = incl;
  __syncthreads();
  int woff = 0;
  for (int i = 0; i < wv; ++i) woff += wsums[i];
  int texcl = woff + incl - s;
#pragma unroll
  for (int i = 0; i < 8; ++i) {
    int idx = t * 8 + i;
    if (idx < TB) {
      int o = texcl + vals[i];
      boff[idx] = o;
      bcur[idx] = o;
    }
  }
  if (t == 0) {
    boff[TB] = Etot;
    rp4[n4] = Etot;
  }
}

// B) partition edges into buckets. grid (ceil(E/8192), NB) x 512.
//    pack: .x = (dstLow7 << 17) | src  (src < 2^17), .y = val bits
__global__ __launch_bounds__(512) void k_bpart(const int* __restrict__ src,
                                               const int* __restrict__ dst,
                                               const float* __restrict__ val,
                                               int* __restrict__ bcur,
                                               int2* __restrict__ ebuf, int E,
                                               int nbuck) {
  __shared__ int lcnt[512];
  __shared__ int lbase[512];
  int tid = threadIdx.x;
  for (int k = tid; k < nbuck; k += 512) lcnt[k] = 0;
  __syncthreads();
  int b = blockIdx.y;
  int e0 = blockIdx.x * 8192;
  const int* db = dst + (size_t)b * E;
  const int* sb = src + (size_t)b * E;
  const float* vb = val + (size_t)b * E;
#pragma unroll
  for (int i = 0; i < 16; ++i) {
    int e = e0 + i * 512 + tid;
    if (e < E) atomicAdd(&lcnt[db[e] >> 7], 1);
  }
  __syncthreads();
  for (int k = tid; k < nbuck; k += 512) {
    int c = lcnt[k];
    lbase[k] = c ? atomicAdd(&bcur[b * nbuck + k], c) : 0;
  }
  __syncthreads();
  for (int k = tid; k < nbuck; k += 512) lcnt[k] = 0;
  __syncthreads();
#pragma unroll
  for (int i = 0; i < 16; ++i) {
    int e = e0 + i * 512 + tid;
    if (e < E) {
      int d = db[e];
      int bk = d >> 7;
      int r = atomicAdd(&lcnt[bk], 1);
      int2 ev;
      ev.x = ((d & 127) << 17) | sb[e];
      ev.y = __float_as_int(vb[e]);
      ebuf[(size_t)lbase[bk] + r] = ev;
    }
  }
}

// C) per-bucket fine CSR + permute (contiguous ~16KB region, L2-local).
//    grid (nbuck, NB) x 256
__global__ __launch_bounds__(256) void k_bfine(const int2* __restrict__ ebuf,
                                               const int* __restrict__ boff,
                                               int* __restrict__ rp4,
                                               int2* __restrict__ pvedge,
                                               int N, int nbuck) {
  __shared__ int ncnt[128], noff[128], ncur[128];
  __shared__ int w0tot;
  int tid = threadIdx.x;
  int br = blockIdx.y, bk = blockIdx.x;
  int idx = br * nbuck + bk;
  int ebeg = boff[idx], eend = boff[idx + 1];
  int n0 = bk << 7;
  int nn = min(128, N - n0);
  if (tid < 128) ncnt[tid] = 0;
  __syncthreads();
  for (int j = ebeg + tid; j < eend; j += 256)
    atomicAdd(&ncnt[ebuf[j].x >> 17], 1);
  __syncthreads();
  // exclusive scan of ncnt[0..127] (2 waves)
  int v = (tid < 128) ? ncnt[tid] : 0;
  int lane = tid & 63;
  int incl = v;
#pragma unroll
  for (int o = 1; o < 64; o <<= 1) {
    int u = __shfl_up(incl, o, 64);
    if (lane >= o) incl += u;
  }
  if (tid == 63) w0tot = incl;
  __syncthreads();
  if (tid >= 64 && tid < 128) incl += w0tot;
  if (tid < 128) {
    noff[tid] = incl - v;
    ncur[tid] = incl - v;
  }
  __syncthreads();
  if (tid < nn) rp4[(size_t)br * N + n0 + tid] = ebeg + noff[tid];
  for (int j = ebeg + tid; j < eend; j += 256) {
    int2 ev = ebuf[j];
    int dl = ev.x >> 17;
    int pos = ebeg + atomicAdd(&ncur[dl], 1);
    pvedge[pos] = make_int2(ev.x & 0x1FFFF, ev.y);
  }
}

// ---- gather SpMM + identity postagg (f32) ----------------------------------
__global__ __launch_bounds__(256) void k_spmm_post(
    const float* __restrict__ ht4, const int* __restrict__ rp4,
    const int2* __restrict__ pvedge, float* __restrict__ out4,
    float* __restrict__ aux4, int N) {
  int wave = threadIdx.x >> 6, lane = threadIdx.x & 63;
  int row = blockIdx.x * 4 + wave;
  if (row >= N) return;
  int b = blockIdx.y;
  size_t R = (size_t)b * N + row;
  const float* ht = ht4 + (size_t)b * N * 64;
  int beg = rp4[R], end = rp4[R + 1];
  float acc = 0.0f;
  for (int j0 = beg; j0 < end; j0 += 64) {
    int nj = min(64, end - j0);
    int2 ev = make_int2(0, 0);
    if (lane < nj) ev = pvedge[j0 + lane];
#pragma unroll 4
    for (int k = 0; k < nj; ++k) {
      int s = __shfl(ev.x, k, 64);
      float v = __int_as_float(__shfl(ev.y, k, 64));
      acc = fmaf(v, ht[(size_t)s * 64 + lane], acc);
    }
  }
  float an = fmaxf(sqrtf(wsum32f(acc * acc)), 1e-30f);
  float t = acc * (an > kArtMaxF ? kArtMaxF / an : 1.0f);
  t = fmaxf(t, 0.0f);  // relu in tangent space
  float tn = fmaxf(sqrtf(wsum32f(t * t)), 1e-30f);
  float h2n = tanhf(tn);
  float scale = fminf(h2n, kMaxNormF) / tn;   // expmap0 + proj
  out4[R * 64 + lane] = t * scale;
  if (lane == 0) aux4[R] = fminf(tn, kArtMaxF);  // artanh(|h2|) exactly
}

// ---- combine (f32, om-tracked mobius chain; aux = atn = artanh(|f|)) -------
__global__ __launch_bounds__(256) void k_combine(const float* __restrict__ F4,
                                                 const float* __restrict__ auxF4,
                                                 float* __restrict__ out, int N) {
  int wave = threadIdx.x >> 6, lane = threadIdx.x & 63;
  int row = blockIdx.x * 4 + wave;
  if (row >= N) return;
  float f[4], art[4], w[4], wn2[4], omw[4];
#pragma unroll
  for (int b = 0; b < 4; b++) {
    f[b] = F4[((size_t)b * N + row) * 64 + lane];
    float atn = auxF4[(size_t)b * N + row];
    art[b] = atn;
    float nb = fmaxf(tanhf(atn), 1e-30f);
    float wn = tanhf(atn * 0.125f);
    w[b] = (wn / nb) * f[b];
    wn2[b] = wn * wn;
    omw[b] = 1.0f - wn2[b];
  }
  float tgt = w[0], tx2 = wn2[0], omt = omw[0];
#pragma unroll
  for (int i = 1; i < 4; i++) {
    float xy = wsum32f(tgt * w[i]);
    float A = 1.f + 2.f * xy + wn2[i];
    float den = fmaxf(1.f + 2.f * xy + tx2 * wn2[i], 1e-15f);
    float rden = 1.0f / den;
    tgt = (A * tgt + omt * w[i]) * rden;
    omt = omt * omw[i] * rden;               // 1-|tgt|^2, stable
    tx2 = 1.0f - omt;
  }
  float tn = fmaxf(sqrtf(fmaxf(tx2, 0.0f)), 1e-30f);
  float artt = 0.5f * __logf((1.f + tn) * (1.f + tn) / fmaxf(omt, 1e-30f));
  float m = (artt / tn) * tgt;
#pragma unroll
  for (int b = 0; b < 4; b++)
    m += (art[b] / fmaxf(tanhf(art[b]), 1e-30f)) * f[b];
  m *= 0.2f;
  float mn = fmaxf(sqrtf(wsum32f(m * m)), 1e-30f);
  float on = tanhf(mn);
  float pf = on > kMaxNormF ? kMaxNormF / on : 1.f;
  out[(size_t)row * 64 + lane] = m * (on / mn) * pf;
}

// ---------------------------------------------------------------------------
extern "C" void kernel_launch(void* const* d_in, const int* in_sizes, int n_in,
                              void* d_out, int out_size, void* d_ws,
                              size_t ws_size, hipStream_t stream) {
  const int FIN = 256, NB = 4;
  const int N = in_sizes[0] / FIN;       // 50000
  const int E = in_sizes[5] / NB;        // 800000
  const float* x = (const float*)d_in[0];
  const float* W1 = (const float*)d_in[1];
  const float* b1 = (const float*)d_in[2];
  const float* W2 = (const float*)d_in[3];
  const float* b2 = (const float*)d_in[4];
  const float* vals = (const float*)d_in[5];
  const int* src = (const int*)d_in[6];
  const int* dst = (const int*)d_in[7];
  float* out = (float*)d_out;
  const int n4 = NB * N;
  const int nbuck = (N + 127) >> 7;      // 391
  const int TB = NB * nbuck;

  char* w = (char*)d_ws;
  auto alloc = [&](size_t bytes) -> char* {
    char* p = w;
    w += (bytes + 255) & ~size_t(255);
    return p;
  };
  const int WF1 = NB * (FIN / 32) * 4 * 64 * 8;   // 65536 ushorts
  const int WF2 = NB * (64 / 32) * 4 * 64 * 8;    // 16384 ushorts
  unsigned short* Wf1h = (unsigned short*)alloc((size_t)WF1 * 2);
  unsigned short* Wf1l = (unsigned short*)alloc((size_t)WF1 * 2);
  unsigned short* Wf2h = (unsigned short*)alloc((size_t)WF2 * 2);
  unsigned short* Wf2l = (unsigned short*)alloc((size_t)WF2 * 2);
  float* hb1 = (float*)alloc(NB * 64 * 4);
  float* hb2 = (float*)alloc(NB * 64 * 4);
  float* y21 = (float*)alloc(NB * 4);
  float* y22 = (float*)alloc(NB * 4);
  float* omy1 = (float*)alloc(NB * 4);
  float* omy2 = (float*)alloc(NB * 4);
  float* auxS = (float*)alloc((size_t)N * 4);
  float* auxSa = (float*)alloc((size_t)N * 4);
  float* auxT4 = (float*)alloc((size_t)n4 * 4);
  float* auxF4 = (float*)alloc((size_t)n4 * 4);
  float* Cb4 = (float*)alloc((size_t)n4 * 64 * 4);   // gemm out / tail inplace
  float* A4 = (float*)alloc((size_t)n4 * 64 * 4);    // spmm out
  int* bcnt = (int*)alloc((size_t)TB * 4);
  int* boff = (int*)alloc(((size_t)TB + 1) * 4);
  int* bcur = (int*)alloc((size_t)TB * 4);
  int* rp4 = (int*)alloc(((size_t)n4 + 1) * 4);
  int2* pvedge = (int2*)alloc((size_t)NB * E * 8);
  // ebuf aliases Cb4 (dead until k_gemm1; 25.6MB <= 51.2MB)
  int2* ebuf = (int2*)Cb4;

  const int rowBlocks = (N + 3) / 4;
  const int gemmBlocks = (N + 63) / 64;
  const int hBlocks = (E + 8191) / 8192;   // 98

  k_wprep<<<(WF1 / 8 + 255) / 256, 256, 0, stream>>>(W1, Wf1h, Wf1l, FIN, WF1 / 8);
  k_wprep<<<(WF2 / 8 + 255) / 256, 256, 0, stream>>>(W2, Wf2h, Wf2l, 64, WF2 / 8);
  k_bias<<<1, 512, 0, stream>>>(b1, b2, hb1, hb2, y21, y22, omy1, omy2);

  // ---- CSR build: bucketed counting sort over all 4 branches ----
  hipMemsetAsync(bcnt, 0, (size_t)TB * 4, stream);
  k_bhist<<<dim3(hBlocks, NB), 512, 0, stream>>>(dst, bcnt, E, nbuck);
  k_bscan<<<1, 256, 0, stream>>>(bcnt, boff, bcur, rp4, TB, n4, NB * E);
  k_bpart<<<dim3(hBlocks, NB), 512, 0, stream>>>(src, dst, vals, bcur, ebuf, E, nbuck);
  k_bfine<<<dim3(nbuck, NB), 256, 0, stream>>>(ebuf, boff, rp4, pvedge, N, nbuck);

  // ---- layer 1 (batched) ----
  k_gemm1<<<gemmBlocks, 256, 0, stream>>>(x, Wf1h, Wf1l, Cb4, auxS, auxSa, N);
  k_tail<true><<<dim3(rowBlocks, NB), 256, 0, stream>>>(Cb4, auxS, auxSa, hb1, y21, omy1, N);
  k_spmm_post<<<dim3(rowBlocks, NB), 256, 0, stream>>>(Cb4, rp4, pvedge, A4, auxT4, N);
  // ---- layer 2 (batched) ----
  k_gemm2<<<dim3(gemmBlocks, NB), 256, 0, stream>>>(A4, Wf2h, Wf2l, Cb4, N);
  k_tail<false><<<dim3(rowBlocks, NB), 256, 0, stream>>>(Cb4, auxT4, nullptr, hb2, y22, omy2, N);
  k_spmm_post<<<dim3(rowBlocks, NB), 256, 0, stream>>>(Cb4, rp4, pvedge, A4, auxF4, N);

  k_combine<<<rowBlocks, 256, 0, stream>>>(A4, auxF4, out, N);
}

// Round 7
// 559.855 us; speedup vs baseline: 14.3691x; 1.3235x over previous
//
#include <hip/hip_runtime.h>
#include <math.h>

// ---------------------------------------------------------------------------
// DHYPR hyperbolic GNN encoder, MI355X (gfx950).  Round 7:
//  - SpMM gather loop: wave-uniform SCALAR edge loads (s_load via
//    readfirstlane'd loop bounds) replace 2x ds_bpermute per edge; unroll 4
//    -> 4 row-gathers in flight per wave.
//  - layer-2 SpMM fused with combine: one block per row, wave=branch, LDS
//    exchange; kills one dispatch + ~115MB of intermediate traffic.
// CSR bucketed sort + f32 gyro-stable Mobius math unchanged from round 6.
// ---------------------------------------------------------------------------

constexpr double kMaxNorm = 1.0 - 1e-5;   // (1-PROJ_EPS)/sqrt(c), c=1
constexpr double kMinNorm = 1e-15;
constexpr double kArtMax  = 6.1030338227611066;  // artanh(kMaxNorm)
#define kMaxNormF 0.99999f
#define kArtMaxF  6.1030338f
#define kOmMaxF   1.99999e-5f                    // 1 - kMaxNorm^2

typedef __attribute__((ext_vector_type(8))) short short8v;   // 8 bf16
typedef __attribute__((ext_vector_type(4))) float f32x4;

__device__ inline double wsum64(double v) {
#pragma unroll
  for (int o = 32; o > 0; o >>= 1) v += __shfl_xor(v, o, 64);
  return v;
}
__device__ inline float wsum32f(float v) {
#pragma unroll
  for (int o = 32; o > 0; o >>= 1) v += __shfl_xor(v, o, 64);
  return v;
}

__device__ inline unsigned short f2bf(float f) {  // RN-even f32->bf16
  union { float f; unsigned int u; } v{f};
  unsigned int r = v.u + 0x7fffu + ((v.u >> 16) & 1u);
  return (unsigned short)(r >> 16);
}
__device__ inline float bf2f(unsigned short h) {
  union { unsigned int u; float f; } v{(unsigned int)h << 16};
  return v.f;
}

// ---- hb = proj(expmap0(bias)) ; outputs f32 (+ y2, 1-y2 scalars) -----------
__global__ __launch_bounds__(512) void k_bias(const float* __restrict__ b1,
                                              const float* __restrict__ b2,
                                              float* __restrict__ hb1,
                                              float* __restrict__ hb2,
                                              float* __restrict__ y21,
                                              float* __restrict__ y22,
                                              float* __restrict__ omy1,
                                              float* __restrict__ omy2) {
  int w = threadIdx.x >> 6, lane = threadIdx.x & 63;
  const float* bs = (w < 4) ? (b1 + w * 64) : (b2 + (w - 4) * 64);
  double v = (double)bs[lane];
  double un = fmax(sqrt(wsum64(v * v)), kMinNorm);
  double pn = tanh(un);
  double pf = pn > kMaxNorm ? kMaxNorm / pn : 1.0;
  double p = v * (pn / un) * pf;
  float* hb = (w < 4) ? hb1 + w * 64 : hb2 + (w - 4) * 64;
  hb[lane] = (float)p;
  if (lane == 0) {
    double n = pn * pf;
    int i = (w < 4) ? w : w - 4;
    float* y2 = (w < 4) ? y21 : y22;
    float* omy = (w < 4) ? omy1 : omy2;
    y2[i] = (float)(n * n);
    omy[i] = (float)(1.0 - n * n);
  }
}

// ---- weight prep: fragment-ready bf16 hi/lo, layout [s][b][f][lane][8] -----
__global__ __launch_bounds__(256) void k_wprep(const float* __restrict__ W,
                                               unsigned short* __restrict__ Wfh,
                                               unsigned short* __restrict__ Wfl,
                                               int DIN, int tot) {
  int idx = blockIdx.x * 256 + threadIdx.x;
  if (idx >= tot) return;
  int lane = idx & 63;
  int t = idx >> 6;
  int f = t & 3; t >>= 2;
  int ks = DIN >> 5;
  int s = t % ks;
  int b = t / ks;
  int c = f * 16 + (lane & 15);
  int k = s * 32 + (lane >> 4) * 8;
  const float* wp = W + ((size_t)(b * 64 + c)) * DIN + k;
  size_t dst = (((size_t)(s * 4 + b) * 4 + f) * 64 + lane) * 8;
#pragma unroll
  for (int j = 0; j < 8; ++j) {
    float v = wp[j];
    unsigned short h = f2bf(v);
    unsigned short l = f2bf(v - bf2f(h));
    Wfh[dst + j] = h;
    Wfl[dst + j] = l;
  }
}

// ---- layer-1 GEMM, all 4 branches batched, prescale fused (f64 prep) -------
__global__ __launch_bounds__(256) void k_gemm1(const float* __restrict__ X,
                                               const unsigned short* __restrict__ Wfh,
                                               const unsigned short* __restrict__ Wfl,
                                               float* __restrict__ C4,
                                               float* __restrict__ auxS,
                                               float* __restrict__ auxSa,
                                               int N) {
  const int wave = threadIdx.x >> 6, lane = threadIdx.x & 63;
  const int r0 = blockIdx.x * 64 + wave * 16;
  const int arow = min(r0 + (lane & 15), N - 1);
  const int kbase = (lane >> 4) * 8;
  f32x4 acc[4][4] = {};
  double ss = 0.0;
#pragma unroll
  for (int s = 0; s < 8; ++s) {
    const float* ap = X + (size_t)arow * 256 + s * 32 + kbase;
    const float4 a0 = *reinterpret_cast<const float4*>(ap);
    const float4 a1 = *reinterpret_cast<const float4*>(ap + 4);
    float av[8] = {a0.x, a0.y, a0.z, a0.w, a1.x, a1.y, a1.z, a1.w};
    short8v ah, al;
#pragma unroll
    for (int j = 0; j < 8; ++j) {
      ss += (double)av[j] * av[j];
      unsigned short h = f2bf(av[j]);
      ah[j] = (short)h;
      al[j] = (short)f2bf(av[j] - bf2f(h));
    }
#pragma unroll
    for (int bb = 0; bb < 4; ++bb)
#pragma unroll
      for (int f = 0; f < 4; ++f) {
        size_t wi = (((size_t)(s * 4 + bb) * 4 + f) * 64 + lane) * 8;
        short8v bh = *reinterpret_cast<const short8v*>(Wfh + wi);
        short8v bl = *reinterpret_cast<const short8v*>(Wfl + wi);
        acc[bb][f] = __builtin_amdgcn_mfma_f32_16x16x32_bf16(al, bl, acc[bb][f], 0, 0, 0);
        acc[bb][f] = __builtin_amdgcn_mfma_f32_16x16x32_bf16(ah, bl, acc[bb][f], 0, 0, 0);
        acc[bb][f] = __builtin_amdgcn_mfma_f32_16x16x32_bf16(al, bh, acc[bb][f], 0, 0, 0);
        acc[bb][f] = __builtin_amdgcn_mfma_f32_16x16x32_bf16(ah, bh, acc[bb][f], 0, 0, 0);
      }
  }
  // fused prescale: row sumsq = reduce over the 4 k-lane groups
  ss += __shfl_xor(ss, 16, 64);
  ss += __shfl_xor(ss, 32, 64);
  if (lane < 16) {
    int row = r0 + lane;
    if (row < N) {
      double un = fmax(sqrt(ss), kMinNorm);
      double pn = tanh(un);
      double pf = pn > kMaxNorm ? kMaxNorm / pn : 1.0;
      double xn = fmax(pn * pf, kMinNorm);
      auxS[row] = (float)((pn / un) * pf);
      auxSa[row] = (float)(fmin(un, kArtMax) / xn);  // artanh(xn)/xn exactly
    }
  }
  // C/D layout: col = lane&15, row = (lane>>4)*4 + j
  const int orow0 = r0 + (lane >> 4) * 4;
#pragma unroll
  for (int bb = 0; bb < 4; ++bb)
#pragma unroll
    for (int f = 0; f < 4; ++f)
#pragma unroll
      for (int j = 0; j < 4; ++j) {
        int row = orow0 + j;
        if (row < N)
          C4[((size_t)bb * N + row) * 64 + f * 16 + (lane & 15)] = acc[bb][f][j];
      }
}

// ---- layer-2 GEMM: per-branch (blockIdx.y), DIN=64 -------------------------
__global__ __launch_bounds__(256) void k_gemm2(const float* __restrict__ X4,
                                               const unsigned short* __restrict__ Wfh,
                                               const unsigned short* __restrict__ Wfl,
                                               float* __restrict__ C4, int N) {
  const int wave = threadIdx.x >> 6, lane = threadIdx.x & 63;
  const int b = blockIdx.y;
  const int r0 = blockIdx.x * 64 + wave * 16;
  const int arow = min(r0 + (lane & 15), N - 1);
  const int kbase = (lane >> 4) * 8;
  const float* X = X4 + (size_t)b * N * 64;
  f32x4 acc[4] = {};
#pragma unroll
  for (int s = 0; s < 2; ++s) {
    const float* ap = X + (size_t)arow * 64 + s * 32 + kbase;
    const float4 a0 = *reinterpret_cast<const float4*>(ap);
    const float4 a1 = *reinterpret_cast<const float4*>(ap + 4);
    float av[8] = {a0.x, a0.y, a0.z, a0.w, a1.x, a1.y, a1.z, a1.w};
    short8v ah, al;
#pragma unroll
    for (int j = 0; j < 8; ++j) {
      unsigned short h = f2bf(av[j]);
      ah[j] = (short)h;
      al[j] = (short)f2bf(av[j] - bf2f(h));
    }
#pragma unroll
    for (int f = 0; f < 4; ++f) {
      size_t wi = (((size_t)(s * 4 + b) * 4 + f) * 64 + lane) * 8;
      short8v bh = *reinterpret_cast<const short8v*>(Wfh + wi);
      short8v bl = *reinterpret_cast<const short8v*>(Wfl + wi);
      acc[f] = __builtin_amdgcn_mfma_f32_16x16x32_bf16(al, bl, acc[f], 0, 0, 0);
      acc[f] = __builtin_amdgcn_mfma_f32_16x16x32_bf16(ah, bl, acc[f], 0, 0, 0);
      acc[f] = __builtin_amdgcn_mfma_f32_16x16x32_bf16(al, bh, acc[f], 0, 0, 0);
      acc[f] = __builtin_amdgcn_mfma_f32_16x16x32_bf16(ah, bh, acc[f], 0, 0, 0);
    }
  }
  const int orow0 = r0 + (lane >> 4) * 4;
#pragma unroll
  for (int f = 0; f < 4; ++f)
#pragma unroll
    for (int j = 0; j < 4; ++j) {
      int row = orow0 + j;
      if (row < N)
        C4[((size_t)b * N + row) * 64 + f * 16 + (lane & 15)] = acc[f][j];
    }
}

// ---- f32 Mobius tail (stable forms), batched, IN-PLACE on C ----------------
template <bool FIRST>
__global__ __launch_bounds__(256) void k_tail(float* __restrict__ C4,
                                              const float* __restrict__ a1,
                                              const float* __restrict__ a2,
                                              const float* __restrict__ hbAll,
                                              const float* __restrict__ y2All,
                                              const float* __restrict__ omyAll,
                                              int N) {
  int wave = threadIdx.x >> 6, lane = threadIdx.x & 63;
  int row = blockIdx.x * 4 + wave;
  if (row >= N) return;
  int b = blockIdx.y;
  size_t R = (size_t)b * N + row;
  float dot = C4[R * 64 + lane];
  float s, sart;
  if constexpr (FIRST) {
    s = a1[row];
    sart = a2[row];
  } else {
    s = 1.0f;
    float atn = a1[R];                        // artanh(|h_in|) exactly
    float xn = fmaxf(tanhf(atn), 1e-30f);
    sart = atn / xn;
  }
  float mx = s * dot;
  float mxn = fmaxf(sqrtf(wsum32f(mx * mx)), 1e-30f);
  float z = mxn * sart;
  float e = __expf(-2.0f * z);
  float r1 = 1.0f / (1.0f + e);
  float nmv = (1.0f - e) * r1;
  float om = 4.0f * e * r1 * r1;
  float pf1 = nmv > kMaxNormF ? kMaxNormF / nmv : 1.0f;   // proj
  float nmvc = nmv * pf1;
  float x2 = nmvc * nmvc;
  float omx = (pf1 < 1.0f) ? kOmMaxF : om;                // 1 - x2, stable
  float mvscale = nmvc / mxn;
  float mv = mvscale * mx;
  float hbd = hbAll[b * 64 + lane];
  float y2 = y2All[b], omy = omyAll[b];
  float xy = wsum32f(mv * hbd);
  float A = 1.0f + 2.0f * xy + y2;
  float den = fmaxf(1.0f + 2.0f * xy + x2 * y2, 1e-15f);
  float rden = 1.0f / den;
  float h = (A * mv + omx * hbd) * rden;
  float hn2 = (x2 + 2.0f * xy + y2) * rden;
  float omh = omx * omy * rden;                           // 1 - hn^2
  float hn = fmaxf(sqrtf(fmaxf(hn2, 0.0f)), 1e-30f);
  float pf2 = 1.0f;
  if (hn > kMaxNormF) {                                   // proj
    pf2 = kMaxNormF / hn;
    hn = kMaxNormF;
    omh = kOmMaxF;
  }
  float art = 0.5f * __logf((1.0f + hn) * (1.0f + hn) / omh);
  float htscale = (art / hn) * pf2;
  C4[R * 64 + lane] = htscale * h;   // in-place (row-local)
}

// ===================== CSR build: bucketed counting sort ====================
__global__ __launch_bounds__(512) void k_bhist(const int* __restrict__ dst,
                                               int* __restrict__ bcnt, int E,
                                               int nbuck) {
  __shared__ int lcnt[512];
  int tid = threadIdx.x;
  for (int k = tid; k < nbuck; k += 512) lcnt[k] = 0;
  __syncthreads();
  int b = blockIdx.y;
  int e0 = blockIdx.x * 8192;
  const int* db = dst + (size_t)b * E;
#pragma unroll
  for (int i = 0; i < 16; ++i) {
    int e = e0 + i * 512 + tid;
    if (e < E) atomicAdd(&lcnt[db[e] >> 7], 1);
  }
  __syncthreads();
  for (int k = tid; k < nbuck; k += 512) {
    int c = lcnt[k];
    if (c) atomicAdd(&bcnt[b * nbuck + k], c);
  }
}

__global__ __launch_bounds__(256) void k_bscan(const int* __restrict__ bcnt,
                                               int* __restrict__ boff,
                                               int* __restrict__ bcur,
                                               int* __restrict__ rp4, int TB,
                                               int n4, int Etot) {
  __shared__ int wsums[4];
  int t = threadIdx.x;
  int lane = t & 63, wv = t >> 6;
  int vals[8];
  int s = 0;
#pragma unroll
  for (int i = 0; i < 8; ++i) {
    int idx = t * 8 + i;
    int v = (idx < TB) ? bcnt[idx] : 0;
    vals[i] = s;
    s += v;
  }
  int incl = s;
#pragma unroll
  for (int o = 1; o < 64; o <<= 1) {
    int u = __shfl_up(incl, o, 64);
    if (lane >= o) incl += u;
  }
  if (lane == 63) wsums[wv] = incl;
  __syncthreads();
  int woff = 0;
  for (int i = 0; i < wv; ++i) woff += wsums[i];
  int texcl = woff + incl - s;
#pragma unroll
  for (int i = 0; i < 8; ++i) {
    int idx = t * 8 + i;
    if (idx < TB) {
      int o = texcl + vals[i];
      boff[idx] = o;
      bcur[idx] = o;
    }
  }
  if (t == 0) {
    boff[TB] = Etot;
    rp4[n4] = Etot;
  }
}

__global__ __launch_bounds__(512) void k_bpart(const int* __restrict__ src,
                                               const int* __restrict__ dst,
                                               const float* __restrict__ val,
                                               int* __restrict__ bcur,
                                               int2* __restrict__ ebuf, int E,
                                               int nbuck) {
  __shared__ int lcnt[512];
  __shared__ int lbase[512];
  int tid = threadIdx.x;
  for (int k = tid; k < nbuck; k += 512) lcnt[k] = 0;
  __syncthreads();
  int b = blockIdx.y;
  int e0 = blockIdx.x * 8192;
  const int* db = dst + (size_t)b * E;
  const int* sb = src + (size_t)b * E;
  const float* vb = val + (size_t)b * E;
#pragma unroll
  for (int i = 0; i < 16; ++i) {
    int e = e0 + i * 512 + tid;
    if (e < E) atomicAdd(&lcnt[db[e] >> 7], 1);
  }
  __syncthreads();
  for (int k = tid; k < nbuck; k += 512) {
    int c = lcnt[k];
    lbase[k] = c ? atomicAdd(&bcur[b * nbuck + k], c) : 0;
  }
  __syncthreads();
  for (int k = tid; k < nbuck; k += 512) lcnt[k] = 0;
  __syncthreads();
#pragma unroll
  for (int i = 0; i < 16; ++i) {
    int e = e0 + i * 512 + tid;
    if (e < E) {
      int d = db[e];
      int bk = d >> 7;
      int r = atomicAdd(&lcnt[bk], 1);
      int2 ev;
      ev.x = ((d & 127) << 17) | sb[e];
      ev.y = __float_as_int(vb[e]);
      ebuf[(size_t)lbase[bk] + r] = ev;
    }
  }
}

__global__ __launch_bounds__(256) void k_bfine(const int2* __restrict__ ebuf,
                                               const int* __restrict__ boff,
                                               int* __restrict__ rp4,
                                               int2* __restrict__ pvedge,
                                               int N, int nbuck) {
  __shared__ int ncnt[128], noff[128], ncur[128];
  __shared__ int w0tot;
  int tid = threadIdx.x;
  int br = blockIdx.y, bk = blockIdx.x;
  int idx = br * nbuck + bk;
  int ebeg = boff[idx], eend = boff[idx + 1];
  int n0 = bk << 7;
  int nn = min(128, N - n0);
  if (tid < 128) ncnt[tid] = 0;
  __syncthreads();
  for (int j = ebeg + tid; j < eend; j += 256)
    atomicAdd(&ncnt[ebuf[j].x >> 17], 1);
  __syncthreads();
  int v = (tid < 128) ? ncnt[tid] : 0;
  int lane = tid & 63;
  int incl = v;
#pragma unroll
  for (int o = 1; o < 64; o <<= 1) {
    int u = __shfl_up(incl, o, 64);
    if (lane >= o) incl += u;
  }
  if (tid == 63) w0tot = incl;
  __syncthreads();
  if (tid >= 64 && tid < 128) incl += w0tot;
  if (tid < 128) {
    noff[tid] = incl - v;
    ncur[tid] = incl - v;
  }
  __syncthreads();
  if (tid < nn) rp4[(size_t)br * N + n0 + tid] = ebeg + noff[tid];
  for (int j = ebeg + tid; j < eend; j += 256) {
    int2 ev = ebuf[j];
    int dl = ev.x >> 17;
    int pos = ebeg + atomicAdd(&ncur[dl], 1);
    pvedge[pos] = make_int2(ev.x & 0x1FFFF, ev.y);
  }
}

// ---- wave-scalar gather core: acc += v_j * ht[src_j][lane], j in [beg,end) -
__device__ inline float gather_row(const float* __restrict__ ht,
                                   const int2* __restrict__ pvedge, int beg,
                                   int end, int lane) {
  float acc = 0.0f;
  int j = beg;
  for (; j + 4 <= end; j += 4) {
    int2 e0 = pvedge[j];
    int2 e1 = pvedge[j + 1];
    int2 e2 = pvedge[j + 2];
    int2 e3 = pvedge[j + 3];
    float f0 = ht[(size_t)e0.x * 64 + lane];
    float f1 = ht[(size_t)e1.x * 64 + lane];
    float f2 = ht[(size_t)e2.x * 64 + lane];
    float f3 = ht[(size_t)e3.x * 64 + lane];
    acc = fmaf(__int_as_float(e0.y), f0, acc);
    acc = fmaf(__int_as_float(e1.y), f1, acc);
    acc = fmaf(__int_as_float(e2.y), f2, acc);
    acc = fmaf(__int_as_float(e3.y), f3, acc);
  }
  for (; j < end; ++j) {
    int2 e = pvedge[j];
    acc = fmaf(__int_as_float(e.y), ht[(size_t)e.x * 64 + lane], acc);
  }
  return acc;
}

// ---- layer-1: gather SpMM + identity postagg (f32), scalar edge loads ------
__global__ __launch_bounds__(256) void k_spmm_post(
    const float* __restrict__ ht4, const int* __restrict__ rp4,
    const int2* __restrict__ pvedge, float* __restrict__ out4,
    float* __restrict__ aux4, int N) {
  int wave = threadIdx.x >> 6, lane = threadIdx.x & 63;
  int row = blockIdx.x * 4 + wave;
  if (row >= N) return;
  int b = blockIdx.y;
  size_t R = (size_t)b * N + row;
  const float* ht = ht4 + (size_t)b * N * 64;
  int beg = __builtin_amdgcn_readfirstlane(rp4[R]);
  int end = __builtin_amdgcn_readfirstlane(rp4[R + 1]);
  float acc = gather_row(ht, pvedge, beg, end, lane);
  float an = fmaxf(sqrtf(wsum32f(acc * acc)), 1e-30f);
  float t = acc * (an > kArtMaxF ? kArtMaxF / an : 1.0f);
  t = fmaxf(t, 0.0f);  // relu in tangent space
  float tn = fmaxf(sqrtf(wsum32f(t * t)), 1e-30f);
  float h2n = tanhf(tn);
  float scale = fminf(h2n, kMaxNormF) / tn;   // expmap0 + proj
  out4[R * 64 + lane] = t * scale;
  if (lane == 0) aux4[R] = fminf(tn, kArtMaxF);  // artanh(|h2|) exactly
}

// ---- layer-2: SpMM + postagg + COMBINE fused; block=row, wave=branch -------
__global__ __launch_bounds__(256) void k_spmm_comb(
    const float* __restrict__ ht4, const int* __restrict__ rp4,
    const int2* __restrict__ pvedge, float* __restrict__ out, int N) {
  __shared__ float lf[4][64];
  __shared__ float latn[4];
  int b = threadIdx.x >> 6, lane = threadIdx.x & 63;
  int row = blockIdx.x;
  size_t R = (size_t)b * N + row;
  const float* ht = ht4 + (size_t)b * N * 64;
  int beg = __builtin_amdgcn_readfirstlane(rp4[R]);
  int end = __builtin_amdgcn_readfirstlane(rp4[R + 1]);
  float acc = gather_row(ht, pvedge, beg, end, lane);
  // postagg: t = relu(acc*min(1,K/|acc|)); h2 = proj(expmap0(t))
  float an = fmaxf(sqrtf(wsum32f(acc * acc)), 1e-30f);
  float t = acc * (an > kArtMaxF ? kArtMaxF / an : 1.0f);
  t = fmaxf(t, 0.0f);
  float tn = fmaxf(sqrtf(wsum32f(t * t)), 1e-30f);
  float h2n = tanhf(tn);
  float scale = fminf(h2n, kMaxNormF) / tn;
  lf[b][lane] = t * scale;
  if (lane == 0) latn[b] = fminf(tn, kArtMaxF);
  __syncthreads();
  if (b != 0) return;
  // combine (single wave): mulscaler(1/8) -> mobius chain -> mean logmap0
  float f[4], art[4], w[4], wn2[4], omw[4];
#pragma unroll
  for (int i = 0; i < 4; i++) {
    f[i] = lf[i][lane];
    float atn = latn[i];
    art[i] = atn;
    float nb = fmaxf(tanhf(atn), 1e-30f);
    float wn = tanhf(atn * 0.125f);
    w[i] = (wn / nb) * f[i];
    wn2[i] = wn * wn;
    omw[i] = 1.0f - wn2[i];
  }
  float tgt = w[0], tx2 = wn2[0], omt = omw[0];
#pragma unroll
  for (int i = 1; i < 4; i++) {
    float xy = wsum32f(tgt * w[i]);
    float A = 1.f + 2.f * xy + wn2[i];
    float den = fmaxf(1.f + 2.f * xy + tx2 * wn2[i], 1e-15f);
    float rden = 1.0f / den;
    tgt = (A * tgt + omt * w[i]) * rden;
    omt = omt * omw[i] * rden;               // 1-|tgt|^2, stable
    tx2 = 1.0f - omt;
  }
  float tnc = fmaxf(sqrtf(fmaxf(tx2, 0.0f)), 1e-30f);
  float artt = 0.5f * __logf((1.f + tnc) * (1.f + tnc) / fmaxf(omt, 1e-30f));
  float m = (artt / tnc) * tgt;
#pragma unroll
  for (int i = 0; i < 4; i++)
    m += (art[i] / fmaxf(tanhf(art[i]), 1e-30f)) * f[i];
  m *= 0.2f;
  float mn = fmaxf(sqrtf(wsum32f(m * m)), 1e-30f);
  float on = tanhf(mn);
  float pf = on > kMaxNormF ? kMaxNormF / on : 1.f;
  out[(size_t)row * 64 + lane] = m * (on / mn) * pf;
}

// ---------------------------------------------------------------------------
extern "C" void kernel_launch(void* const* d_in, const int* in_sizes, int n_in,
                              void* d_out, int out_size, void* d_ws,
                              size_t ws_size, hipStream_t stream) {
  const int FIN = 256, NB = 4;
  const int N = in_sizes[0] / FIN;       // 50000
  const int E = in_sizes[5] / NB;        // 800000
  const float* x = (const float*)d_in[0];
  const float* W1 = (const float*)d_in[1];
  const float* b1 = (const float*)d_in[2];
  const float* W2 = (const float*)d_in[3];
  const float* b2 = (const float*)d_in[4];
  const float* vals = (const float*)d_in[5];
  const int* src = (const int*)d_in[6];
  const int* dst = (const int*)d_in[7];
  float* out = (float*)d_out;
  const int n4 = NB * N;
  const int nbuck = (N + 127) >> 7;      // 391
  const int TB = NB * nbuck;

  char* w = (char*)d_ws;
  auto alloc = [&](size_t bytes) -> char* {
    char* p = w;
    w += (bytes + 255) & ~size_t(255);
    return p;
  };
  const int WF1 = NB * (FIN / 32) * 4 * 64 * 8;   // 65536 ushorts
  const int WF2 = NB * (64 / 32) * 4 * 64 * 8;    // 16384 ushorts
  unsigned short* Wf1h = (unsigned short*)alloc((size_t)WF1 * 2);
  unsigned short* Wf1l = (unsigned short*)alloc((size_t)WF1 * 2);
  unsigned short* Wf2h = (unsigned short*)alloc((size_t)WF2 * 2);
  unsigned short* Wf2l = (unsigned short*)alloc((size_t)WF2 * 2);
  float* hb1 = (float*)alloc(NB * 64 * 4);
  float* hb2 = (float*)alloc(NB * 64 * 4);
  float* y21 = (float*)alloc(NB * 4);
  float* y22 = (float*)alloc(NB * 4);
  float* omy1 = (float*)alloc(NB * 4);
  float* omy2 = (float*)alloc(NB * 4);
  float* auxS = (float*)alloc((size_t)N * 4);
  float* auxSa = (float*)alloc((size_t)N * 4);
  float* auxT4 = (float*)alloc((size_t)n4 * 4);
  float* Cb4 = (float*)alloc((size_t)n4 * 64 * 4);   // gemm out / tail inplace
  float* A4 = (float*)alloc((size_t)n4 * 64 * 4);    // spmm out
  int* bcnt = (int*)alloc((size_t)TB * 4);
  int* boff = (int*)alloc(((size_t)TB + 1) * 4);
  int* bcur = (int*)alloc((size_t)TB * 4);
  int* rp4 = (int*)alloc(((size_t)n4 + 1) * 4);
  int2* pvedge = (int2*)alloc((size_t)NB * E * 8);
  // ebuf aliases Cb4 (dead until k_gemm1; 25.6MB <= 51.2MB)
  int2* ebuf = (int2*)Cb4;

  const int rowBlocks = (N + 3) / 4;
  const int gemmBlocks = (N + 63) / 64;
  const int hBlocks = (E + 8191) / 8192;   // 98

  k_wprep<<<(WF1 / 8 + 255) / 256, 256, 0, stream>>>(W1, Wf1h, Wf1l, FIN, WF1 / 8);
  k_wprep<<<(WF2 / 8 + 255) / 256, 256, 0, stream>>>(W2, Wf2h, Wf2l, 64, WF2 / 8);
  k_bias<<<1, 512, 0, stream>>>(b1, b2, hb1, hb2, y21, y22, omy1, omy2);

  // ---- CSR build: bucketed counting sort over all 4 branches ----
  hipMemsetAsync(bcnt, 0, (size_t)TB * 4, stream);
  k_bhist<<<dim3(hBlocks, NB), 512, 0, stream>>>(dst, bcnt, E, nbuck);
  k_bscan<<<1, 256, 0, stream>>>(bcnt, boff, bcur, rp4, TB, n4, NB * E);
  k_bpart<<<dim3(hBlocks, NB), 512, 0, stream>>>(src, dst, vals, bcur, ebuf, E, nbuck);
  k_bfine<<<dim3(nbuck, NB), 256, 0, stream>>>(ebuf, boff, rp4, pvedge, N, nbuck);

  // ---- layer 1 (batched) ----
  k_gemm1<<<gemmBlocks, 256, 0, stream>>>(x, Wf1h, Wf1l, Cb4, auxS, auxSa, N);
  k_tail<true><<<dim3(rowBlocks, NB), 256, 0, stream>>>(Cb4, auxS, auxSa, hb1, y21, omy1, N);
  k_spmm_post<<<dim3(rowBlocks, NB), 256, 0, stream>>>(Cb4, rp4, pvedge, A4, auxT4, N);
  // ---- layer 2 (batched) ----
  k_gemm2<<<dim3(gemmBlocks, NB), 256, 0, stream>>>(A4, Wf2h, Wf2l, Cb4, N);
  k_tail<false><<<dim3(rowBlocks, NB), 256, 0, stream>>>(Cb4, auxT4, nullptr, hb2, y22, omy2, N);
  // ---- layer-2 SpMM + combine fused: one block per row, wave = branch ----
  k_spmm_comb<<<N, 256, 0, stream>>>(Cb4, rp4, pvedge, out, N);
}

// Round 8
// 474.229 us; speedup vs baseline: 16.9635x; 1.1806x over previous
//
#include <hip/hip_runtime.h>
#include <math.h>

// ---------------------------------------------------------------------------
// DHYPR hyperbolic GNN encoder, MI355X (gfx950).  Round 8:
//  - Mobius tails FUSED into GEMM epilogues (in-register, 16-lane-group
//    shfl reductions on the MFMA fragment layout); k_tail kernels deleted
//    (saves ~204MB Cb4 re-traffic + 2 dispatches).
//  - all libm tanhf replaced by e=__expf(-2z) form in spmm kernels.
// CSR bucketed sort + gather structure unchanged from round 7.
// ---------------------------------------------------------------------------

constexpr double kMaxNorm = 1.0 - 1e-5;   // (1-PROJ_EPS)/sqrt(c), c=1
constexpr double kMinNorm = 1e-15;
#define kMaxNormF 0.99999f
#define kArtMaxF  6.1030338f
#define kOmMaxF   1.99999e-5f                    // 1 - kMaxNorm^2

typedef __attribute__((ext_vector_type(8))) short short8v;   // 8 bf16
typedef __attribute__((ext_vector_type(4))) float f32x4;

__device__ inline double wsum64(double v) {
#pragma unroll
  for (int o = 32; o > 0; o >>= 1) v += __shfl_xor(v, o, 64);
  return v;
}
__device__ inline float wsum32f(float v) {
#pragma unroll
  for (int o = 32; o > 0; o >>= 1) v += __shfl_xor(v, o, 64);
  return v;
}
__device__ inline float qsum16(float v) {   // reduce within 16-lane group
#pragma unroll
  for (int o = 1; o < 16; o <<= 1) v += __shfl_xor(v, o, 64);
  return v;
}
__device__ inline float tanh_pos(float z) {  // z >= 0, cancellation-free
  float e = __expf(-2.0f * z);
  return (1.0f - e) / (1.0f + e);
}

__device__ inline unsigned short f2bf(float f) {  // RN-even f32->bf16
  union { float f; unsigned int u; } v{f};
  unsigned int r = v.u + 0x7fffu + ((v.u >> 16) & 1u);
  return (unsigned short)(r >> 16);
}
__device__ inline float bf2f(unsigned short h) {
  union { unsigned int u; float f; } v{(unsigned int)h << 16};
  return v.f;
}

// ---- hb = proj(expmap0(bias)) ; outputs f32 (+ y2, 1-y2 scalars) -----------
__global__ __launch_bounds__(512) void k_bias(const float* __restrict__ b1,
                                              const float* __restrict__ b2,
                                              float* __restrict__ hb1,
                                              float* __restrict__ hb2,
                                              float* __restrict__ y21,
                                              float* __restrict__ y22,
                                              float* __restrict__ omy1,
                                              float* __restrict__ omy2) {
  int w = threadIdx.x >> 6, lane = threadIdx.x & 63;
  const float* bs = (w < 4) ? (b1 + w * 64) : (b2 + (w - 4) * 64);
  double v = (double)bs[lane];
  double un = fmax(sqrt(wsum64(v * v)), kMinNorm);
  double pn = tanh(un);
  double pf = pn > kMaxNorm ? kMaxNorm / pn : 1.0;
  double p = v * (pn / un) * pf;
  float* hb = (w < 4) ? hb1 + w * 64 : hb2 + (w - 4) * 64;
  hb[lane] = (float)p;
  if (lane == 0) {
    double n = pn * pf;
    int i = (w < 4) ? w : w - 4;
    float* y2 = (w < 4) ? y21 : y22;
    float* omy = (w < 4) ? omy1 : omy2;
    y2[i] = (float)(n * n);
    omy[i] = (float)(1.0 - n * n);
  }
}

// ---- weight prep: fragment-ready bf16 hi/lo, layout [s][b][f][lane][8] -----
__global__ __launch_bounds__(256) void k_wprep(const float* __restrict__ W,
                                               unsigned short* __restrict__ Wfh,
                                               unsigned short* __restrict__ Wfl,
                                               int DIN, int tot) {
  int idx = blockIdx.x * 256 + threadIdx.x;
  if (idx >= tot) return;
  int lane = idx & 63;
  int t = idx >> 6;
  int f = t & 3; t >>= 2;
  int ks = DIN >> 5;
  int s = t % ks;
  int b = t / ks;
  int c = f * 16 + (lane & 15);
  int k = s * 32 + (lane >> 4) * 8;
  const float* wp = W + ((size_t)(b * 64 + c)) * DIN + k;
  size_t dst = (((size_t)(s * 4 + b) * 4 + f) * 64 + lane) * 8;
#pragma unroll
  for (int j = 0; j < 8; ++j) {
    float v = wp[j];
    unsigned short h = f2bf(v);
    unsigned short l = f2bf(v - bf2f(h));
    Wfh[dst + j] = h;
    Wfl[dst + j] = l;
  }
}

// ---- shared epilogue: full Mobius tail for one row-chain -------------------
// Given mx[4] (this lane's 4 elements of the row, already scaled by s),
// sart_row, hb lane values hbv[4], y2, omy: returns ht elements in mx[].
__device__ inline void tail_chain(float mx[4], float sart_row,
                                  const float hbv[4], float y2, float omy) {
  float p = mx[0] * mx[0] + mx[1] * mx[1] + mx[2] * mx[2] + mx[3] * mx[3];
  float mxn = fmaxf(sqrtf(qsum16(p)), 1e-30f);
  float z = mxn * sart_row;
  float e = __expf(-2.0f * z);
  float r1 = 1.0f / (1.0f + e);
  float nmv = (1.0f - e) * r1;
  float om = 4.0f * e * r1 * r1;
  float pf1 = nmv > kMaxNormF ? kMaxNormF / nmv : 1.0f;   // proj
  float nmvc = nmv * pf1;
  float x2 = nmvc * nmvc;
  float omx = (pf1 < 1.0f) ? kOmMaxF : om;                // 1 - x2, stable
  float mvs = nmvc / mxn;
  float pxy = 0.0f;
#pragma unroll
  for (int f = 0; f < 4; ++f) {
    mx[f] = mvs * mx[f];
    pxy += mx[f] * hbv[f];
  }
  float xy = qsum16(pxy);
  float A = 1.0f + 2.0f * xy + y2;
  float den = fmaxf(1.0f + 2.0f * xy + x2 * y2, 1e-15f);
  float rden = 1.0f / den;
  float hn2 = (x2 + 2.0f * xy + y2) * rden;
  float omh = omx * omy * rden;                           // 1 - hn^2
  float hn = fmaxf(sqrtf(fmaxf(hn2, 0.0f)), 1e-30f);
  float pf2 = 1.0f;
  if (hn > kMaxNormF) {                                   // proj
    pf2 = kMaxNormF / hn;
    hn = kMaxNormF;
    omh = kOmMaxF;
  }
  float art = 0.5f * __logf((1.0f + hn) * (1.0f + hn) / omh);
  float hts = (art / hn) * pf2 * rden;
#pragma unroll
  for (int f = 0; f < 4; ++f)
    mx[f] = hts * (A * mx[f] + omx * hbv[f]);
}

// ---- layer-1 GEMM + prescale + FUSED tail; all 4 branches batched ----------
__global__ __launch_bounds__(256) void k_gemm1(const float* __restrict__ X,
                                               const unsigned short* __restrict__ Wfh,
                                               const unsigned short* __restrict__ Wfl,
                                               float* __restrict__ C4,
                                               const float* __restrict__ hbAll,
                                               const float* __restrict__ y2All,
                                               const float* __restrict__ omyAll,
                                               int N) {
  const int wave = threadIdx.x >> 6, lane = threadIdx.x & 63;
  const int r0 = blockIdx.x * 64 + wave * 16;
  const int l = lane & 15, g = lane >> 4;
  const int arow = min(r0 + l, N - 1);
  const int kbase = g * 8;
  f32x4 acc[4][4] = {};
  double ss = 0.0;
#pragma unroll
  for (int s = 0; s < 8; ++s) {
    const float* ap = X + (size_t)arow * 256 + s * 32 + kbase;
    const float4 a0 = *reinterpret_cast<const float4*>(ap);
    const float4 a1 = *reinterpret_cast<const float4*>(ap + 4);
    float av[8] = {a0.x, a0.y, a0.z, a0.w, a1.x, a1.y, a1.z, a1.w};
    short8v ah, al;
#pragma unroll
    for (int j = 0; j < 8; ++j) {
      ss += (double)av[j] * av[j];
      unsigned short h = f2bf(av[j]);
      ah[j] = (short)h;
      al[j] = (short)f2bf(av[j] - bf2f(h));
    }
#pragma unroll
    for (int bb = 0; bb < 4; ++bb)
#pragma unroll
      for (int f = 0; f < 4; ++f) {
        size_t wi = (((size_t)(s * 4 + bb) * 4 + f) * 64 + lane) * 8;
        short8v bh = *reinterpret_cast<const short8v*>(Wfh + wi);
        short8v bl = *reinterpret_cast<const short8v*>(Wfl + wi);
        acc[bb][f] = __builtin_amdgcn_mfma_f32_16x16x32_bf16(al, bl, acc[bb][f], 0, 0, 0);
        acc[bb][f] = __builtin_amdgcn_mfma_f32_16x16x32_bf16(ah, bl, acc[bb][f], 0, 0, 0);
        acc[bb][f] = __builtin_amdgcn_mfma_f32_16x16x32_bf16(al, bh, acc[bb][f], 0, 0, 0);
        acc[bb][f] = __builtin_amdgcn_mfma_f32_16x16x32_bf16(ah, bh, acc[bb][f], 0, 0, 0);
      }
  }
  // prescale for input row r0+l (expmap0(x) scale + artanh factor), f32 forms
  ss += __shfl_xor(ss, 16, 64);
  ss += __shfl_xor(ss, 32, 64);
  float un = fmaxf(sqrtf((float)ss), 1e-30f);
  float pn = tanh_pos(un);
  float pfx = pn > kMaxNormF ? kMaxNormF / pn : 1.0f;
  float xn = fmaxf(pn * pfx, 1e-30f);
  float s_i = (pn / un) * pfx;
  float sart_i = fminf(un, kArtMaxF) / xn;   // artanh(xn)/xn exactly
  // per-lane hb values (col = f*16 + l)
  float hbv[4][4], y2v[4], omyv[4];
#pragma unroll
  for (int bb = 0; bb < 4; ++bb) {
    y2v[bb] = y2All[bb];
    omyv[bb] = omyAll[bb];
#pragma unroll
    for (int f = 0; f < 4; ++f) hbv[bb][f] = hbAll[bb * 64 + f * 16 + l];
  }
#pragma unroll
  for (int j = 0; j < 4; ++j) {
    int row = r0 + g * 4 + j;
    float s_row = __shfl(s_i, g * 4 + j, 64);
    float sart_row = __shfl(sart_i, g * 4 + j, 64);
#pragma unroll
    for (int bb = 0; bb < 4; ++bb) {
      float mx[4] = {s_row * acc[bb][0][j], s_row * acc[bb][1][j],
                     s_row * acc[bb][2][j], s_row * acc[bb][3][j]};
      tail_chain(mx, sart_row, hbv[bb], y2v[bb], omyv[bb]);
      if (row < N) {
        size_t base = ((size_t)bb * N + row) * 64 + l;
        C4[base] = mx[0];
        C4[base + 16] = mx[1];
        C4[base + 32] = mx[2];
        C4[base + 48] = mx[3];
      }
    }
  }
}

// ---- layer-2 GEMM + FUSED tail: per-branch (blockIdx.y), DIN=64 ------------
__global__ __launch_bounds__(256) void k_gemm2(const float* __restrict__ X4,
                                               const unsigned short* __restrict__ Wfh,
                                               const unsigned short* __restrict__ Wfl,
                                               float* __restrict__ C4,
                                               const float* __restrict__ auxT4,
                                               const float* __restrict__ hbAll,
                                               const float* __restrict__ y2All,
                                               const float* __restrict__ omyAll,
                                               int N) {
  const int wave = threadIdx.x >> 6, lane = threadIdx.x & 63;
  const int b = blockIdx.y;
  const int r0 = blockIdx.x * 64 + wave * 16;
  const int l = lane & 15, g = lane >> 4;
  const int arow = min(r0 + l, N - 1);
  const int kbase = g * 8;
  const float* X = X4 + (size_t)b * N * 64;
  f32x4 acc[4] = {};
#pragma unroll
  for (int s = 0; s < 2; ++s) {
    const float* ap = X + (size_t)arow * 64 + s * 32 + kbase;
    const float4 a0 = *reinterpret_cast<const float4*>(ap);
    const float4 a1 = *reinterpret_cast<const float4*>(ap + 4);
    float av[8] = {a0.x, a0.y, a0.z, a0.w, a1.x, a1.y, a1.z, a1.w};
    short8v ah, al;
#pragma unroll
    for (int j = 0; j < 8; ++j) {
      unsigned short h = f2bf(av[j]);
      ah[j] = (short)h;
      al[j] = (short)f2bf(av[j] - bf2f(h));
    }
#pragma unroll
    for (int f = 0; f < 4; ++f) {
      size_t wi = (((size_t)(s * 4 + b) * 4 + f) * 64 + lane) * 8;
      short8v bh = *reinterpret_cast<const short8v*>(Wfh + wi);
      short8v bl = *reinterpret_cast<const short8v*>(Wfl + wi);
      acc[f] = __builtin_amdgcn_mfma_f32_16x16x32_bf16(al, bl, acc[f], 0, 0, 0);
      acc[f] = __builtin_amdgcn_mfma_f32_16x16x32_bf16(ah, bl, acc[f], 0, 0, 0);
      acc[f] = __builtin_amdgcn_mfma_f32_16x16x32_bf16(al, bh, acc[f], 0, 0, 0);
      acc[f] = __builtin_amdgcn_mfma_f32_16x16x32_bf16(ah, bh, acc[f], 0, 0, 0);
    }
  }
  // sart for input row r0+l from aux atn = artanh(|h_in|)
  float atn = auxT4[(size_t)b * N + arow];
  float xn = fmaxf(tanh_pos(atn), 1e-30f);
  float sart_i = atn / xn;
  float hbv[4];
  float y2v = y2All[b], omyv = omyAll[b];
#pragma unroll
  for (int f = 0; f < 4; ++f) hbv[f] = hbAll[b * 64 + f * 16 + l];
#pragma unroll
  for (int j = 0; j < 4; ++j) {
    int row = r0 + g * 4 + j;
    float sart_row = __shfl(sart_i, g * 4 + j, 64);
    float mx[4] = {acc[0][j], acc[1][j], acc[2][j], acc[3][j]};
    tail_chain(mx, sart_row, hbv, y2v, omyv);
    if (row < N) {
      size_t base = ((size_t)b * N + row) * 64 + l;
      C4[base] = mx[0];
      C4[base + 16] = mx[1];
      C4[base + 32] = mx[2];
      C4[base + 48] = mx[3];
    }
  }
}

// ===================== CSR build: bucketed counting sort ====================
__global__ __launch_bounds__(512) void k_bhist(const int* __restrict__ dst,
                                               int* __restrict__ bcnt, int E,
                                               int nbuck) {
  __shared__ int lcnt[512];
  int tid = threadIdx.x;
  for (int k = tid; k < nbuck; k += 512) lcnt[k] = 0;
  __syncthreads();
  int b = blockIdx.y;
  int e0 = blockIdx.x * 8192;
  const int* db = dst + (size_t)b * E;
#pragma unroll
  for (int i = 0; i < 16; ++i) {
    int e = e0 + i * 512 + tid;
    if (e < E) atomicAdd(&lcnt[db[e] >> 7], 1);
  }
  __syncthreads();
  for (int k = tid; k < nbuck; k += 512) {
    int c = lcnt[k];
    if (c) atomicAdd(&bcnt[b * nbuck + k], c);
  }
}

__global__ __launch_bounds__(256) void k_bscan(const int* __restrict__ bcnt,
                                               int* __restrict__ boff,
                                               int* __restrict__ bcur,
                                               int* __restrict__ rp4, int TB,
                                               int n4, int Etot) {
  __shared__ int wsums[4];
  int t = threadIdx.x;
  int lane = t & 63, wv = t >> 6;
  int vals[8];
  int s = 0;
#pragma unroll
  for (int i = 0; i < 8; ++i) {
    int idx = t * 8 + i;
    int v = (idx < TB) ? bcnt[idx] : 0;
    vals[i] = s;
    s += v;
  }
  int incl = s;
#pragma unroll
  for (int o = 1; o < 64; o <<= 1) {
    int u = __shfl_up(incl, o, 64);
    if (lane >= o) incl += u;
  }
  if (lane == 63) wsums[wv] = incl;
  __syncthreads();
  int woff = 0;
  for (int i = 0; i < wv; ++i) woff += wsums[i];
  int texcl = woff + incl - s;
#pragma unroll
  for (int i = 0; i < 8; ++i) {
    int idx = t * 8 + i;
    if (idx < TB) {
      int o = texcl + vals[i];
      boff[idx] = o;
      bcur[idx] = o;
    }
  }
  if (t == 0) {
    boff[TB] = Etot;
    rp4[n4] = Etot;
  }
}

__global__ __launch_bounds__(512) void k_bpart(const int* __restrict__ src,
                                               const int* __restrict__ dst,
                                               const float* __restrict__ val,
                                               int* __restrict__ bcur,
                                               int2* __restrict__ ebuf, int E,
                                               int nbuck) {
  __shared__ int lcnt[512];
  __shared__ int lbase[512];
  int tid = threadIdx.x;
  for (int k = tid; k < nbuck; k += 512) lcnt[k] = 0;
  __syncthreads();
  int b = blockIdx.y;
  int e0 = blockIdx.x * 8192;
  const int* db = dst + (size_t)b * E;
  const int* sb = src + (size_t)b * E;
  const float* vb = val + (size_t)b * E;
#pragma unroll
  for (int i = 0; i < 16; ++i) {
    int e = e0 + i * 512 + tid;
    if (e < E) atomicAdd(&lcnt[db[e] >> 7], 1);
  }
  __syncthreads();
  for (int k = tid; k < nbuck; k += 512) {
    int c = lcnt[k];
    lbase[k] = c ? atomicAdd(&bcur[b * nbuck + k], c) : 0;
  }
  __syncthreads();
  for (int k = tid; k < nbuck; k += 512) lcnt[k] = 0;
  __syncthreads();
#pragma unroll
  for (int i = 0; i < 16; ++i) {
    int e = e0 + i * 512 + tid;
    if (e < E) {
      int d = db[e];
      int bk = d >> 7;
      int r = atomicAdd(&lcnt[bk], 1);
      int2 ev;
      ev.x = ((d & 127) << 17) | sb[e];
      ev.y = __float_as_int(vb[e]);
      ebuf[(size_t)lbase[bk] + r] = ev;
    }
  }
}

__global__ __launch_bounds__(256) void k_bfine(const int2* __restrict__ ebuf,
                                               const int* __restrict__ boff,
                                               int* __restrict__ rp4,
                                               int2* __restrict__ pvedge,
                                               int N, int nbuck) {
  __shared__ int ncnt[128], noff[128], ncur[128];
  __shared__ int w0tot;
  int tid = threadIdx.x;
  int br = blockIdx.y, bk = blockIdx.x;
  int idx = br * nbuck + bk;
  int ebeg = boff[idx], eend = boff[idx + 1];
  int n0 = bk << 7;
  int nn = min(128, N - n0);
  if (tid < 128) ncnt[tid] = 0;
  __syncthreads();
  for (int j = ebeg + tid; j < eend; j += 256)
    atomicAdd(&ncnt[ebuf[j].x >> 17], 1);
  __syncthreads();
  int v = (tid < 128) ? ncnt[tid] : 0;
  int lane = tid & 63;
  int incl = v;
#pragma unroll
  for (int o = 1; o < 64; o <<= 1) {
    int u = __shfl_up(incl, o, 64);
    if (lane >= o) incl += u;
  }
  if (tid == 63) w0tot = incl;
  __syncthreads();
  if (tid >= 64 && tid < 128) incl += w0tot;
  if (tid < 128) {
    noff[tid] = incl - v;
    ncur[tid] = incl - v;
  }
  __syncthreads();
  if (tid < nn) rp4[(size_t)br * N + n0 + tid] = ebeg + noff[tid];
  for (int j = ebeg + tid; j < eend; j += 256) {
    int2 ev = ebuf[j];
    int dl = ev.x >> 17;
    int pos = ebeg + atomicAdd(&ncur[dl], 1);
    pvedge[pos] = make_int2(ev.x & 0x1FFFF, ev.y);
  }
}

// ---- wave-scalar gather core: acc += v_j * ht[src_j][lane], j in [beg,end) -
__device__ inline float gather_row(const float* __restrict__ ht,
                                   const int2* __restrict__ pvedge, int beg,
                                   int end, int lane) {
  float acc = 0.0f;
  int j = beg;
  for (; j + 4 <= end; j += 4) {
    int2 e0 = pvedge[j];
    int2 e1 = pvedge[j + 1];
    int2 e2 = pvedge[j + 2];
    int2 e3 = pvedge[j + 3];
    float f0 = ht[(size_t)e0.x * 64 + lane];
    float f1 = ht[(size_t)e1.x * 64 + lane];
    float f2 = ht[(size_t)e2.x * 64 + lane];
    float f3 = ht[(size_t)e3.x * 64 + lane];
    acc = fmaf(__int_as_float(e0.y), f0, acc);
    acc = fmaf(__int_as_float(e1.y), f1, acc);
    acc = fmaf(__int_as_float(e2.y), f2, acc);
    acc = fmaf(__int_as_float(e3.y), f3, acc);
  }
  for (; j < end; ++j) {
    int2 e = pvedge[j];
    acc = fmaf(__int_as_float(e.y), ht[(size_t)e.x * 64 + lane], acc);
  }
  return acc;
}

// ---- layer-1: gather SpMM + identity postagg (f32), scalar edge loads ------
__global__ __launch_bounds__(256) void k_spmm_post(
    const float* __restrict__ ht4, const int* __restrict__ rp4,
    const int2* __restrict__ pvedge, float* __restrict__ out4,
    float* __restrict__ aux4, int N) {
  int wave = threadIdx.x >> 6, lane = threadIdx.x & 63;
  int row = blockIdx.x * 4 + wave;
  if (row >= N) return;
  int b = blockIdx.y;
  size_t R = (size_t)b * N + row;
  const float* ht = ht4 + (size_t)b * N * 64;
  int beg = __builtin_amdgcn_readfirstlane(rp4[R]);
  int end = __builtin_amdgcn_readfirstlane(rp4[R + 1]);
  float acc = gather_row(ht, pvedge, beg, end, lane);
  float an = fmaxf(sqrtf(wsum32f(acc * acc)), 1e-30f);
  float t = acc * (an > kArtMaxF ? kArtMaxF / an : 1.0f);
  t = fmaxf(t, 0.0f);  // relu in tangent space
  float tn = fmaxf(sqrtf(wsum32f(t * t)), 1e-30f);
  float h2n = tanh_pos(tn);
  float scale = fminf(h2n, kMaxNormF) / tn;   // expmap0 + proj
  out4[R * 64 + lane] = t * scale;
  if (lane == 0) aux4[R] = fminf(tn, kArtMaxF);  // artanh(|h2|) exactly
}

// ---- layer-2: SpMM + postagg + COMBINE fused; block=row, wave=branch -------
__global__ __launch_bounds__(256) void k_spmm_comb(
    const float* __restrict__ ht4, const int* __restrict__ rp4,
    const int2* __restrict__ pvedge, float* __restrict__ out, int N) {
  __shared__ float lf[4][64];
  __shared__ float latn[4];
  int b = threadIdx.x >> 6, lane = threadIdx.x & 63;
  int row = blockIdx.x;
  size_t R = (size_t)b * N + row;
  const float* ht = ht4 + (size_t)b * N * 64;
  int beg = __builtin_amdgcn_readfirstlane(rp4[R]);
  int end = __builtin_amdgcn_readfirstlane(rp4[R + 1]);
  float acc = gather_row(ht, pvedge, beg, end, lane);
  // postagg: t = relu(acc*min(1,K/|acc|)); h2 = proj(expmap0(t))
  float an = fmaxf(sqrtf(wsum32f(acc * acc)), 1e-30f);
  float t = acc * (an > kArtMaxF ? kArtMaxF / an : 1.0f);
  t = fmaxf(t, 0.0f);
  float tn = fmaxf(sqrtf(wsum32f(t * t)), 1e-30f);
  float h2n = tanh_pos(tn);
  float scale = fminf(h2n, kMaxNormF) / tn;
  lf[b][lane] = t * scale;
  if (lane == 0) latn[b] = fminf(tn, kArtMaxF);
  __syncthreads();
  if (b != 0) return;
  // combine (single wave): mulscaler(1/8) -> mobius chain -> mean logmap0
  float f[4], art[4], w[4], wn2[4], omw[4];
#pragma unroll
  for (int i = 0; i < 4; i++) {
    f[i] = lf[i][lane];
    float atn = latn[i];
    art[i] = atn;
    float nb = fmaxf(tanh_pos(atn), 1e-30f);
    float wn = tanh_pos(atn * 0.125f);
    w[i] = (wn / nb) * f[i];
    wn2[i] = wn * wn;
    omw[i] = 1.0f - wn2[i];
  }
  float tgt = w[0], tx2 = wn2[0], omt = omw[0];
#pragma unroll
  for (int i = 1; i < 4; i++) {
    float xy = wsum32f(tgt * w[i]);
    float A = 1.f + 2.f * xy + wn2[i];
    float den = fmaxf(1.f + 2.f * xy + tx2 * wn2[i], 1e-15f);
    float rden = 1.0f / den;
    tgt = (A * tgt + omt * w[i]) * rden;
    omt = omt * omw[i] * rden;               // 1-|tgt|^2, stable
    tx2 = 1.0f - omt;
  }
  float tnc = fmaxf(sqrtf(fmaxf(tx2, 0.0f)), 1e-30f);
  float artt = 0.5f * __logf((1.f + tnc) * (1.f + tnc) / fmaxf(omt, 1e-30f));
  float m = (artt / tnc) * tgt;
#pragma unroll
  for (int i = 0; i < 4; i++)
    m += (art[i] / fmaxf(tanh_pos(art[i]), 1e-30f)) * f[i];
  m *= 0.2f;
  float mn = fmaxf(sqrtf(wsum32f(m * m)), 1e-30f);
  float on = tanh_pos(mn);
  float pf = on > kMaxNormF ? kMaxNormF / on : 1.f;
  out[(size_t)row * 64 + lane] = m * (on / mn) * pf;
}

// ---------------------------------------------------------------------------
extern "C" void kernel_launch(void* const* d_in, const int* in_sizes, int n_in,
                              void* d_out, int out_size, void* d_ws,
                              size_t ws_size, hipStream_t stream) {
  const int FIN = 256, NB = 4;
  const int N = in_sizes[0] / FIN;       // 50000
  const int E = in_sizes[5] / NB;        // 800000
  const float* x = (const float*)d_in[0];
  const float* W1 = (const float*)d_in[1];
  const float* b1 = (const float*)d_in[2];
  const float* W2 = (const float*)d_in[3];
  const float* b2 = (const float*)d_in[4];
  const float* vals = (const float*)d_in[5];
  const int* src = (const int*)d_in[6];
  const int* dst = (const int*)d_in[7];
  float* out = (float*)d_out;
  const int n4 = NB * N;
  const int nbuck = (N + 127) >> 7;      // 391
  const int TB = NB * nbuck;

  char* w = (char*)d_ws;
  auto alloc = [&](size_t bytes) -> char* {
    char* p = w;
    w += (bytes + 255) & ~size_t(255);
    return p;
  };
  const int WF1 = NB * (FIN / 32) * 4 * 64 * 8;   // 65536 ushorts
  const int WF2 = NB * (64 / 32) * 4 * 64 * 8;    // 16384 ushorts
  unsigned short* Wf1h = (unsigned short*)alloc((size_t)WF1 * 2);
  unsigned short* Wf1l = (unsigned short*)alloc((size_t)WF1 * 2);
  unsigned short* Wf2h = (unsigned short*)alloc((size_t)WF2 * 2);
  unsigned short* Wf2l = (unsigned short*)alloc((size_t)WF2 * 2);
  float* hb1 = (float*)alloc(NB * 64 * 4);
  float* hb2 = (float*)alloc(NB * 64 * 4);
  float* y21 = (float*)alloc(NB * 4);
  float* y22 = (float*)alloc(NB * 4);
  float* omy1 = (float*)alloc(NB * 4);
  float* omy2 = (float*)alloc(NB * 4);
  float* auxT4 = (float*)alloc((size_t)n4 * 4);
  float* Cb4 = (float*)alloc((size_t)n4 * 64 * 4);   // gemm/tail out
  float* A4 = (float*)alloc((size_t)n4 * 64 * 4);    // spmm out
  int* bcnt = (int*)alloc((size_t)TB * 4);
  int* boff = (int*)alloc(((size_t)TB + 1) * 4);
  int* bcur = (int*)alloc((size_t)TB * 4);
  int* rp4 = (int*)alloc(((size_t)n4 + 1) * 4);
  int2* pvedge = (int2*)alloc((size_t)NB * E * 8);
  // ebuf aliases Cb4 (dead until k_gemm1; 25.6MB <= 51.2MB)
  int2* ebuf = (int2*)Cb4;

  const int rowBlocks = (N + 3) / 4;
  const int gemmBlocks = (N + 63) / 64;
  const int hBlocks = (E + 8191) / 8192;   // 98

  k_wprep<<<(WF1 / 8 + 255) / 256, 256, 0, stream>>>(W1, Wf1h, Wf1l, FIN, WF1 / 8);
  k_wprep<<<(WF2 / 8 + 255) / 256, 256, 0, stream>>>(W2, Wf2h, Wf2l, 64, WF2 / 8);
  k_bias<<<1, 512, 0, stream>>>(b1, b2, hb1, hb2, y21, y22, omy1, omy2);

  // ---- CSR build: bucketed counting sort over all 4 branches ----
  hipMemsetAsync(bcnt, 0, (size_t)TB * 4, stream);
  k_bhist<<<dim3(hBlocks, NB), 512, 0, stream>>>(dst, bcnt, E, nbuck);
  k_bscan<<<1, 256, 0, stream>>>(bcnt, boff, bcur, rp4, TB, n4, NB * E);
  k_bpart<<<dim3(hBlocks, NB), 512, 0, stream>>>(src, dst, vals, bcur, ebuf, E, nbuck);
  k_bfine<<<dim3(nbuck, NB), 256, 0, stream>>>(ebuf, boff, rp4, pvedge, N, nbuck);

  // ---- layer 1: GEMM(+tail fused) then SpMM(+postagg) ----
  k_gemm1<<<gemmBlocks, 256, 0, stream>>>(x, Wf1h, Wf1l, Cb4, hb1, y21, omy1, N);
  k_spmm_post<<<dim3(rowBlocks, NB), 256, 0, stream>>>(Cb4, rp4, pvedge, A4, auxT4, N);
  // ---- layer 2: GEMM(+tail fused) then SpMM+combine fused ----
  k_gemm2<<<dim3(gemmBlocks, NB), 256, 0, stream>>>(A4, Wf2h, Wf2l, Cb4, auxT4,
                                                    hb2, y22, omy2, N);
  k_spmm_comb<<<N, 256, 0, stream>>>(Cb4, rp4, pvedge, out, N);
}

// Round 9
// 438.510 us; speedup vs baseline: 18.3453x; 1.0815x over previous
//
#include <hip/hip_runtime.h>
#include <math.h>

// ---------------------------------------------------------------------------
// DHYPR hyperbolic GNN encoder, MI355X (gfx950).  Round 9:
//  - k_gemm1 restructured: block = 16 rows, wave = branch (grid 782 -> 3125
//    blocks, ~4x occupancy) -- was latency-bound at 19% occupancy with all
//    pipes idle (MfmaUtil 6%, VALU 14%, HBM 6%).
//  - 3-MFMA hi/lo split in both GEMMs (drop al*bl, <=2^-18 relative).
// Everything else unchanged from round 8.
// ---------------------------------------------------------------------------

constexpr double kMaxNorm = 1.0 - 1e-5;   // (1-PROJ_EPS)/sqrt(c), c=1
constexpr double kMinNorm = 1e-15;
#define kMaxNormF 0.99999f
#define kArtMaxF  6.1030338f
#define kOmMaxF   1.99999e-5f                    // 1 - kMaxNorm^2

typedef __attribute__((ext_vector_type(8))) short short8v;   // 8 bf16
typedef __attribute__((ext_vector_type(4))) float f32x4;

__device__ inline double wsum64(double v) {
#pragma unroll
  for (int o = 32; o > 0; o >>= 1) v += __shfl_xor(v, o, 64);
  return v;
}
__device__ inline float wsum32f(float v) {
#pragma unroll
  for (int o = 32; o > 0; o >>= 1) v += __shfl_xor(v, o, 64);
  return v;
}
__device__ inline float qsum16(float v) {   // reduce within 16-lane group
#pragma unroll
  for (int o = 1; o < 16; o <<= 1) v += __shfl_xor(v, o, 64);
  return v;
}
__device__ inline float tanh_pos(float z) {  // z >= 0, cancellation-free
  float e = __expf(-2.0f * z);
  return (1.0f - e) / (1.0f + e);
}

__device__ inline unsigned short f2bf(float f) {  // RN-even f32->bf16
  union { float f; unsigned int u; } v{f};
  unsigned int r = v.u + 0x7fffu + ((v.u >> 16) & 1u);
  return (unsigned short)(r >> 16);
}
__device__ inline float bf2f(unsigned short h) {
  union { unsigned int u; float f; } v{(unsigned int)h << 16};
  return v.f;
}

// ---- hb = proj(expmap0(bias)) ; outputs f32 (+ y2, 1-y2 scalars) -----------
__global__ __launch_bounds__(512) void k_bias(const float* __restrict__ b1,
                                              const float* __restrict__ b2,
                                              float* __restrict__ hb1,
                                              float* __restrict__ hb2,
                                              float* __restrict__ y21,
                                              float* __restrict__ y22,
                                              float* __restrict__ omy1,
                                              float* __restrict__ omy2) {
  int w = threadIdx.x >> 6, lane = threadIdx.x & 63;
  const float* bs = (w < 4) ? (b1 + w * 64) : (b2 + (w - 4) * 64);
  double v = (double)bs[lane];
  double un = fmax(sqrt(wsum64(v * v)), kMinNorm);
  double pn = tanh(un);
  double pf = pn > kMaxNorm ? kMaxNorm / pn : 1.0;
  double p = v * (pn / un) * pf;
  float* hb = (w < 4) ? hb1 + w * 64 : hb2 + (w - 4) * 64;
  hb[lane] = (float)p;
  if (lane == 0) {
    double n = pn * pf;
    int i = (w < 4) ? w : w - 4;
    float* y2 = (w < 4) ? y21 : y22;
    float* omy = (w < 4) ? omy1 : omy2;
    y2[i] = (float)(n * n);
    omy[i] = (float)(1.0 - n * n);
  }
}

// ---- weight prep: fragment-ready bf16 hi/lo, layout [s][b][f][lane][8] -----
__global__ __launch_bounds__(256) void k_wprep(const float* __restrict__ W,
                                               unsigned short* __restrict__ Wfh,
                                               unsigned short* __restrict__ Wfl,
                                               int DIN, int tot) {
  int idx = blockIdx.x * 256 + threadIdx.x;
  if (idx >= tot) return;
  int lane = idx & 63;
  int t = idx >> 6;
  int f = t & 3; t >>= 2;
  int ks = DIN >> 5;
  int s = t % ks;
  int b = t / ks;
  int c = f * 16 + (lane & 15);
  int k = s * 32 + (lane >> 4) * 8;
  const float* wp = W + ((size_t)(b * 64 + c)) * DIN + k;
  size_t dst = (((size_t)(s * 4 + b) * 4 + f) * 64 + lane) * 8;
#pragma unroll
  for (int j = 0; j < 8; ++j) {
    float v = wp[j];
    unsigned short h = f2bf(v);
    unsigned short l = f2bf(v - bf2f(h));
    Wfh[dst + j] = h;
    Wfl[dst + j] = l;
  }
}

// ---- shared epilogue: full Mobius tail for one row-chain -------------------
__device__ inline void tail_chain(float mx[4], float sart_row,
                                  const float hbv[4], float y2, float omy) {
  float p = mx[0] * mx[0] + mx[1] * mx[1] + mx[2] * mx[2] + mx[3] * mx[3];
  float mxn = fmaxf(sqrtf(qsum16(p)), 1e-30f);
  float z = mxn * sart_row;
  float e = __expf(-2.0f * z);
  float r1 = 1.0f / (1.0f + e);
  float nmv = (1.0f - e) * r1;
  float om = 4.0f * e * r1 * r1;
  float pf1 = nmv > kMaxNormF ? kMaxNormF / nmv : 1.0f;   // proj
  float nmvc = nmv * pf1;
  float x2 = nmvc * nmvc;
  float omx = (pf1 < 1.0f) ? kOmMaxF : om;                // 1 - x2, stable
  float mvs = nmvc / mxn;
  float pxy = 0.0f;
#pragma unroll
  for (int f = 0; f < 4; ++f) {
    mx[f] = mvs * mx[f];
    pxy += mx[f] * hbv[f];
  }
  float xy = qsum16(pxy);
  float A = 1.0f + 2.0f * xy + y2;
  float den = fmaxf(1.0f + 2.0f * xy + x2 * y2, 1e-15f);
  float rden = 1.0f / den;
  float hn2 = (x2 + 2.0f * xy + y2) * rden;
  float omh = omx * omy * rden;                           // 1 - hn^2
  float hn = fmaxf(sqrtf(fmaxf(hn2, 0.0f)), 1e-30f);
  float pf2 = 1.0f;
  if (hn > kMaxNormF) {                                   // proj
    pf2 = kMaxNormF / hn;
    hn = kMaxNormF;
    omh = kOmMaxF;
  }
  float art = 0.5f * __logf((1.0f + hn) * (1.0f + hn) / omh);
  float hts = (art / hn) * pf2 * rden;
#pragma unroll
  for (int f = 0; f < 4; ++f)
    mx[f] = hts * (A * mx[f] + omx * hbv[f]);
}

// ---- layer-1 GEMM + prescale + FUSED tail; block = 16 rows, wave = branch --
__global__ __launch_bounds__(256) void k_gemm1(const float* __restrict__ X,
                                               const unsigned short* __restrict__ Wfh,
                                               const unsigned short* __restrict__ Wfl,
                                               float* __restrict__ C4,
                                               const float* __restrict__ hbAll,
                                               const float* __restrict__ y2All,
                                               const float* __restrict__ omyAll,
                                               int N) {
  const int bb = threadIdx.x >> 6, lane = threadIdx.x & 63;
  const int r0 = blockIdx.x * 16;
  const int l = lane & 15, g = lane >> 4;
  const int arow = min(r0 + l, N - 1);
  const int kbase = g * 8;
  f32x4 acc[4] = {};
  double ss = 0.0;
#pragma unroll
  for (int s = 0; s < 8; ++s) {
    const float* ap = X + (size_t)arow * 256 + s * 32 + kbase;
    const float4 a0 = *reinterpret_cast<const float4*>(ap);
    const float4 a1 = *reinterpret_cast<const float4*>(ap + 4);
    float av[8] = {a0.x, a0.y, a0.z, a0.w, a1.x, a1.y, a1.z, a1.w};
    short8v ah, al;
#pragma unroll
    for (int j = 0; j < 8; ++j) {
      ss += (double)av[j] * av[j];
      unsigned short h = f2bf(av[j]);
      ah[j] = (short)h;
      al[j] = (short)f2bf(av[j] - bf2f(h));
    }
#pragma unroll
    for (int f = 0; f < 4; ++f) {
      size_t wi = (((size_t)(s * 4 + bb) * 4 + f) * 64 + lane) * 8;
      short8v bh = *reinterpret_cast<const short8v*>(Wfh + wi);
      short8v bl = *reinterpret_cast<const short8v*>(Wfl + wi);
      acc[f] = __builtin_amdgcn_mfma_f32_16x16x32_bf16(ah, bl, acc[f], 0, 0, 0);
      acc[f] = __builtin_amdgcn_mfma_f32_16x16x32_bf16(al, bh, acc[f], 0, 0, 0);
      acc[f] = __builtin_amdgcn_mfma_f32_16x16x32_bf16(ah, bh, acc[f], 0, 0, 0);
    }
  }
  // prescale for input row r0+l (expmap0(x) scale + artanh factor)
  ss += __shfl_xor(ss, 16, 64);
  ss += __shfl_xor(ss, 32, 64);
  float un = fmaxf(sqrtf((float)ss), 1e-30f);
  float pn = tanh_pos(un);
  float pfx = pn > kMaxNormF ? kMaxNormF / pn : 1.0f;
  float xn = fmaxf(pn * pfx, 1e-30f);
  float s_i = (pn / un) * pfx;
  float sart_i = fminf(un, kArtMaxF) / xn;   // artanh(xn)/xn exactly
  // per-lane hb values (col = f*16 + l)
  float hbv[4];
  float y2v = y2All[bb], omyv = omyAll[bb];
#pragma unroll
  for (int f = 0; f < 4; ++f) hbv[f] = hbAll[bb * 64 + f * 16 + l];
#pragma unroll
  for (int j = 0; j < 4; ++j) {
    int row = r0 + g * 4 + j;
    float s_row = __shfl(s_i, g * 4 + j, 64);
    float sart_row = __shfl(sart_i, g * 4 + j, 64);
    float mx[4] = {s_row * acc[0][j], s_row * acc[1][j], s_row * acc[2][j],
                   s_row * acc[3][j]};
    tail_chain(mx, sart_row, hbv, y2v, omyv);
    if (row < N) {
      size_t base = ((size_t)bb * N + row) * 64 + l;
      C4[base] = mx[0];
      C4[base + 16] = mx[1];
      C4[base + 32] = mx[2];
      C4[base + 48] = mx[3];
    }
  }
}

// ---- layer-2 GEMM + FUSED tail: per-branch (blockIdx.y), DIN=64 ------------
__global__ __launch_bounds__(256) void k_gemm2(const float* __restrict__ X4,
                                               const unsigned short* __restrict__ Wfh,
                                               const unsigned short* __restrict__ Wfl,
                                               float* __restrict__ C4,
                                               const float* __restrict__ auxT4,
                                               const float* __restrict__ hbAll,
                                               const float* __restrict__ y2All,
                                               const float* __restrict__ omyAll,
                                               int N) {
  const int wave = threadIdx.x >> 6, lane = threadIdx.x & 63;
  const int b = blockIdx.y;
  const int r0 = blockIdx.x * 64 + wave * 16;
  const int l = lane & 15, g = lane >> 4;
  const int arow = min(r0 + l, N - 1);
  const int kbase = g * 8;
  const float* X = X4 + (size_t)b * N * 64;
  f32x4 acc[4] = {};
#pragma unroll
  for (int s = 0; s < 2; ++s) {
    const float* ap = X + (size_t)arow * 64 + s * 32 + kbase;
    const float4 a0 = *reinterpret_cast<const float4*>(ap);
    const float4 a1 = *reinterpret_cast<const float4*>(ap + 4);
    float av[8] = {a0.x, a0.y, a0.z, a0.w, a1.x, a1.y, a1.z, a1.w};
    short8v ah, al;
#pragma unroll
    for (int j = 0; j < 8; ++j) {
      unsigned short h = f2bf(av[j]);
      ah[j] = (short)h;
      al[j] = (short)f2bf(av[j] - bf2f(h));
    }
#pragma unroll
    for (int f = 0; f < 4; ++f) {
      size_t wi = (((size_t)(s * 4 + b) * 4 + f) * 64 + lane) * 8;
      short8v bh = *reinterpret_cast<const short8v*>(Wfh + wi);
      short8v bl = *reinterpret_cast<const short8v*>(Wfl + wi);
      acc[f] = __builtin_amdgcn_mfma_f32_16x16x32_bf16(ah, bl, acc[f], 0, 0, 0);
      acc[f] = __builtin_amdgcn_mfma_f32_16x16x32_bf16(al, bh, acc[f], 0, 0, 0);
      acc[f] = __builtin_amdgcn_mfma_f32_16x16x32_bf16(ah, bh, acc[f], 0, 0, 0);
    }
  }
  // sart for input row r0+l from aux atn = artanh(|h_in|)
  float atn = auxT4[(size_t)b * N + arow];
  float xn = fmaxf(tanh_pos(atn), 1e-30f);
  float sart_i = atn / xn;
  float hbv[4];
  float y2v = y2All[b], omyv = omyAll[b];
#pragma unroll
  for (int f = 0; f < 4; ++f) hbv[f] = hbAll[b * 64 + f * 16 + l];
#pragma unroll
  for (int j = 0; j < 4; ++j) {
    int row = r0 + g * 4 + j;
    float sart_row = __shfl(sart_i, g * 4 + j, 64);
    float mx[4] = {acc[0][j], acc[1][j], acc[2][j], acc[3][j]};
    tail_chain(mx, sart_row, hbv, y2v, omyv);
    if (row < N) {
      size_t base = ((size_t)b * N + row) * 64 + l;
      C4[base] = mx[0];
      C4[base + 16] = mx[1];
      C4[base + 32] = mx[2];
      C4[base + 48] = mx[3];
    }
  }
}

// ===================== CSR build: bucketed counting sort ====================
__global__ __launch_bounds__(512) void k_bhist(const int* __restrict__ dst,
                                               int* __restrict__ bcnt, int E,
                                               int nbuck) {
  __shared__ int lcnt[512];
  int tid = threadIdx.x;
  for (int k = tid; k < nbuck; k += 512) lcnt[k] = 0;
  __syncthreads();
  int b = blockIdx.y;
  int e0 = blockIdx.x * 8192;
  const int* db = dst + (size_t)b * E;
#pragma unroll
  for (int i = 0; i < 16; ++i) {
    int e = e0 + i * 512 + tid;
    if (e < E) atomicAdd(&lcnt[db[e] >> 7], 1);
  }
  __syncthreads();
  for (int k = tid; k < nbuck; k += 512) {
    int c = lcnt[k];
    if (c) atomicAdd(&bcnt[b * nbuck + k], c);
  }
}

__global__ __launch_bounds__(256) void k_bscan(const int* __restrict__ bcnt,
                                               int* __restrict__ boff,
                                               int* __restrict__ bcur,
                                               int* __restrict__ rp4, int TB,
                                               int n4, int Etot) {
  __shared__ int wsums[4];
  int t = threadIdx.x;
  int lane = t & 63, wv = t >> 6;
  int vals[8];
  int s = 0;
#pragma unroll
  for (int i = 0; i < 8; ++i) {
    int idx = t * 8 + i;
    int v = (idx < TB) ? bcnt[idx] : 0;
    vals[i] = s;
    s += v;
  }
  int incl = s;
#pragma unroll
  for (int o = 1; o < 64; o <<= 1) {
    int u = __shfl_up(incl, o, 64);
    if (lane >= o) incl += u;
  }
  if (lane == 63) wsums[wv] = incl;
  __syncthreads();
  int woff = 0;
  for (int i = 0; i < wv; ++i) woff += wsums[i];
  int texcl = woff + incl - s;
#pragma unroll
  for (int i = 0; i < 8; ++i) {
    int idx = t * 8 + i;
    if (idx < TB) {
      int o = texcl + vals[i];
      boff[idx] = o;
      bcur[idx] = o;
    }
  }
  if (t == 0) {
    boff[TB] = Etot;
    rp4[n4] = Etot;
  }
}

__global__ __launch_bounds__(512) void k_bpart(const int* __restrict__ src,
                                               const int* __restrict__ dst,
                                               const float* __restrict__ val,
                                               int* __restrict__ bcur,
                                               int2* __restrict__ ebuf, int E,
                                               int nbuck) {
  __shared__ int lcnt[512];
  __shared__ int lbase[512];
  int tid = threadIdx.x;
  for (int k = tid; k < nbuck; k += 512) lcnt[k] = 0;
  __syncthreads();
  int b = blockIdx.y;
  int e0 = blockIdx.x * 8192;
  const int* db = dst + (size_t)b * E;
  const int* sb = src + (size_t)b * E;
  const float* vb = val + (size_t)b * E;
#pragma unroll
  for (int i = 0; i < 16; ++i) {
    int e = e0 + i * 512 + tid;
    if (e < E) atomicAdd(&lcnt[db[e] >> 7], 1);
  }
  __syncthreads();
  for (int k = tid; k < nbuck; k += 512) {
    int c = lcnt[k];
    lbase[k] = c ? atomicAdd(&bcur[b * nbuck + k], c) : 0;
  }
  __syncthreads();
  for (int k = tid; k < nbuck; k += 512) lcnt[k] = 0;
  __syncthreads();
#pragma unroll
  for (int i = 0; i < 16; ++i) {
    int e = e0 + i * 512 + tid;
    if (e < E) {
      int d = db[e];
      int bk = d >> 7;
      int r = atomicAdd(&lcnt[bk], 1);
      int2 ev;
      ev.x = ((d & 127) << 17) | sb[e];
      ev.y = __float_as_int(vb[e]);
      ebuf[(size_t)lbase[bk] + r] = ev;
    }
  }
}

__global__ __launch_bounds__(256) void k_bfine(const int2* __restrict__ ebuf,
                                               const int* __restrict__ boff,
                                               int* __restrict__ rp4,
                                               int2* __restrict__ pvedge,
                                               int N, int nbuck) {
  __shared__ int ncnt[128], noff[128], ncur[128];
  __shared__ int w0tot;
  int tid = threadIdx.x;
  int br = blockIdx.y, bk = blockIdx.x;
  int idx = br * nbuck + bk;
  int ebeg = boff[idx], eend = boff[idx + 1];
  int n0 = bk << 7;
  int nn = min(128, N - n0);
  if (tid < 128) ncnt[tid] = 0;
  __syncthreads();
  for (int j = ebeg + tid; j < eend; j += 256)
    atomicAdd(&ncnt[ebuf[j].x >> 17], 1);
  __syncthreads();
  int v = (tid < 128) ? ncnt[tid] : 0;
  int lane = tid & 63;
  int incl = v;
#pragma unroll
  for (int o = 1; o < 64; o <<= 1) {
    int u = __shfl_up(incl, o, 64);
    if (lane >= o) incl += u;
  }
  if (tid == 63) w0tot = incl;
  __syncthreads();
  if (tid >= 64 && tid < 128) incl += w0tot;
  if (tid < 128) {
    noff[tid] = incl - v;
    ncur[tid] = incl - v;
  }
  __syncthreads();
  if (tid < nn) rp4[(size_t)br * N + n0 + tid] = ebeg + noff[tid];
  for (int j = ebeg + tid; j < eend; j += 256) {
    int2 ev = ebuf[j];
    int dl = ev.x >> 17;
    int pos = ebeg + atomicAdd(&ncur[dl], 1);
    pvedge[pos] = make_int2(ev.x & 0x1FFFF, ev.y);
  }
}

// ---- wave-scalar gather core: acc += v_j * ht[src_j][lane], j in [beg,end) -
__device__ inline float gather_row(const float* __restrict__ ht,
                                   const int2* __restrict__ pvedge, int beg,
                                   int end, int lane) {
  float acc = 0.0f;
  int j = beg;
  for (; j + 4 <= end; j += 4) {
    int2 e0 = pvedge[j];
    int2 e1 = pvedge[j + 1];
    int2 e2 = pvedge[j + 2];
    int2 e3 = pvedge[j + 3];
    float f0 = ht[(size_t)e0.x * 64 + lane];
    float f1 = ht[(size_t)e1.x * 64 + lane];
    float f2 = ht[(size_t)e2.x * 64 + lane];
    float f3 = ht[(size_t)e3.x * 64 + lane];
    acc = fmaf(__int_as_float(e0.y), f0, acc);
    acc = fmaf(__int_as_float(e1.y), f1, acc);
    acc = fmaf(__int_as_float(e2.y), f2, acc);
    acc = fmaf(__int_as_float(e3.y), f3, acc);
  }
  for (; j < end; ++j) {
    int2 e = pvedge[j];
    acc = fmaf(__int_as_float(e.y), ht[(size_t)e.x * 64 + lane], acc);
  }
  return acc;
}

// ---- layer-1: gather SpMM + identity postagg (f32), scalar edge loads ------
__global__ __launch_bounds__(256) void k_spmm_post(
    const float* __restrict__ ht4, const int* __restrict__ rp4,
    const int2* __restrict__ pvedge, float* __restrict__ out4,
    float* __restrict__ aux4, int N) {
  int wave = threadIdx.x >> 6, lane = threadIdx.x & 63;
  int row = blockIdx.x * 4 + wave;
  if (row >= N) return;
  int b = blockIdx.y;
  size_t R = (size_t)b * N + row;
  const float* ht = ht4 + (size_t)b * N * 64;
  int beg = __builtin_amdgcn_readfirstlane(rp4[R]);
  int end = __builtin_amdgcn_readfirstlane(rp4[R + 1]);
  float acc = gather_row(ht, pvedge, beg, end, lane);
  float an = fmaxf(sqrtf(wsum32f(acc * acc)), 1e-30f);
  float t = acc * (an > kArtMaxF ? kArtMaxF / an : 1.0f);
  t = fmaxf(t, 0.0f);  // relu in tangent space
  float tn = fmaxf(sqrtf(wsum32f(t * t)), 1e-30f);
  float h2n = tanh_pos(tn);
  float scale = fminf(h2n, kMaxNormF) / tn;   // expmap0 + proj
  out4[R * 64 + lane] = t * scale;
  if (lane == 0) aux4[R] = fminf(tn, kArtMaxF);  // artanh(|h2|) exactly
}

// ---- layer-2: SpMM + postagg + COMBINE fused; block=row, wave=branch -------
__global__ __launch_bounds__(256) void k_spmm_comb(
    const float* __restrict__ ht4, const int* __restrict__ rp4,
    const int2* __restrict__ pvedge, float* __restrict__ out, int N) {
  __shared__ float lf[4][64];
  __shared__ float latn[4];
  int b = threadIdx.x >> 6, lane = threadIdx.x & 63;
  int row = blockIdx.x;
  size_t R = (size_t)b * N + row;
  const float* ht = ht4 + (size_t)b * N * 64;
  int beg = __builtin_amdgcn_readfirstlane(rp4[R]);
  int end = __builtin_amdgcn_readfirstlane(rp4[R + 1]);
  float acc = gather_row(ht, pvedge, beg, end, lane);
  // postagg: t = relu(acc*min(1,K/|acc|)); h2 = proj(expmap0(t))
  float an = fmaxf(sqrtf(wsum32f(acc * acc)), 1e-30f);
  float t = acc * (an > kArtMaxF ? kArtMaxF / an : 1.0f);
  t = fmaxf(t, 0.0f);
  float tn = fmaxf(sqrtf(wsum32f(t * t)), 1e-30f);
  float h2n = tanh_pos(tn);
  float scale = fminf(h2n, kMaxNormF) / tn;
  lf[b][lane] = t * scale;
  if (lane == 0) latn[b] = fminf(tn, kArtMaxF);
  __syncthreads();
  if (b != 0) return;
  // combine (single wave): mulscaler(1/8) -> mobius chain -> mean logmap0
  float f[4], art[4], w[4], wn2[4], omw[4];
#pragma unroll
  for (int i = 0; i < 4; i++) {
    f[i] = lf[i][lane];
    float atn = latn[i];
    art[i] = atn;
    float nb = fmaxf(tanh_pos(atn), 1e-30f);
    float wn = tanh_pos(atn * 0.125f);
    w[i] = (wn / nb) * f[i];
    wn2[i] = wn * wn;
    omw[i] = 1.0f - wn2[i];
  }
  float tgt = w[0], tx2 = wn2[0], omt = omw[0];
#pragma unroll
  for (int i = 1; i < 4; i++) {
    float xy = wsum32f(tgt * w[i]);
    float A = 1.f + 2.f * xy + wn2[i];
    float den = fmaxf(1.f + 2.f * xy + tx2 * wn2[i], 1e-15f);
    float rden = 1.0f / den;
    tgt = (A * tgt + omt * w[i]) * rden;
    omt = omt * omw[i] * rden;               // 1-|tgt|^2, stable
    tx2 = 1.0f - omt;
  }
  float tnc = fmaxf(sqrtf(fmaxf(tx2, 0.0f)), 1e-30f);
  float artt = 0.5f * __logf((1.f + tnc) * (1.f + tnc) / fmaxf(omt, 1e-30f));
  float m = (artt / tnc) * tgt;
#pragma unroll
  for (int i = 0; i < 4; i++)
    m += (art[i] / fmaxf(tanh_pos(art[i]), 1e-30f)) * f[i];
  m *= 0.2f;
  float mn = fmaxf(sqrtf(wsum32f(m * m)), 1e-30f);
  float on = tanh_pos(mn);
  float pf = on > kMaxNormF ? kMaxNormF / on : 1.f;
  out[(size_t)row * 64 + lane] = m * (on / mn) * pf;
}

// ---------------------------------------------------------------------------
extern "C" void kernel_launch(void* const* d_in, const int* in_sizes, int n_in,
                              void* d_out, int out_size, void* d_ws,
                              size_t ws_size, hipStream_t stream) {
  const int FIN = 256, NB = 4;
  const int N = in_sizes[0] / FIN;       // 50000
  const int E = in_sizes[5] / NB;        // 800000
  const float* x = (const float*)d_in[0];
  const float* W1 = (const float*)d_in[1];
  const float* b1 = (const float*)d_in[2];
  const float* W2 = (const float*)d_in[3];
  const float* b2 = (const float*)d_in[4];
  const float* vals = (const float*)d_in[5];
  const int* src = (const int*)d_in[6];
  const int* dst = (const int*)d_in[7];
  float* out = (float*)d_out;
  const int n4 = NB * N;
  const int nbuck = (N + 127) >> 7;      // 391
  const int TB = NB * nbuck;

  char* w = (char*)d_ws;
  auto alloc = [&](size_t bytes) -> char* {
    char* p = w;
    w += (bytes + 255) & ~size_t(255);
    return p;
  };
  const int WF1 = NB * (FIN / 32) * 4 * 64 * 8;   // 65536 ushorts
  const int WF2 = NB * (64 / 32) * 4 * 64 * 8;    // 16384 ushorts
  unsigned short* Wf1h = (unsigned short*)alloc((size_t)WF1 * 2);
  unsigned short* Wf1l = (unsigned short*)alloc((size_t)WF1 * 2);
  unsigned short* Wf2h = (unsigned short*)alloc((size_t)WF2 * 2);
  unsigned short* Wf2l = (unsigned short*)alloc((size_t)WF2 * 2);
  float* hb1 = (float*)alloc(NB * 64 * 4);
  float* hb2 = (float*)alloc(NB * 64 * 4);
  float* y21 = (float*)alloc(NB * 4);
  float* y22 = (float*)alloc(NB * 4);
  float* omy1 = (float*)alloc(NB * 4);
  float* omy2 = (float*)alloc(NB * 4);
  float* auxT4 = (float*)alloc((size_t)n4 * 4);
  float* Cb4 = (float*)alloc((size_t)n4 * 64 * 4);   // gemm/tail out
  float* A4 = (float*)alloc((size_t)n4 * 64 * 4);    // spmm out
  int* bcnt = (int*)alloc((size_t)TB * 4);
  int* boff = (int*)alloc(((size_t)TB + 1) * 4);
  int* bcur = (int*)alloc((size_t)TB * 4);
  int* rp4 = (int*)alloc(((size_t)n4 + 1) * 4);
  int2* pvedge = (int2*)alloc((size_t)NB * E * 8);
  // ebuf aliases Cb4 (dead until k_gemm1; 25.6MB <= 51.2MB)
  int2* ebuf = (int2*)Cb4;

  const int rowBlocks = (N + 3) / 4;
  const int g1Blocks = (N + 15) / 16;      // 3125: 16 rows/block, wave=branch
  const int g2Blocks = (N + 63) / 64;
  const int hBlocks = (E + 8191) / 8192;   // 98

  k_wprep<<<(WF1 / 8 + 255) / 256, 256, 0, stream>>>(W1, Wf1h, Wf1l, FIN, WF1 / 8);
  k_wprep<<<(WF2 / 8 + 255) / 256, 256, 0, stream>>>(W2, Wf2h, Wf2l, 64, WF2 / 8);
  k_bias<<<1, 512, 0, stream>>>(b1, b2, hb1, hb2, y21, y22, omy1, omy2);

  // ---- CSR build: bucketed counting sort over all 4 branches ----
  hipMemsetAsync(bcnt, 0, (size_t)TB * 4, stream);
  k_bhist<<<dim3(hBlocks, NB), 512, 0, stream>>>(dst, bcnt, E, nbuck);
  k_bscan<<<1, 256, 0, stream>>>(bcnt, boff, bcur, rp4, TB, n4, NB * E);
  k_bpart<<<dim3(hBlocks, NB), 512, 0, stream>>>(src, dst, vals, bcur, ebuf, E, nbuck);
  k_bfine<<<dim3(nbuck, NB), 256, 0, stream>>>(ebuf, boff, rp4, pvedge, N, nbuck);

  // ---- layer 1: GEMM(+tail fused) then SpMM(+postagg) ----
  k_gemm1<<<g1Blocks, 256, 0, stream>>>(x, Wf1h, Wf1l, Cb4, hb1, y21, omy1, N);
  k_spmm_post<<<dim3(rowBlocks, NB), 256, 0, stream>>>(Cb4, rp4, pvedge, A4, auxT4, N);
  // ---- layer 2: GEMM(+tail fused) then SpMM+combine fused ----
  k_gemm2<<<dim3(g2Blocks, NB), 256, 0, stream>>>(A4, Wf2h, Wf2l, Cb4, auxT4,
                                                  hb2, y22, omy2, N);
  k_spmm_comb<<<N, 256, 0, stream>>>(Cb4, rp4, pvedge, out, N);
}

// Round 10
// 415.113 us; speedup vs baseline: 19.3793x; 1.0564x over previous
//
#include <hip/hip_runtime.h>
#include <hip/hip_fp16.h>
#include <math.h>

// ---------------------------------------------------------------------------
// DHYPR hyperbolic GNN encoder, MI355X (gfx950).  Round 10:
//  - gather tables (tangent-space ht) stored f16: row 256B -> 128B, FETCH
//    halves, per-XCD L2 hit rate up. f32 accumulate; norms still via f32 aux.
//  - paired gather: lanes 0-31 = edge j, lanes 32-63 = edge j+1 (__half2
//    loads, scalar edge records + cndmask select); merge via shfl_xor(32).
//  - combine reuses |f_i| from postagg via LDS (kills 4 tanh per row).
// ---------------------------------------------------------------------------

constexpr double kMaxNorm = 1.0 - 1e-5;   // (1-PROJ_EPS)/sqrt(c), c=1
constexpr double kMinNorm = 1e-15;
#define kMaxNormF 0.99999f
#define kArtMaxF  6.1030338f
#define kOmMaxF   1.99999e-5f                    // 1 - kMaxNorm^2

typedef __attribute__((ext_vector_type(8))) short short8v;   // 8 bf16
typedef __attribute__((ext_vector_type(4))) float f32x4;

__device__ inline double wsum64(double v) {
#pragma unroll
  for (int o = 32; o > 0; o >>= 1) v += __shfl_xor(v, o, 64);
  return v;
}
__device__ inline float wsum32f(float v) {
#pragma unroll
  for (int o = 32; o > 0; o >>= 1) v += __shfl_xor(v, o, 64);
  return v;
}
__device__ inline float wsum32h(float v) {  // sum within each 32-lane half
#pragma unroll
  for (int o = 1; o < 32; o <<= 1) v += __shfl_xor(v, o, 64);
  return v;
}
__device__ inline float qsum16(float v) {   // reduce within 16-lane group
#pragma unroll
  for (int o = 1; o < 16; o <<= 1) v += __shfl_xor(v, o, 64);
  return v;
}
__device__ inline float tanh_pos(float z) {  // z >= 0, cancellation-free
  float e = __expf(-2.0f * z);
  return (1.0f - e) / (1.0f + e);
}

__device__ inline unsigned short f2bf(float f) {  // RN-even f32->bf16
  union { float f; unsigned int u; } v{f};
  unsigned int r = v.u + 0x7fffu + ((v.u >> 16) & 1u);
  return (unsigned short)(r >> 16);
}
__device__ inline float bf2f(unsigned short h) {
  union { unsigned int u; float f; } v{(unsigned int)h << 16};
  return v.f;
}

// ---- hb = proj(expmap0(bias)) ; outputs f32 (+ y2, 1-y2 scalars) -----------
__global__ __launch_bounds__(512) void k_bias(const float* __restrict__ b1,
                                              const float* __restrict__ b2,
                                              float* __restrict__ hb1,
                                              float* __restrict__ hb2,
                                              float* __restrict__ y21,
                                              float* __restrict__ y22,
                                              float* __restrict__ omy1,
                                              float* __restrict__ omy2) {
  int w = threadIdx.x >> 6, lane = threadIdx.x & 63;
  const float* bs = (w < 4) ? (b1 + w * 64) : (b2 + (w - 4) * 64);
  double v = (double)bs[lane];
  double un = fmax(sqrt(wsum64(v * v)), kMinNorm);
  double pn = tanh(un);
  double pf = pn > kMaxNorm ? kMaxNorm / pn : 1.0;
  double p = v * (pn / un) * pf;
  float* hb = (w < 4) ? hb1 + w * 64 : hb2 + (w - 4) * 64;
  hb[lane] = (float)p;
  if (lane == 0) {
    double n = pn * pf;
    int i = (w < 4) ? w : w - 4;
    float* y2 = (w < 4) ? y21 : y22;
    float* omy = (w < 4) ? omy1 : omy2;
    y2[i] = (float)(n * n);
    omy[i] = (float)(1.0 - n * n);
  }
}

// ---- weight prep: fragment-ready bf16 hi/lo, layout [s][b][f][lane][8] -----
__global__ __launch_bounds__(256) void k_wprep(const float* __restrict__ W,
                                               unsigned short* __restrict__ Wfh,
                                               unsigned short* __restrict__ Wfl,
                                               int DIN, int tot) {
  int idx = blockIdx.x * 256 + threadIdx.x;
  if (idx >= tot) return;
  int lane = idx & 63;
  int t = idx >> 6;
  int f = t & 3; t >>= 2;
  int ks = DIN >> 5;
  int s = t % ks;
  int b = t / ks;
  int c = f * 16 + (lane & 15);
  int k = s * 32 + (lane >> 4) * 8;
  const float* wp = W + ((size_t)(b * 64 + c)) * DIN + k;
  size_t dst = (((size_t)(s * 4 + b) * 4 + f) * 64 + lane) * 8;
#pragma unroll
  for (int j = 0; j < 8; ++j) {
    float v = wp[j];
    unsigned short h = f2bf(v);
    unsigned short l = f2bf(v - bf2f(h));
    Wfh[dst + j] = h;
    Wfl[dst + j] = l;
  }
}

// ---- shared epilogue: full Mobius tail for one row-chain -------------------
__device__ inline void tail_chain(float mx[4], float sart_row,
                                  const float hbv[4], float y2, float omy) {
  float p = mx[0] * mx[0] + mx[1] * mx[1] + mx[2] * mx[2] + mx[3] * mx[3];
  float mxn = fmaxf(sqrtf(qsum16(p)), 1e-30f);
  float z = mxn * sart_row;
  float e = __expf(-2.0f * z);
  float r1 = 1.0f / (1.0f + e);
  float nmv = (1.0f - e) * r1;
  float om = 4.0f * e * r1 * r1;
  float pf1 = nmv > kMaxNormF ? kMaxNormF / nmv : 1.0f;   // proj
  float nmvc = nmv * pf1;
  float x2 = nmvc * nmvc;
  float omx = (pf1 < 1.0f) ? kOmMaxF : om;                // 1 - x2, stable
  float mvs = nmvc / mxn;
  float pxy = 0.0f;
#pragma unroll
  for (int f = 0; f < 4; ++f) {
    mx[f] = mvs * mx[f];
    pxy += mx[f] * hbv[f];
  }
  float xy = qsum16(pxy);
  float A = 1.0f + 2.0f * xy + y2;
  float den = fmaxf(1.0f + 2.0f * xy + x2 * y2, 1e-15f);
  float rden = 1.0f / den;
  float hn2 = (x2 + 2.0f * xy + y2) * rden;
  float omh = omx * omy * rden;                           // 1 - hn^2
  float hn = fmaxf(sqrtf(fmaxf(hn2, 0.0f)), 1e-30f);
  float pf2 = 1.0f;
  if (hn > kMaxNormF) {                                   // proj
    pf2 = kMaxNormF / hn;
    hn = kMaxNormF;
    omh = kOmMaxF;
  }
  float art = 0.5f * __logf((1.0f + hn) * (1.0f + hn) / omh);
  float hts = (art / hn) * pf2 * rden;
#pragma unroll
  for (int f = 0; f < 4; ++f)
    mx[f] = hts * (A * mx[f] + omx * hbv[f]);
}

// ---- layer-1 GEMM + prescale + FUSED tail; block = 16 rows, wave = branch --
__global__ __launch_bounds__(256) void k_gemm1(const float* __restrict__ X,
                                               const unsigned short* __restrict__ Wfh,
                                               const unsigned short* __restrict__ Wfl,
                                               __half* __restrict__ C4,
                                               const float* __restrict__ hbAll,
                                               const float* __restrict__ y2All,
                                               const float* __restrict__ omyAll,
                                               int N) {
  const int bb = threadIdx.x >> 6, lane = threadIdx.x & 63;
  const int r0 = blockIdx.x * 16;
  const int l = lane & 15, g = lane >> 4;
  const int arow = min(r0 + l, N - 1);
  const int kbase = g * 8;
  f32x4 acc[4] = {};
  double ss = 0.0;
#pragma unroll
  for (int s = 0; s < 8; ++s) {
    const float* ap = X + (size_t)arow * 256 + s * 32 + kbase;
    const float4 a0 = *reinterpret_cast<const float4*>(ap);
    const float4 a1 = *reinterpret_cast<const float4*>(ap + 4);
    float av[8] = {a0.x, a0.y, a0.z, a0.w, a1.x, a1.y, a1.z, a1.w};
    short8v ah, al;
#pragma unroll
    for (int j = 0; j < 8; ++j) {
      ss += (double)av[j] * av[j];
      unsigned short h = f2bf(av[j]);
      ah[j] = (short)h;
      al[j] = (short)f2bf(av[j] - bf2f(h));
    }
#pragma unroll
    for (int f = 0; f < 4; ++f) {
      size_t wi = (((size_t)(s * 4 + bb) * 4 + f) * 64 + lane) * 8;
      short8v bh = *reinterpret_cast<const short8v*>(Wfh + wi);
      short8v bl = *reinterpret_cast<const short8v*>(Wfl + wi);
      acc[f] = __builtin_amdgcn_mfma_f32_16x16x32_bf16(ah, bl, acc[f], 0, 0, 0);
      acc[f] = __builtin_amdgcn_mfma_f32_16x16x32_bf16(al, bh, acc[f], 0, 0, 0);
      acc[f] = __builtin_amdgcn_mfma_f32_16x16x32_bf16(ah, bh, acc[f], 0, 0, 0);
    }
  }
  // prescale for input row r0+l (expmap0(x) scale + artanh factor)
  ss += __shfl_xor(ss, 16, 64);
  ss += __shfl_xor(ss, 32, 64);
  float un = fmaxf(sqrtf((float)ss), 1e-30f);
  float pn = tanh_pos(un);
  float pfx = pn > kMaxNormF ? kMaxNormF / pn : 1.0f;
  float xn = fmaxf(pn * pfx, 1e-30f);
  float s_i = (pn / un) * pfx;
  float sart_i = fminf(un, kArtMaxF) / xn;   // artanh(xn)/xn exactly
  float hbv[4];
  float y2v = y2All[bb], omyv = omyAll[bb];
#pragma unroll
  for (int f = 0; f < 4; ++f) hbv[f] = hbAll[bb * 64 + f * 16 + l];
#pragma unroll
  for (int j = 0; j < 4; ++j) {
    int row = r0 + g * 4 + j;
    float s_row = __shfl(s_i, g * 4 + j, 64);
    float sart_row = __shfl(sart_i, g * 4 + j, 64);
    float mx[4] = {s_row * acc[0][j], s_row * acc[1][j], s_row * acc[2][j],
                   s_row * acc[3][j]};
    tail_chain(mx, sart_row, hbv, y2v, omyv);
    if (row < N) {
      size_t base = ((size_t)bb * N + row) * 64 + l;
      C4[base] = __float2half(mx[0]);
      C4[base + 16] = __float2half(mx[1]);
      C4[base + 32] = __float2half(mx[2]);
      C4[base + 48] = __float2half(mx[3]);
    }
  }
}

// ---- layer-2 GEMM + FUSED tail: per-branch (blockIdx.y), DIN=64 ------------
__global__ __launch_bounds__(256) void k_gemm2(const float* __restrict__ X4,
                                               const unsigned short* __restrict__ Wfh,
                                               const unsigned short* __restrict__ Wfl,
                                               __half* __restrict__ C4,
                                               const float* __restrict__ auxT4,
                                               const float* __restrict__ hbAll,
                                               const float* __restrict__ y2All,
                                               const float* __restrict__ omyAll,
                                               int N) {
  const int wave = threadIdx.x >> 6, lane = threadIdx.x & 63;
  const int b = blockIdx.y;
  const int r0 = blockIdx.x * 64 + wave * 16;
  const int l = lane & 15, g = lane >> 4;
  const int arow = min(r0 + l, N - 1);
  const int kbase = g * 8;
  const float* X = X4 + (size_t)b * N * 64;
  f32x4 acc[4] = {};
#pragma unroll
  for (int s = 0; s < 2; ++s) {
    const float* ap = X + (size_t)arow * 64 + s * 32 + kbase;
    const float4 a0 = *reinterpret_cast<const float4*>(ap);
    const float4 a1 = *reinterpret_cast<const float4*>(ap + 4);
    float av[8] = {a0.x, a0.y, a0.z, a0.w, a1.x, a1.y, a1.z, a1.w};
    short8v ah, al;
#pragma unroll
    for (int j = 0; j < 8; ++j) {
      unsigned short h = f2bf(av[j]);
      ah[j] = (short)h;
      al[j] = (short)f2bf(av[j] - bf2f(h));
    }
#pragma unroll
    for (int f = 0; f < 4; ++f) {
      size_t wi = (((size_t)(s * 4 + b) * 4 + f) * 64 + lane) * 8;
      short8v bh = *reinterpret_cast<const short8v*>(Wfh + wi);
      short8v bl = *reinterpret_cast<const short8v*>(Wfl + wi);
      acc[f] = __builtin_amdgcn_mfma_f32_16x16x32_bf16(ah, bl, acc[f], 0, 0, 0);
      acc[f] = __builtin_amdgcn_mfma_f32_16x16x32_bf16(al, bh, acc[f], 0, 0, 0);
      acc[f] = __builtin_amdgcn_mfma_f32_16x16x32_bf16(ah, bh, acc[f], 0, 0, 0);
    }
  }
  float atn = auxT4[(size_t)b * N + arow];
  float xn = fmaxf(tanh_pos(atn), 1e-30f);
  float sart_i = atn / xn;
  float hbv[4];
  float y2v = y2All[b], omyv = omyAll[b];
#pragma unroll
  for (int f = 0; f < 4; ++f) hbv[f] = hbAll[b * 64 + f * 16 + l];
#pragma unroll
  for (int j = 0; j < 4; ++j) {
    int row = r0 + g * 4 + j;
    float sart_row = __shfl(sart_i, g * 4 + j, 64);
    float mx[4] = {acc[0][j], acc[1][j], acc[2][j], acc[3][j]};
    tail_chain(mx, sart_row, hbv, y2v, omyv);
    if (row < N) {
      size_t base = ((size_t)b * N + row) * 64 + l;
      C4[base] = __float2half(mx[0]);
      C4[base + 16] = __float2half(mx[1]);
      C4[base + 32] = __float2half(mx[2]);
      C4[base + 48] = __float2half(mx[3]);
    }
  }
}

// ===================== CSR build: bucketed counting sort ====================
__global__ __launch_bounds__(512) void k_bhist(const int* __restrict__ dst,
                                               int* __restrict__ bcnt, int E,
                                               int nbuck) {
  __shared__ int lcnt[512];
  int tid = threadIdx.x;
  for (int k = tid; k < nbuck; k += 512) lcnt[k] = 0;
  __syncthreads();
  int b = blockIdx.y;
  int e0 = blockIdx.x * 8192;
  const int* db = dst + (size_t)b * E;
#pragma unroll
  for (int i = 0; i < 16; ++i) {
    int e = e0 + i * 512 + tid;
    if (e < E) atomicAdd(&lcnt[db[e] >> 7], 1);
  }
  __syncthreads();
  for (int k = tid; k < nbuck; k += 512) {
    int c = lcnt[k];
    if (c) atomicAdd(&bcnt[b * nbuck + k], c);
  }
}

__global__ __launch_bounds__(256) void k_bscan(const int* __restrict__ bcnt,
                                               int* __restrict__ boff,
                                               int* __restrict__ bcur,
                                               int* __restrict__ rp4, int TB,
                                               int n4, int Etot) {
  __shared__ int wsums[4];
  int t = threadIdx.x;
  int lane = t & 63, wv = t >> 6;
  int vals[8];
  int s = 0;
#pragma unroll
  for (int i = 0; i < 8; ++i) {
    int idx = t * 8 + i;
    int v = (idx < TB) ? bcnt[idx] : 0;
    vals[i] = s;
    s += v;
  }
  int incl = s;
#pragma unroll
  for (int o = 1; o < 64; o <<= 1) {
    int u = __shfl_up(incl, o, 64);
    if (lane >= o) incl += u;
  }
  if (lane == 63) wsums[wv] = incl;
  __syncthreads();
  int woff = 0;
  for (int i = 0; i < wv; ++i) woff += wsums[i];
  int texcl = woff + incl - s;
#pragma unroll
  for (int i = 0; i < 8; ++i) {
    int idx = t * 8 + i;
    if (idx < TB) {
      int o = texcl + vals[i];
      boff[idx] = o;
      bcur[idx] = o;
    }
  }
  if (t == 0) {
    boff[TB] = Etot;
    rp4[n4] = Etot;
  }
}

__global__ __launch_bounds__(512) void k_bpart(const int* __restrict__ src,
                                               const int* __restrict__ dst,
                                               const float* __restrict__ val,
                                               int* __restrict__ bcur,
                                               int2* __restrict__ ebuf, int E,
                                               int nbuck) {
  __shared__ int lcnt[512];
  __shared__ int lbase[512];
  int tid = threadIdx.x;
  for (int k = tid; k < nbuck; k += 512) lcnt[k] = 0;
  __syncthreads();
  int b = blockIdx.y;
  int e0 = blockIdx.x * 8192;
  const int* db = dst + (size_t)b * E;
  const int* sb = src + (size_t)b * E;
  const float* vb = val + (size_t)b * E;
#pragma unroll
  for (int i = 0; i < 16; ++i) {
    int e = e0 + i * 512 + tid;
    if (e < E) atomicAdd(&lcnt[db[e] >> 7], 1);
  }
  __syncthreads();
  for (int k = tid; k < nbuck; k += 512) {
    int c = lcnt[k];
    lbase[k] = c ? atomicAdd(&bcur[b * nbuck + k], c) : 0;
  }
  __syncthreads();
  for (int k = tid; k < nbuck; k += 512) lcnt[k] = 0;
  __syncthreads();
#pragma unroll
  for (int i = 0; i < 16; ++i) {
    int e = e0 + i * 512 + tid;
    if (e < E) {
      int d = db[e];
      int bk = d >> 7;
      int r = atomicAdd(&lcnt[bk], 1);
      int2 ev;
      ev.x = ((d & 127) << 17) | sb[e];
      ev.y = __float_as_int(vb[e]);
      ebuf[(size_t)lbase[bk] + r] = ev;
    }
  }
}

__global__ __launch_bounds__(256) void k_bfine(const int2* __restrict__ ebuf,
                                               const int* __restrict__ boff,
                                               int* __restrict__ rp4,
                                               int2* __restrict__ pvedge,
                                               int N, int nbuck) {
  __shared__ int ncnt[128], noff[128], ncur[128];
  __shared__ int w0tot;
  int tid = threadIdx.x;
  int br = blockIdx.y, bk = blockIdx.x;
  int idx = br * nbuck + bk;
  int ebeg = boff[idx], eend = boff[idx + 1];
  int n0 = bk << 7;
  int nn = min(128, N - n0);
  if (tid < 128) ncnt[tid] = 0;
  __syncthreads();
  for (int j = ebeg + tid; j < eend; j += 256)
    atomicAdd(&ncnt[ebuf[j].x >> 17], 1);
  __syncthreads();
  int v = (tid < 128) ? ncnt[tid] : 0;
  int lane = tid & 63;
  int incl = v;
#pragma unroll
  for (int o = 1; o < 64; o <<= 1) {
    int u = __shfl_up(incl, o, 64);
    if (lane >= o) incl += u;
  }
  if (tid == 63) w0tot = incl;
  __syncthreads();
  if (tid >= 64 && tid < 128) incl += w0tot;
  if (tid < 128) {
    noff[tid] = incl - v;
    ncur[tid] = incl - v;
  }
  __syncthreads();
  if (tid < nn) rp4[(size_t)br * N + n0 + tid] = ebeg + noff[tid];
  for (int j = ebeg + tid; j < eend; j += 256) {
    int2 ev = ebuf[j];
    int dl = ev.x >> 17;
    int pos = ebeg + atomicAdd(&ncur[dl], 1);
    pvedge[pos] = make_int2(ev.x & 0x1FFFF, ev.y);
  }
}

// ---- paired f16 gather: lanes 0-31 = edge j, 32-63 = edge j+1 --------------
// ht2: row r at ht2[r*32 + sub] (__half2, 2 dims/lane).  Returns merged
// float2 acc (dims 2*sub, 2*sub+1), identical in both halves.
__device__ inline float2 gather_row_h2(const __half2* __restrict__ ht2,
                                       const int2* __restrict__ pvedge,
                                       int beg, int end, int half, int sub) {
  float ax = 0.0f, ay = 0.0f;
  int j = beg;
  for (; j + 4 <= end; j += 4) {
    int2 e0 = pvedge[j], e1 = pvedge[j + 1];
    int2 e2 = pvedge[j + 2], e3 = pvedge[j + 3];
    int sA = half ? e1.x : e0.x;
    float vA = __int_as_float(half ? e1.y : e0.y);
    int sB = half ? e3.x : e2.x;
    float vB = __int_as_float(half ? e3.y : e2.y);
    float2 fA = __half22float2(ht2[(size_t)sA * 32 + sub]);
    float2 fB = __half22float2(ht2[(size_t)sB * 32 + sub]);
    ax = fmaf(vA, fA.x, ax);
    ay = fmaf(vA, fA.y, ay);
    ax = fmaf(vB, fB.x, ax);
    ay = fmaf(vB, fB.y, ay);
  }
  for (; j + 2 <= end; j += 2) {
    int2 e0 = pvedge[j], e1 = pvedge[j + 1];
    int s = half ? e1.x : e0.x;
    float v = __int_as_float(half ? e1.y : e0.y);
    float2 f = __half22float2(ht2[(size_t)s * 32 + sub]);
    ax = fmaf(v, f.x, ax);
    ay = fmaf(v, f.y, ay);
  }
  if (j < end) {
    int2 e = pvedge[j];
    if (!half) {
      float2 f = __half22float2(ht2[(size_t)e.x * 32 + sub]);
      float v = __int_as_float(e.y);
      ax = fmaf(v, f.x, ax);
      ay = fmaf(v, f.y, ay);
    }
  }
  ax += __shfl_xor(ax, 32, 64);
  ay += __shfl_xor(ay, 32, 64);
  return make_float2(ax, ay);
}

// ---- layer-1: gather SpMM + identity postagg -------------------------------
__global__ __launch_bounds__(256) void k_spmm_post(
    const __half2* __restrict__ ht4, const int* __restrict__ rp4,
    const int2* __restrict__ pvedge, float* __restrict__ out4,
    float* __restrict__ aux4, int N) {
  int wave = threadIdx.x >> 6, lane = threadIdx.x & 63;
  int half = lane >> 5, sub = lane & 31;
  int row = blockIdx.x * 4 + wave;
  if (row >= N) return;
  int b = blockIdx.y;
  size_t R = (size_t)b * N + row;
  const __half2* ht = ht4 + (size_t)b * N * 32;
  int beg = __builtin_amdgcn_readfirstlane(rp4[R]);
  int end = __builtin_amdgcn_readfirstlane(rp4[R + 1]);
  float2 acc = gather_row_h2(ht, pvedge, beg, end, half, sub);
  float an = fmaxf(sqrtf(wsum32h(acc.x * acc.x + acc.y * acc.y)), 1e-30f);
  float s1 = an > kArtMaxF ? kArtMaxF / an : 1.0f;
  float tx = fmaxf(acc.x * s1, 0.0f), ty = fmaxf(acc.y * s1, 0.0f);
  float tn = fmaxf(sqrtf(wsum32h(tx * tx + ty * ty)), 1e-30f);
  float h2n = tanh_pos(tn);
  float sc = fminf(h2n, kMaxNormF) / tn;   // expmap0 + proj
  if (half == 0) {
    *reinterpret_cast<float2*>(&out4[R * 64 + sub * 2]) =
        make_float2(tx * sc, ty * sc);
    if (sub == 0) aux4[R] = fminf(tn, kArtMaxF);  // artanh(|h2|) exactly
  }
}

// ---- layer-2: SpMM + postagg + COMBINE fused; block=row, wave=branch -------
__global__ __launch_bounds__(256) void k_spmm_comb(
    const __half2* __restrict__ ht4, const int* __restrict__ rp4,
    const int2* __restrict__ pvedge, float* __restrict__ out, int N) {
  __shared__ float lf[4][64];
  __shared__ float latn[4], lnb[4];
  int b = threadIdx.x >> 6, lane = threadIdx.x & 63;
  int half = lane >> 5, sub = lane & 31;
  int row = blockIdx.x;
  size_t R = (size_t)b * N + row;
  const __half2* ht = ht4 + (size_t)b * N * 32;
  int beg = __builtin_amdgcn_readfirstlane(rp4[R]);
  int end = __builtin_amdgcn_readfirstlane(rp4[R + 1]);
  float2 acc = gather_row_h2(ht, pvedge, beg, end, half, sub);
  float an = fmaxf(sqrtf(wsum32h(acc.x * acc.x + acc.y * acc.y)), 1e-30f);
  float s1 = an > kArtMaxF ? kArtMaxF / an : 1.0f;
  float tx = fmaxf(acc.x * s1, 0.0f), ty = fmaxf(acc.y * s1, 0.0f);
  float tn = fmaxf(sqrtf(wsum32h(tx * tx + ty * ty)), 1e-30f);
  float h2n = tanh_pos(tn);
  float nb = fminf(h2n, kMaxNormF);
  float sc = nb / tn;
  if (half == 0)
    *reinterpret_cast<float2*>(&lf[b][sub * 2]) =
        make_float2(tx * sc, ty * sc);
  if (lane == 0) {
    latn[b] = fminf(tn, kArtMaxF);
    lnb[b] = fmaxf(nb, 1e-30f);
  }
  __syncthreads();
  if (b != 0) return;
  // combine (single wave): mulscaler(1/8) -> mobius chain -> mean logmap0
  float f[4], art[4], nbv[4], w[4], wn2[4], omw[4];
#pragma unroll
  for (int i = 0; i < 4; i++) {
    f[i] = lf[i][lane];
    art[i] = latn[i];
    nbv[i] = lnb[i];
    float wn = tanh_pos(art[i] * 0.125f);
    w[i] = (wn / nbv[i]) * f[i];
    wn2[i] = wn * wn;
    omw[i] = 1.0f - wn2[i];
  }
  float tgt = w[0], tx2 = wn2[0], omt = omw[0];
#pragma unroll
  for (int i = 1; i < 4; i++) {
    float xy = wsum32f(tgt * w[i]);
    float A = 1.f + 2.f * xy + wn2[i];
    float den = fmaxf(1.f + 2.f * xy + tx2 * wn2[i], 1e-15f);
    float rden = 1.0f / den;
    tgt = (A * tgt + omt * w[i]) * rden;
    omt = omt * omw[i] * rden;               // 1-|tgt|^2, stable
    tx2 = 1.0f - omt;
  }
  float tnc = fmaxf(sqrtf(fmaxf(tx2, 0.0f)), 1e-30f);
  float artt = 0.5f * __logf((1.f + tnc) * (1.f + tnc) / fmaxf(omt, 1e-30f));
  float m = (artt / tnc) * tgt;
#pragma unroll
  for (int i = 0; i < 4; i++) m += (art[i] / nbv[i]) * f[i];
  m *= 0.2f;
  float mn = fmaxf(sqrtf(wsum32f(m * m)), 1e-30f);
  float on = tanh_pos(mn);
  float pf = on > kMaxNormF ? kMaxNormF / on : 1.f;
  out[(size_t)row * 64 + lane] = m * (on / mn) * pf;
}

// ---------------------------------------------------------------------------
extern "C" void kernel_launch(void* const* d_in, const int* in_sizes, int n_in,
                              void* d_out, int out_size, void* d_ws,
                              size_t ws_size, hipStream_t stream) {
  const int FIN = 256, NB = 4;
  const int N = in_sizes[0] / FIN;       // 50000
  const int E = in_sizes[5] / NB;        // 800000
  const float* x = (const float*)d_in[0];
  const float* W1 = (const float*)d_in[1];
  const float* b1 = (const float*)d_in[2];
  const float* W2 = (const float*)d_in[3];
  const float* b2 = (const float*)d_in[4];
  const float* vals = (const float*)d_in[5];
  const int* src = (const int*)d_in[6];
  const int* dst = (const int*)d_in[7];
  float* out = (float*)d_out;
  const int n4 = NB * N;
  const int nbuck = (N + 127) >> 7;      // 391
  const int TB = NB * nbuck;

  char* w = (char*)d_ws;
  auto alloc = [&](size_t bytes) -> char* {
    char* p = w;
    w += (bytes + 255) & ~size_t(255);
    return p;
  };
  const int WF1 = NB * (FIN / 32) * 4 * 64 * 8;   // 65536 ushorts
  const int WF2 = NB * (64 / 32) * 4 * 64 * 8;    // 16384 ushorts
  unsigned short* Wf1h = (unsigned short*)alloc((size_t)WF1 * 2);
  unsigned short* Wf1l = (unsigned short*)alloc((size_t)WF1 * 2);
  unsigned short* Wf2h = (unsigned short*)alloc((size_t)WF2 * 2);
  unsigned short* Wf2l = (unsigned short*)alloc((size_t)WF2 * 2);
  float* hb1 = (float*)alloc(NB * 64 * 4);
  float* hb2 = (float*)alloc(NB * 64 * 4);
  float* y21 = (float*)alloc(NB * 4);
  float* y22 = (float*)alloc(NB * 4);
  float* omy1 = (float*)alloc(NB * 4);
  float* omy2 = (float*)alloc(NB * 4);
  float* auxT4 = (float*)alloc((size_t)n4 * 4);
  __half* Cb4 = (__half*)alloc((size_t)n4 * 64 * 2);   // f16 ht table
  float* A4 = (float*)alloc((size_t)n4 * 64 * 4);      // spmm out (f32)
  int* bcnt = (int*)alloc((size_t)TB * 4);
  int* boff = (int*)alloc(((size_t)TB + 1) * 4);
  int* bcur = (int*)alloc((size_t)TB * 4);
  int* rp4 = (int*)alloc(((size_t)n4 + 1) * 4);
  int2* pvedge = (int2*)alloc((size_t)NB * E * 8);
  // ebuf aliases Cb4 (dead until k_gemm1; both exactly 25.6MB)
  int2* ebuf = (int2*)Cb4;

  const int rowBlocks = (N + 3) / 4;
  const int g1Blocks = (N + 15) / 16;      // 3125: 16 rows/block, wave=branch
  const int g2Blocks = (N + 63) / 64;
  const int hBlocks = (E + 8191) / 8192;   // 98

  k_wprep<<<(WF1 / 8 + 255) / 256, 256, 0, stream>>>(W1, Wf1h, Wf1l, FIN, WF1 / 8);
  k_wprep<<<(WF2 / 8 + 255) / 256, 256, 0, stream>>>(W2, Wf2h, Wf2l, 64, WF2 / 8);
  k_bias<<<1, 512, 0, stream>>>(b1, b2, hb1, hb2, y21, y22, omy1, omy2);

  // ---- CSR build: bucketed counting sort over all 4 branches ----
  hipMemsetAsync(bcnt, 0, (size_t)TB * 4, stream);
  k_bhist<<<dim3(hBlocks, NB), 512, 0, stream>>>(dst, bcnt, E, nbuck);
  k_bscan<<<1, 256, 0, stream>>>(bcnt, boff, bcur, rp4, TB, n4, NB * E);
  k_bpart<<<dim3(hBlocks, NB), 512, 0, stream>>>(src, dst, vals, bcur, ebuf, E, nbuck);
  k_bfine<<<dim3(nbuck, NB), 256, 0, stream>>>(ebuf, boff, rp4, pvedge, N, nbuck);

  // ---- layer 1: GEMM(+tail fused) then SpMM(+postagg) ----
  k_gemm1<<<g1Blocks, 256, 0, stream>>>(x, Wf1h, Wf1l, Cb4, hb1, y21, omy1, N);
  k_spmm_post<<<dim3(rowBlocks, NB), 256, 0, stream>>>((const __half2*)Cb4, rp4,
                                                       pvedge, A4, auxT4, N);
  // ---- layer 2: GEMM(+tail fused) then SpMM+combine fused ----
  k_gemm2<<<dim3(g2Blocks, NB), 256, 0, stream>>>(A4, Wf2h, Wf2l, Cb4, auxT4,
                                                  hb2, y22, omy2, N);
  k_spmm_comb<<<N, 256, 0, stream>>>((const __half2*)Cb4, rp4, pvedge, out, N);
}

// Round 11
// 412.097 us; speedup vs baseline: 19.5211x; 1.0073x over previous
//
#include <hip/hip_runtime.h>
#include <hip/hip_fp16.h>
#include <math.h>

// ---------------------------------------------------------------------------
// DHYPR hyperbolic GNN encoder, MI355X (gfx950).  Round 11:
//  - gather addressing slimmed: edge records carry src*128 (byte offset);
//    gather address = uniform base + 32-bit voffset (saddr global_load),
//    no per-load shift/mul/64-bit carries.  fp16->f32 cvt folded into
//    v_fma_mix via adjacent fpext+fma.
// Everything else unchanged from round 10.
// ---------------------------------------------------------------------------

constexpr double kMaxNorm = 1.0 - 1e-5;   // (1-PROJ_EPS)/sqrt(c), c=1
constexpr double kMinNorm = 1e-15;
#define kMaxNormF 0.99999f
#define kArtMaxF  6.1030338f
#define kOmMaxF   1.99999e-5f                    // 1 - kMaxNorm^2

typedef __attribute__((ext_vector_type(8))) short short8v;   // 8 bf16
typedef __attribute__((ext_vector_type(4))) float f32x4;

__device__ inline double wsum64(double v) {
#pragma unroll
  for (int o = 32; o > 0; o >>= 1) v += __shfl_xor(v, o, 64);
  return v;
}
__device__ inline float wsum32f(float v) {
#pragma unroll
  for (int o = 32; o > 0; o >>= 1) v += __shfl_xor(v, o, 64);
  return v;
}
__device__ inline float wsum32h(float v) {  // sum within each 32-lane half
#pragma unroll
  for (int o = 1; o < 32; o <<= 1) v += __shfl_xor(v, o, 64);
  return v;
}
__device__ inline float qsum16(float v) {   // reduce within 16-lane group
#pragma unroll
  for (int o = 1; o < 16; o <<= 1) v += __shfl_xor(v, o, 64);
  return v;
}
__device__ inline float tanh_pos(float z) {  // z >= 0, cancellation-free
  float e = __expf(-2.0f * z);
  return (1.0f - e) / (1.0f + e);
}

__device__ inline unsigned short f2bf(float f) {  // RN-even f32->bf16
  union { float f; unsigned int u; } v{f};
  unsigned int r = v.u + 0x7fffu + ((v.u >> 16) & 1u);
  return (unsigned short)(r >> 16);
}
__device__ inline float bf2f(unsigned short h) {
  union { unsigned int u; float f; } v{(unsigned int)h << 16};
  return v.f;
}

// ---- hb = proj(expmap0(bias)) ; outputs f32 (+ y2, 1-y2 scalars) -----------
__global__ __launch_bounds__(512) void k_bias(const float* __restrict__ b1,
                                              const float* __restrict__ b2,
                                              float* __restrict__ hb1,
                                              float* __restrict__ hb2,
                                              float* __restrict__ y21,
                                              float* __restrict__ y22,
                                              float* __restrict__ omy1,
                                              float* __restrict__ omy2) {
  int w = threadIdx.x >> 6, lane = threadIdx.x & 63;
  const float* bs = (w < 4) ? (b1 + w * 64) : (b2 + (w - 4) * 64);
  double v = (double)bs[lane];
  double un = fmax(sqrt(wsum64(v * v)), kMinNorm);
  double pn = tanh(un);
  double pf = pn > kMaxNorm ? kMaxNorm / pn : 1.0;
  double p = v * (pn / un) * pf;
  float* hb = (w < 4) ? hb1 + w * 64 : hb2 + (w - 4) * 64;
  hb[lane] = (float)p;
  if (lane == 0) {
    double n = pn * pf;
    int i = (w < 4) ? w : w - 4;
    float* y2 = (w < 4) ? y21 : y22;
    float* omy = (w < 4) ? omy1 : omy2;
    y2[i] = (float)(n * n);
    omy[i] = (float)(1.0 - n * n);
  }
}

// ---- weight prep: fragment-ready bf16 hi/lo, layout [s][b][f][lane][8] -----
__global__ __launch_bounds__(256) void k_wprep(const float* __restrict__ W,
                                               unsigned short* __restrict__ Wfh,
                                               unsigned short* __restrict__ Wfl,
                                               int DIN, int tot) {
  int idx = blockIdx.x * 256 + threadIdx.x;
  if (idx >= tot) return;
  int lane = idx & 63;
  int t = idx >> 6;
  int f = t & 3; t >>= 2;
  int ks = DIN >> 5;
  int s = t % ks;
  int b = t / ks;
  int c = f * 16 + (lane & 15);
  int k = s * 32 + (lane >> 4) * 8;
  const float* wp = W + ((size_t)(b * 64 + c)) * DIN + k;
  size_t dst = (((size_t)(s * 4 + b) * 4 + f) * 64 + lane) * 8;
#pragma unroll
  for (int j = 0; j < 8; ++j) {
    float v = wp[j];
    unsigned short h = f2bf(v);
    unsigned short l = f2bf(v - bf2f(h));
    Wfh[dst + j] = h;
    Wfl[dst + j] = l;
  }
}

// ---- shared epilogue: full Mobius tail for one row-chain -------------------
__device__ inline void tail_chain(float mx[4], float sart_row,
                                  const float hbv[4], float y2, float omy) {
  float p = mx[0] * mx[0] + mx[1] * mx[1] + mx[2] * mx[2] + mx[3] * mx[3];
  float mxn = fmaxf(sqrtf(qsum16(p)), 1e-30f);
  float z = mxn * sart_row;
  float e = __expf(-2.0f * z);
  float r1 = 1.0f / (1.0f + e);
  float nmv = (1.0f - e) * r1;
  float om = 4.0f * e * r1 * r1;
  float pf1 = nmv > kMaxNormF ? kMaxNormF / nmv : 1.0f;   // proj
  float nmvc = nmv * pf1;
  float x2 = nmvc * nmvc;
  float omx = (pf1 < 1.0f) ? kOmMaxF : om;                // 1 - x2, stable
  float mvs = nmvc / mxn;
  float pxy = 0.0f;
#pragma unroll
  for (int f = 0; f < 4; ++f) {
    mx[f] = mvs * mx[f];
    pxy += mx[f] * hbv[f];
  }
  float xy = qsum16(pxy);
  float A = 1.0f + 2.0f * xy + y2;
  float den = fmaxf(1.0f + 2.0f * xy + x2 * y2, 1e-15f);
  float rden = 1.0f / den;
  float hn2 = (x2 + 2.0f * xy + y2) * rden;
  float omh = omx * omy * rden;                           // 1 - hn^2
  float hn = fmaxf(sqrtf(fmaxf(hn2, 0.0f)), 1e-30f);
  float pf2 = 1.0f;
  if (hn > kMaxNormF) {                                   // proj
    pf2 = kMaxNormF / hn;
    hn = kMaxNormF;
    omh = kOmMaxF;
  }
  float art = 0.5f * __logf((1.0f + hn) * (1.0f + hn) / omh);
  float hts = (art / hn) * pf2 * rden;
#pragma unroll
  for (int f = 0; f < 4; ++f)
    mx[f] = hts * (A * mx[f] + omx * hbv[f]);
}

// ---- layer-1 GEMM + prescale + FUSED tail; block = 16 rows, wave = branch --
__global__ __launch_bounds__(256) void k_gemm1(const float* __restrict__ X,
                                               const unsigned short* __restrict__ Wfh,
                                               const unsigned short* __restrict__ Wfl,
                                               __half* __restrict__ C4,
                                               const float* __restrict__ hbAll,
                                               const float* __restrict__ y2All,
                                               const float* __restrict__ omyAll,
                                               int N) {
  const int bb = threadIdx.x >> 6, lane = threadIdx.x & 63;
  const int r0 = blockIdx.x * 16;
  const int l = lane & 15, g = lane >> 4;
  const int arow = min(r0 + l, N - 1);
  const int kbase = g * 8;
  f32x4 acc[4] = {};
  double ss = 0.0;
#pragma unroll
  for (int s = 0; s < 8; ++s) {
    const float* ap = X + (size_t)arow * 256 + s * 32 + kbase;
    const float4 a0 = *reinterpret_cast<const float4*>(ap);
    const float4 a1 = *reinterpret_cast<const float4*>(ap + 4);
    float av[8] = {a0.x, a0.y, a0.z, a0.w, a1.x, a1.y, a1.z, a1.w};
    short8v ah, al;
#pragma unroll
    for (int j = 0; j < 8; ++j) {
      ss += (double)av[j] * av[j];
      unsigned short h = f2bf(av[j]);
      ah[j] = (short)h;
      al[j] = (short)f2bf(av[j] - bf2f(h));
    }
#pragma unroll
    for (int f = 0; f < 4; ++f) {
      size_t wi = (((size_t)(s * 4 + bb) * 4 + f) * 64 + lane) * 8;
      short8v bh = *reinterpret_cast<const short8v*>(Wfh + wi);
      short8v bl = *reinterpret_cast<const short8v*>(Wfl + wi);
      acc[f] = __builtin_amdgcn_mfma_f32_16x16x32_bf16(ah, bl, acc[f], 0, 0, 0);
      acc[f] = __builtin_amdgcn_mfma_f32_16x16x32_bf16(al, bh, acc[f], 0, 0, 0);
      acc[f] = __builtin_amdgcn_mfma_f32_16x16x32_bf16(ah, bh, acc[f], 0, 0, 0);
    }
  }
  // prescale for input row r0+l (expmap0(x) scale + artanh factor)
  ss += __shfl_xor(ss, 16, 64);
  ss += __shfl_xor(ss, 32, 64);
  float un = fmaxf(sqrtf((float)ss), 1e-30f);
  float pn = tanh_pos(un);
  float pfx = pn > kMaxNormF ? kMaxNormF / pn : 1.0f;
  float xn = fmaxf(pn * pfx, 1e-30f);
  float s_i = (pn / un) * pfx;
  float sart_i = fminf(un, kArtMaxF) / xn;   // artanh(xn)/xn exactly
  float hbv[4];
  float y2v = y2All[bb], omyv = omyAll[bb];
#pragma unroll
  for (int f = 0; f < 4; ++f) hbv[f] = hbAll[bb * 64 + f * 16 + l];
#pragma unroll
  for (int j = 0; j < 4; ++j) {
    int row = r0 + g * 4 + j;
    float s_row = __shfl(s_i, g * 4 + j, 64);
    float sart_row = __shfl(sart_i, g * 4 + j, 64);
    float mx[4] = {s_row * acc[0][j], s_row * acc[1][j], s_row * acc[2][j],
                   s_row * acc[3][j]};
    tail_chain(mx, sart_row, hbv, y2v, omyv);
    if (row < N) {
      size_t base = ((size_t)bb * N + row) * 64 + l;
      C4[base] = __float2half(mx[0]);
      C4[base + 16] = __float2half(mx[1]);
      C4[base + 32] = __float2half(mx[2]);
      C4[base + 48] = __float2half(mx[3]);
    }
  }
}

// ---- layer-2 GEMM + FUSED tail: per-branch (blockIdx.y), DIN=64 ------------
__global__ __launch_bounds__(256) void k_gemm2(const float* __restrict__ X4,
                                               const unsigned short* __restrict__ Wfh,
                                               const unsigned short* __restrict__ Wfl,
                                               __half* __restrict__ C4,
                                               const float* __restrict__ auxT4,
                                               const float* __restrict__ hbAll,
                                               const float* __restrict__ y2All,
                                               const float* __restrict__ omyAll,
                                               int N) {
  const int wave = threadIdx.x >> 6, lane = threadIdx.x & 63;
  const int b = blockIdx.y;
  const int r0 = blockIdx.x * 64 + wave * 16;
  const int l = lane & 15, g = lane >> 4;
  const int arow = min(r0 + l, N - 1);
  const int kbase = g * 8;
  const float* X = X4 + (size_t)b * N * 64;
  f32x4 acc[4] = {};
#pragma unroll
  for (int s = 0; s < 2; ++s) {
    const float* ap = X + (size_t)arow * 64 + s * 32 + kbase;
    const float4 a0 = *reinterpret_cast<const float4*>(ap);
    const float4 a1 = *reinterpret_cast<const float4*>(ap + 4);
    float av[8] = {a0.x, a0.y, a0.z, a0.w, a1.x, a1.y, a1.z, a1.w};
    short8v ah, al;
#pragma unroll
    for (int j = 0; j < 8; ++j) {
      unsigned short h = f2bf(av[j]);
      ah[j] = (short)h;
      al[j] = (short)f2bf(av[j] - bf2f(h));
    }
#pragma unroll
    for (int f = 0; f < 4; ++f) {
      size_t wi = (((size_t)(s * 4 + b) * 4 + f) * 64 + lane) * 8;
      short8v bh = *reinterpret_cast<const short8v*>(Wfh + wi);
      short8v bl = *reinterpret_cast<const short8v*>(Wfl + wi);
      acc[f] = __builtin_amdgcn_mfma_f32_16x16x32_bf16(ah, bl, acc[f], 0, 0, 0);
      acc[f] = __builtin_amdgcn_mfma_f32_16x16x32_bf16(al, bh, acc[f], 0, 0, 0);
      acc[f] = __builtin_amdgcn_mfma_f32_16x16x32_bf16(ah, bh, acc[f], 0, 0, 0);
    }
  }
  float atn = auxT4[(size_t)b * N + arow];
  float xn = fmaxf(tanh_pos(atn), 1e-30f);
  float sart_i = atn / xn;
  float hbv[4];
  float y2v = y2All[b], omyv = omyAll[b];
#pragma unroll
  for (int f = 0; f < 4; ++f) hbv[f] = hbAll[b * 64 + f * 16 + l];
#pragma unroll
  for (int j = 0; j < 4; ++j) {
    int row = r0 + g * 4 + j;
    float sart_row = __shfl(sart_i, g * 4 + j, 64);
    float mx[4] = {acc[0][j], acc[1][j], acc[2][j], acc[3][j]};
    tail_chain(mx, sart_row, hbv, y2v, omyv);
    if (row < N) {
      size_t base = ((size_t)b * N + row) * 64 + l;
      C4[base] = __float2half(mx[0]);
      C4[base + 16] = __float2half(mx[1]);
      C4[base + 32] = __float2half(mx[2]);
      C4[base + 48] = __float2half(mx[3]);
    }
  }
}

// ===================== CSR build: bucketed counting sort ====================
__global__ __launch_bounds__(512) void k_bhist(const int* __restrict__ dst,
                                               int* __restrict__ bcnt, int E,
                                               int nbuck) {
  __shared__ int lcnt[512];
  int tid = threadIdx.x;
  for (int k = tid; k < nbuck; k += 512) lcnt[k] = 0;
  __syncthreads();
  int b = blockIdx.y;
  int e0 = blockIdx.x * 8192;
  const int* db = dst + (size_t)b * E;
#pragma unroll
  for (int i = 0; i < 16; ++i) {
    int e = e0 + i * 512 + tid;
    if (e < E) atomicAdd(&lcnt[db[e] >> 7], 1);
  }
  __syncthreads();
  for (int k = tid; k < nbuck; k += 512) {
    int c = lcnt[k];
    if (c) atomicAdd(&bcnt[b * nbuck + k], c);
  }
}

__global__ __launch_bounds__(256) void k_bscan(const int* __restrict__ bcnt,
                                               int* __restrict__ boff,
                                               int* __restrict__ bcur,
                                               int* __restrict__ rp4, int TB,
                                               int n4, int Etot) {
  __shared__ int wsums[4];
  int t = threadIdx.x;
  int lane = t & 63, wv = t >> 6;
  int vals[8];
  int s = 0;
#pragma unroll
  for (int i = 0; i < 8; ++i) {
    int idx = t * 8 + i;
    int v = (idx < TB) ? bcnt[idx] : 0;
    vals[i] = s;
    s += v;
  }
  int incl = s;
#pragma unroll
  for (int o = 1; o < 64; o <<= 1) {
    int u = __shfl_up(incl, o, 64);
    if (lane >= o) incl += u;
  }
  if (lane == 63) wsums[wv] = incl;
  __syncthreads();
  int woff = 0;
  for (int i = 0; i < wv; ++i) woff += wsums[i];
  int texcl = woff + incl - s;
#pragma unroll
  for (int i = 0; i < 8; ++i) {
    int idx = t * 8 + i;
    if (idx < TB) {
      int o = texcl + vals[i];
      boff[idx] = o;
      bcur[idx] = o;
    }
  }
  if (t == 0) {
    boff[TB] = Etot;
    rp4[n4] = Etot;
  }
}

__global__ __launch_bounds__(512) void k_bpart(const int* __restrict__ src,
                                               const int* __restrict__ dst,
                                               const float* __restrict__ val,
                                               int* __restrict__ bcur,
                                               int2* __restrict__ ebuf, int E,
                                               int nbuck) {
  __shared__ int lcnt[512];
  __shared__ int lbase[512];
  int tid = threadIdx.x;
  for (int k = tid; k < nbuck; k += 512) lcnt[k] = 0;
  __syncthreads();
  int b = blockIdx.y;
  int e0 = blockIdx.x * 8192;
  const int* db = dst + (size_t)b * E;
  const int* sb = src + (size_t)b * E;
  const float* vb = val + (size_t)b * E;
#pragma unroll
  for (int i = 0; i < 16; ++i) {
    int e = e0 + i * 512 + tid;
    if (e < E) atomicAdd(&lcnt[db[e] >> 7], 1);
  }
  __syncthreads();
  for (int k = tid; k < nbuck; k += 512) {
    int c = lcnt[k];
    lbase[k] = c ? atomicAdd(&bcur[b * nbuck + k], c) : 0;
  }
  __syncthreads();
  for (int k = tid; k < nbuck; k += 512) lcnt[k] = 0;
  __syncthreads();
#pragma unroll
  for (int i = 0; i < 16; ++i) {
    int e = e0 + i * 512 + tid;
    if (e < E) {
      int d = db[e];
      int bk = d >> 7;
      int r = atomicAdd(&lcnt[bk], 1);
      int2 ev;
      ev.x = ((d & 127) << 17) | sb[e];
      ev.y = __float_as_int(vb[e]);
      ebuf[(size_t)lbase[bk] + r] = ev;
    }
  }
}

__global__ __launch_bounds__(256) void k_bfine(const int2* __restrict__ ebuf,
                                               const int* __restrict__ boff,
                                               int* __restrict__ rp4,
                                               int2* __restrict__ pvedge,
                                               int N, int nbuck) {
  __shared__ int ncnt[128], noff[128], ncur[128];
  __shared__ int w0tot;
  int tid = threadIdx.x;
  int br = blockIdx.y, bk = blockIdx.x;
  int idx = br * nbuck + bk;
  int ebeg = boff[idx], eend = boff[idx + 1];
  int n0 = bk << 7;
  int nn = min(128, N - n0);
  if (tid < 128) ncnt[tid] = 0;
  __syncthreads();
  for (int j = ebeg + tid; j < eend; j += 256)
    atomicAdd(&ncnt[ebuf[j].x >> 17], 1);
  __syncthreads();
  int v = (tid < 128) ? ncnt[tid] : 0;
  int lane = tid & 63;
  int incl = v;
#pragma unroll
  for (int o = 1; o < 64; o <<= 1) {
    int u = __shfl_up(incl, o, 64);
    if (lane >= o) incl += u;
  }
  if (tid == 63) w0tot = incl;
  __syncthreads();
  if (tid >= 64 && tid < 128) incl += w0tot;
  if (tid < 128) {
    noff[tid] = incl - v;
    ncur[tid] = incl - v;
  }
  __syncthreads();
  if (tid < nn) rp4[(size_t)br * N + n0 + tid] = ebeg + noff[tid];
  for (int j = ebeg + tid; j < eend; j += 256) {
    int2 ev = ebuf[j];
    int dl = ev.x >> 17;
    int pos = ebeg + atomicAdd(&ncur[dl], 1);
    // .x = src*128: byte offset of the f16 row (row = 64 halves = 128 B)
    pvedge[pos] = make_int2((ev.x & 0x1FFFF) << 7, ev.y);
  }
}

// ---- paired f16 gather, byte-offset edge records ---------------------------
// htb = branch table base (char*); edge .x = src*128.  Lane address =
// base + (.x + sub*4): one 32-bit add feeding saddr global_load.
__device__ inline float2 gather_row_h2(const char* __restrict__ htb,
                                       const int2* __restrict__ pvedge,
                                       int beg, int end, int half, int sub) {
  float ax = 0.0f, ay = 0.0f;
  const unsigned subOff = (unsigned)sub * 4u;
  int j = beg;
  for (; j + 4 <= end; j += 4) {
    int2 e0 = pvedge[j], e1 = pvedge[j + 1];
    int2 e2 = pvedge[j + 2], e3 = pvedge[j + 3];
    unsigned offA = (unsigned)(half ? e1.x : e0.x) + subOff;
    float vA = __int_as_float(half ? e1.y : e0.y);
    unsigned offB = (unsigned)(half ? e3.x : e2.x) + subOff;
    float vB = __int_as_float(half ? e3.y : e2.y);
    __half2 hA = *reinterpret_cast<const __half2*>(htb + offA);
    __half2 hB = *reinterpret_cast<const __half2*>(htb + offB);
    ax = fmaf(vA, __half2float(__low2half(hA)), ax);
    ay = fmaf(vA, __half2float(__high2half(hA)), ay);
    ax = fmaf(vB, __half2float(__low2half(hB)), ax);
    ay = fmaf(vB, __half2float(__high2half(hB)), ay);
  }
  for (; j + 2 <= end; j += 2) {
    int2 e0 = pvedge[j], e1 = pvedge[j + 1];
    unsigned off = (unsigned)(half ? e1.x : e0.x) + subOff;
    float v = __int_as_float(half ? e1.y : e0.y);
    __half2 h = *reinterpret_cast<const __half2*>(htb + off);
    ax = fmaf(v, __half2float(__low2half(h)), ax);
    ay = fmaf(v, __half2float(__high2half(h)), ay);
  }
  if (j < end) {
    int2 e = pvedge[j];
    if (!half) {
      unsigned off = (unsigned)e.x + subOff;
      __half2 h = *reinterpret_cast<const __half2*>(htb + off);
      float v = __int_as_float(e.y);
      ax = fmaf(v, __half2float(__low2half(h)), ax);
      ay = fmaf(v, __half2float(__high2half(h)), ay);
    }
  }
  ax += __shfl_xor(ax, 32, 64);
  ay += __shfl_xor(ay, 32, 64);
  return make_float2(ax, ay);
}

// ---- layer-1: gather SpMM + identity postagg -------------------------------
__global__ __launch_bounds__(256) void k_spmm_post(
    const __half* __restrict__ ht4, const int* __restrict__ rp4,
    const int2* __restrict__ pvedge, float* __restrict__ out4,
    float* __restrict__ aux4, int N) {
  int wave = threadIdx.x >> 6, lane = threadIdx.x & 63;
  int half = lane >> 5, sub = lane & 31;
  int row = blockIdx.x * 4 + wave;
  if (row >= N) return;
  int b = blockIdx.y;
  size_t R = (size_t)b * N + row;
  const char* htb = (const char*)(ht4 + (size_t)b * N * 64);
  int beg = __builtin_amdgcn_readfirstlane(rp4[R]);
  int end = __builtin_amdgcn_readfirstlane(rp4[R + 1]);
  float2 acc = gather_row_h2(htb, pvedge, beg, end, half, sub);
  float an = fmaxf(sqrtf(wsum32h(acc.x * acc.x + acc.y * acc.y)), 1e-30f);
  float s1 = an > kArtMaxF ? kArtMaxF / an : 1.0f;
  float tx = fmaxf(acc.x * s1, 0.0f), ty = fmaxf(acc.y * s1, 0.0f);
  float tn = fmaxf(sqrtf(wsum32h(tx * tx + ty * ty)), 1e-30f);
  float h2n = tanh_pos(tn);
  float sc = fminf(h2n, kMaxNormF) / tn;   // expmap0 + proj
  if (half == 0) {
    *reinterpret_cast<float2*>(&out4[R * 64 + sub * 2]) =
        make_float2(tx * sc, ty * sc);
    if (sub == 0) aux4[R] = fminf(tn, kArtMaxF);  // artanh(|h2|) exactly
  }
}

// ---- layer-2: SpMM + postagg + COMBINE fused; block=row, wave=branch -------
__global__ __launch_bounds__(256) void k_spmm_comb(
    const __half* __restrict__ ht4, const int* __restrict__ rp4,
    const int2* __restrict__ pvedge, float* __restrict__ out, int N) {
  __shared__ float lf[4][64];
  __shared__ float latn[4], lnb[4];
  int b = threadIdx.x >> 6, lane = threadIdx.x & 63;
  int half = lane >> 5, sub = lane & 31;
  int row = blockIdx.x;
  size_t R = (size_t)b * N + row;
  const char* htb = (const char*)(ht4 + (size_t)b * N * 64);
  int beg = __builtin_amdgcn_readfirstlane(rp4[R]);
  int end = __builtin_amdgcn_readfirstlane(rp4[R + 1]);
  float2 acc = gather_row_h2(htb, pvedge, beg, end, half, sub);
  float an = fmaxf(sqrtf(wsum32h(acc.x * acc.x + acc.y * acc.y)), 1e-30f);
  float s1 = an > kArtMaxF ? kArtMaxF / an : 1.0f;
  float tx = fmaxf(acc.x * s1, 0.0f), ty = fmaxf(acc.y * s1, 0.0f);
  float tn = fmaxf(sqrtf(wsum32h(tx * tx + ty * ty)), 1e-30f);
  float h2n = tanh_pos(tn);
  float nb = fminf(h2n, kMaxNormF);
  float sc = nb / tn;
  if (half == 0)
    *reinterpret_cast<float2*>(&lf[b][sub * 2]) =
        make_float2(tx * sc, ty * sc);
  if (lane == 0) {
    latn[b] = fminf(tn, kArtMaxF);
    lnb[b] = fmaxf(nb, 1e-30f);
  }
  __syncthreads();
  if (b != 0) return;
  // combine (single wave): mulscaler(1/8) -> mobius chain -> mean logmap0
  float f[4], art[4], nbv[4], w[4], wn2[4], omw[4];
#pragma unroll
  for (int i = 0; i < 4; i++) {
    f[i] = lf[i][lane];
    art[i] = latn[i];
    nbv[i] = lnb[i];
    float wn = tanh_pos(art[i] * 0.125f);
    w[i] = (wn / nbv[i]) * f[i];
    wn2[i] = wn * wn;
    omw[i] = 1.0f - wn2[i];
  }
  float tgt = w[0], tx2 = wn2[0], omt = omw[0];
#pragma unroll
  for (int i = 1; i < 4; i++) {
    float xy = wsum32f(tgt * w[i]);
    float A = 1.f + 2.f * xy + wn2[i];
    float den = fmaxf(1.f + 2.f * xy + tx2 * wn2[i], 1e-15f);
    float rden = 1.0f / den;
    tgt = (A * tgt + omt * w[i]) * rden;
    omt = omt * omw[i] * rden;               // 1-|tgt|^2, stable
    tx2 = 1.0f - omt;
  }
  float tnc = fmaxf(sqrtf(fmaxf(tx2, 0.0f)), 1e-30f);
  float artt = 0.5f * __logf((1.f + tnc) * (1.f + tnc) / fmaxf(omt, 1e-30f));
  float m = (artt / tnc) * tgt;
#pragma unroll
  for (int i = 0; i < 4; i++) m += (art[i] / nbv[i]) * f[i];
  m *= 0.2f;
  float mn = fmaxf(sqrtf(wsum32f(m * m)), 1e-30f);
  float on = tanh_pos(mn);
  float pf = on > kMaxNormF ? kMaxNormF / on : 1.f;
  out[(size_t)row * 64 + lane] = m * (on / mn) * pf;
}

// ---------------------------------------------------------------------------
extern "C" void kernel_launch(void* const* d_in, const int* in_sizes, int n_in,
                              void* d_out, int out_size, void* d_ws,
                              size_t ws_size, hipStream_t stream) {
  const int FIN = 256, NB = 4;
  const int N = in_sizes[0] / FIN;       // 50000
  const int E = in_sizes[5] / NB;        // 800000
  const float* x = (const float*)d_in[0];
  const float* W1 = (const float*)d_in[1];
  const float* b1 = (const float*)d_in[2];
  const float* W2 = (const float*)d_in[3];
  const float* b2 = (const float*)d_in[4];
  const float* vals = (const float*)d_in[5];
  const int* src = (const int*)d_in[6];
  const int* dst = (const int*)d_in[7];
  float* out = (float*)d_out;
  const int n4 = NB * N;
  const int nbuck = (N + 127) >> 7;      // 391
  const int TB = NB * nbuck;

  char* w = (char*)d_ws;
  auto alloc = [&](size_t bytes) -> char* {
    char* p = w;
    w += (bytes + 255) & ~size_t(255);
    return p;
  };
  const int WF1 = NB * (FIN / 32) * 4 * 64 * 8;   // 65536 ushorts
  const int WF2 = NB * (64 / 32) * 4 * 64 * 8;    // 16384 ushorts
  unsigned short* Wf1h = (unsigned short*)alloc((size_t)WF1 * 2);
  unsigned short* Wf1l = (unsigned short*)alloc((size_t)WF1 * 2);
  unsigned short* Wf2h = (unsigned short*)alloc((size_t)WF2 * 2);
  unsigned short* Wf2l = (unsigned short*)alloc((size_t)WF2 * 2);
  float* hb1 = (float*)alloc(NB * 64 * 4);
  float* hb2 = (float*)alloc(NB * 64 * 4);
  float* y21 = (float*)alloc(NB * 4);
  float* y22 = (float*)alloc(NB * 4);
  float* omy1 = (float*)alloc(NB * 4);
  float* omy2 = (float*)alloc(NB * 4);
  float* auxT4 = (float*)alloc((size_t)n4 * 4);
  __half* Cb4 = (__half*)alloc((size_t)n4 * 64 * 2);   // f16 ht table
  float* A4 = (float*)alloc((size_t)n4 * 64 * 4);      // spmm out (f32)
  int* bcnt = (int*)alloc((size_t)TB * 4);
  int* boff = (int*)alloc(((size_t)TB + 1) * 4);
  int* bcur = (int*)alloc((size_t)TB * 4);
  int* rp4 = (int*)alloc(((size_t)n4 + 1) * 4);
  int2* pvedge = (int2*)alloc((size_t)NB * E * 8);
  // ebuf aliases Cb4 (dead until k_gemm1; both exactly 25.6MB)
  int2* ebuf = (int2*)Cb4;

  const int rowBlocks = (N + 3) / 4;
  const int g1Blocks = (N + 15) / 16;      // 3125: 16 rows/block, wave=branch
  const int g2Blocks = (N + 63) / 64;
  const int hBlocks = (E + 8191) / 8192;   // 98

  k_wprep<<<(WF1 / 8 + 255) / 256, 256, 0, stream>>>(W1, Wf1h, Wf1l, FIN, WF1 / 8);
  k_wprep<<<(WF2 / 8 + 255) / 256, 256, 0, stream>>>(W2, Wf2h, Wf2l, 64, WF2 / 8);
  k_bias<<<1, 512, 0, stream>>>(b1, b2, hb1, hb2, y21, y22, omy1, omy2);

  // ---- CSR build: bucketed counting sort over all 4 branches ----
  hipMemsetAsync(bcnt, 0, (size_t)TB * 4, stream);
  k_bhist<<<dim3(hBlocks, NB), 512, 0, stream>>>(dst, bcnt, E, nbuck);
  k_bscan<<<1, 256, 0, stream>>>(bcnt, boff, bcur, rp4, TB, n4, NB * E);
  k_bpart<<<dim3(hBlocks, NB), 512, 0, stream>>>(src, dst, vals, bcur, ebuf, E, nbuck);
  k_bfine<<<dim3(nbuck, NB), 256, 0, stream>>>(ebuf, boff, rp4, pvedge, N, nbuck);

  // ---- layer 1: GEMM(+tail fused) then SpMM(+postagg) ----
  k_gemm1<<<g1Blocks, 256, 0, stream>>>(x, Wf1h, Wf1l, Cb4, hb1, y21, omy1, N);
  k_spmm_post<<<dim3(rowBlocks, NB), 256, 0, stream>>>(Cb4, rp4, pvedge, A4,
                                                       auxT4, N);
  // ---- layer 2: GEMM(+tail fused) then SpMM+combine fused ----
  k_gemm2<<<dim3(g2Blocks, NB), 256, 0, stream>>>(A4, Wf2h, Wf2l, Cb4, auxT4,
                                                  hb2, y22, omy2, N);
  k_spmm_comb<<<N, 256, 0, stream>>>(Cb4, rp4, pvedge, out, N);
}

// Round 12
// 381.280 us; speedup vs baseline: 21.0989x; 1.0808x over previous
//
#include <hip/hip_runtime.h>
#include <hip/hip_fp16.h>
#include <math.h>

// ---------------------------------------------------------------------------
// DHYPR hyperbolic GNN encoder, MI355X (gfx950).  Round 12:
//  - gather loop deepened: 16-edge chunks. All 16 wave-uniform edge records
//    read upfront (wide s_loads, one lgkm wait), then 8 per-lane gathers
//    issued back-to-back (one vmcnt region). Remainder = one clamped+masked
//    chunk. Rows now take 1-2 dependent round trips instead of 4-8.
// Everything else unchanged from round 11.
// ---------------------------------------------------------------------------

constexpr double kMaxNorm = 1.0 - 1e-5;   // (1-PROJ_EPS)/sqrt(c), c=1
constexpr double kMinNorm = 1e-15;
#define kMaxNormF 0.99999f
#define kArtMaxF  6.1030338f
#define kOmMaxF   1.99999e-5f                    // 1 - kMaxNorm^2

typedef __attribute__((ext_vector_type(8))) short short8v;   // 8 bf16
typedef __attribute__((ext_vector_type(4))) float f32x4;

__device__ inline double wsum64(double v) {
#pragma unroll
  for (int o = 32; o > 0; o >>= 1) v += __shfl_xor(v, o, 64);
  return v;
}
__device__ inline float wsum32f(float v) {
#pragma unroll
  for (int o = 32; o > 0; o >>= 1) v += __shfl_xor(v, o, 64);
  return v;
}
__device__ inline float wsum32h(float v) {  // sum within each 32-lane half
#pragma unroll
  for (int o = 1; o < 32; o <<= 1) v += __shfl_xor(v, o, 64);
  return v;
}
__device__ inline float qsum16(float v) {   // reduce within 16-lane group
#pragma unroll
  for (int o = 1; o < 16; o <<= 1) v += __shfl_xor(v, o, 64);
  return v;
}
__device__ inline float tanh_pos(float z) {  // z >= 0, cancellation-free
  float e = __expf(-2.0f * z);
  return (1.0f - e) / (1.0f + e);
}

__device__ inline unsigned short f2bf(float f) {  // RN-even f32->bf16
  union { float f; unsigned int u; } v{f};
  unsigned int r = v.u + 0x7fffu + ((v.u >> 16) & 1u);
  return (unsigned short)(r >> 16);
}
__device__ inline float bf2f(unsigned short h) {
  union { unsigned int u; float f; } v{(unsigned int)h << 16};
  return v.f;
}

// ---- hb = proj(expmap0(bias)) ; outputs f32 (+ y2, 1-y2 scalars) -----------
__global__ __launch_bounds__(512) void k_bias(const float* __restrict__ b1,
                                              const float* __restrict__ b2,
                                              float* __restrict__ hb1,
                                              float* __restrict__ hb2,
                                              float* __restrict__ y21,
                                              float* __restrict__ y22,
                                              float* __restrict__ omy1,
                                              float* __restrict__ omy2) {
  int w = threadIdx.x >> 6, lane = threadIdx.x & 63;
  const float* bs = (w < 4) ? (b1 + w * 64) : (b2 + (w - 4) * 64);
  double v = (double)bs[lane];
  double un = fmax(sqrt(wsum64(v * v)), kMinNorm);
  double pn = tanh(un);
  double pf = pn > kMaxNorm ? kMaxNorm / pn : 1.0;
  double p = v * (pn / un) * pf;
  float* hb = (w < 4) ? hb1 + w * 64 : hb2 + (w - 4) * 64;
  hb[lane] = (float)p;
  if (lane == 0) {
    double n = pn * pf;
    int i = (w < 4) ? w : w - 4;
    float* y2 = (w < 4) ? y21 : y22;
    float* omy = (w < 4) ? omy1 : omy2;
    y2[i] = (float)(n * n);
    omy[i] = (float)(1.0 - n * n);
  }
}

// ---- weight prep: fragment-ready bf16 hi/lo, layout [s][b][f][lane][8] -----
__global__ __launch_bounds__(256) void k_wprep(const float* __restrict__ W,
                                               unsigned short* __restrict__ Wfh,
                                               unsigned short* __restrict__ Wfl,
                                               int DIN, int tot) {
  int idx = blockIdx.x * 256 + threadIdx.x;
  if (idx >= tot) return;
  int lane = idx & 63;
  int t = idx >> 6;
  int f = t & 3; t >>= 2;
  int ks = DIN >> 5;
  int s = t % ks;
  int b = t / ks;
  int c = f * 16 + (lane & 15);
  int k = s * 32 + (lane >> 4) * 8;
  const float* wp = W + ((size_t)(b * 64 + c)) * DIN + k;
  size_t dst = (((size_t)(s * 4 + b) * 4 + f) * 64 + lane) * 8;
#pragma unroll
  for (int j = 0; j < 8; ++j) {
    float v = wp[j];
    unsigned short h = f2bf(v);
    unsigned short l = f2bf(v - bf2f(h));
    Wfh[dst + j] = h;
    Wfl[dst + j] = l;
  }
}

// ---- shared epilogue: full Mobius tail for one row-chain -------------------
__device__ inline void tail_chain(float mx[4], float sart_row,
                                  const float hbv[4], float y2, float omy) {
  float p = mx[0] * mx[0] + mx[1] * mx[1] + mx[2] * mx[2] + mx[3] * mx[3];
  float mxn = fmaxf(sqrtf(qsum16(p)), 1e-30f);
  float z = mxn * sart_row;
  float e = __expf(-2.0f * z);
  float r1 = 1.0f / (1.0f + e);
  float nmv = (1.0f - e) * r1;
  float om = 4.0f * e * r1 * r1;
  float pf1 = nmv > kMaxNormF ? kMaxNormF / nmv : 1.0f;   // proj
  float nmvc = nmv * pf1;
  float x2 = nmvc * nmvc;
  float omx = (pf1 < 1.0f) ? kOmMaxF : om;                // 1 - x2, stable
  float mvs = nmvc / mxn;
  float pxy = 0.0f;
#pragma unroll
  for (int f = 0; f < 4; ++f) {
    mx[f] = mvs * mx[f];
    pxy += mx[f] * hbv[f];
  }
  float xy = qsum16(pxy);
  float A = 1.0f + 2.0f * xy + y2;
  float den = fmaxf(1.0f + 2.0f * xy + x2 * y2, 1e-15f);
  float rden = 1.0f / den;
  float hn2 = (x2 + 2.0f * xy + y2) * rden;
  float omh = omx * omy * rden;                           // 1 - hn^2
  float hn = fmaxf(sqrtf(fmaxf(hn2, 0.0f)), 1e-30f);
  float pf2 = 1.0f;
  if (hn > kMaxNormF) {                                   // proj
    pf2 = kMaxNormF / hn;
    hn = kMaxNormF;
    omh = kOmMaxF;
  }
  float art = 0.5f * __logf((1.0f + hn) * (1.0f + hn) / omh);
  float hts = (art / hn) * pf2 * rden;
#pragma unroll
  for (int f = 0; f < 4; ++f)
    mx[f] = hts * (A * mx[f] + omx * hbv[f]);
}

// ---- layer-1 GEMM + prescale + FUSED tail; block = 16 rows, wave = branch --
__global__ __launch_bounds__(256) void k_gemm1(const float* __restrict__ X,
                                               const unsigned short* __restrict__ Wfh,
                                               const unsigned short* __restrict__ Wfl,
                                               __half* __restrict__ C4,
                                               const float* __restrict__ hbAll,
                                               const float* __restrict__ y2All,
                                               const float* __restrict__ omyAll,
                                               int N) {
  const int bb = threadIdx.x >> 6, lane = threadIdx.x & 63;
  const int r0 = blockIdx.x * 16;
  const int l = lane & 15, g = lane >> 4;
  const int arow = min(r0 + l, N - 1);
  const int kbase = g * 8;
  f32x4 acc[4] = {};
  double ss = 0.0;
#pragma unroll
  for (int s = 0; s < 8; ++s) {
    const float* ap = X + (size_t)arow * 256 + s * 32 + kbase;
    const float4 a0 = *reinterpret_cast<const float4*>(ap);
    const float4 a1 = *reinterpret_cast<const float4*>(ap + 4);
    float av[8] = {a0.x, a0.y, a0.z, a0.w, a1.x, a1.y, a1.z, a1.w};
    short8v ah, al;
#pragma unroll
    for (int j = 0; j < 8; ++j) {
      ss += (double)av[j] * av[j];
      unsigned short h = f2bf(av[j]);
      ah[j] = (short)h;
      al[j] = (short)f2bf(av[j] - bf2f(h));
    }
#pragma unroll
    for (int f = 0; f < 4; ++f) {
      size_t wi = (((size_t)(s * 4 + bb) * 4 + f) * 64 + lane) * 8;
      short8v bh = *reinterpret_cast<const short8v*>(Wfh + wi);
      short8v bl = *reinterpret_cast<const short8v*>(Wfl + wi);
      acc[f] = __builtin_amdgcn_mfma_f32_16x16x32_bf16(ah, bl, acc[f], 0, 0, 0);
      acc[f] = __builtin_amdgcn_mfma_f32_16x16x32_bf16(al, bh, acc[f], 0, 0, 0);
      acc[f] = __builtin_amdgcn_mfma_f32_16x16x32_bf16(ah, bh, acc[f], 0, 0, 0);
    }
  }
  // prescale for input row r0+l (expmap0(x) scale + artanh factor)
  ss += __shfl_xor(ss, 16, 64);
  ss += __shfl_xor(ss, 32, 64);
  float un = fmaxf(sqrtf((float)ss), 1e-30f);
  float pn = tanh_pos(un);
  float pfx = pn > kMaxNormF ? kMaxNormF / pn : 1.0f;
  float xn = fmaxf(pn * pfx, 1e-30f);
  float s_i = (pn / un) * pfx;
  float sart_i = fminf(un, kArtMaxF) / xn;   // artanh(xn)/xn exactly
  float hbv[4];
  float y2v = y2All[bb], omyv = omyAll[bb];
#pragma unroll
  for (int f = 0; f < 4; ++f) hbv[f] = hbAll[bb * 64 + f * 16 + l];
#pragma unroll
  for (int j = 0; j < 4; ++j) {
    int row = r0 + g * 4 + j;
    float s_row = __shfl(s_i, g * 4 + j, 64);
    float sart_row = __shfl(sart_i, g * 4 + j, 64);
    float mx[4] = {s_row * acc[0][j], s_row * acc[1][j], s_row * acc[2][j],
                   s_row * acc[3][j]};
    tail_chain(mx, sart_row, hbv, y2v, omyv);
    if (row < N) {
      size_t base = ((size_t)bb * N + row) * 64 + l;
      C4[base] = __float2half(mx[0]);
      C4[base + 16] = __float2half(mx[1]);
      C4[base + 32] = __float2half(mx[2]);
      C4[base + 48] = __float2half(mx[3]);
    }
  }
}

// ---- layer-2 GEMM + FUSED tail: per-branch (blockIdx.y), DIN=64 ------------
__global__ __launch_bounds__(256) void k_gemm2(const float* __restrict__ X4,
                                               const unsigned short* __restrict__ Wfh,
                                               const unsigned short* __restrict__ Wfl,
                                               __half* __restrict__ C4,
                                               const float* __restrict__ auxT4,
                                               const float* __restrict__ hbAll,
                                               const float* __restrict__ y2All,
                                               const float* __restrict__ omyAll,
                                               int N) {
  const int wave = threadIdx.x >> 6, lane = threadIdx.x & 63;
  const int b = blockIdx.y;
  const int r0 = blockIdx.x * 64 + wave * 16;
  const int l = lane & 15, g = lane >> 4;
  const int arow = min(r0 + l, N - 1);
  const int kbase = g * 8;
  const float* X = X4 + (size_t)b * N * 64;
  f32x4 acc[4] = {};
#pragma unroll
  for (int s = 0; s < 2; ++s) {
    const float* ap = X + (size_t)arow * 64 + s * 32 + kbase;
    const float4 a0 = *reinterpret_cast<const float4*>(ap);
    const float4 a1 = *reinterpret_cast<const float4*>(ap + 4);
    float av[8] = {a0.x, a0.y, a0.z, a0.w, a1.x, a1.y, a1.z, a1.w};
    short8v ah, al;
#pragma unroll
    for (int j = 0; j < 8; ++j) {
      unsigned short h = f2bf(av[j]);
      ah[j] = (short)h;
      al[j] = (short)f2bf(av[j] - bf2f(h));
    }
#pragma unroll
    for (int f = 0; f < 4; ++f) {
      size_t wi = (((size_t)(s * 4 + b) * 4 + f) * 64 + lane) * 8;
      short8v bh = *reinterpret_cast<const short8v*>(Wfh + wi);
      short8v bl = *reinterpret_cast<const short8v*>(Wfl + wi);
      acc[f] = __builtin_amdgcn_mfma_f32_16x16x32_bf16(ah, bl, acc[f], 0, 0, 0);
      acc[f] = __builtin_amdgcn_mfma_f32_16x16x32_bf16(al, bh, acc[f], 0, 0, 0);
      acc[f] = __builtin_amdgcn_mfma_f32_16x16x32_bf16(ah, bh, acc[f], 0, 0, 0);
    }
  }
  float atn = auxT4[(size_t)b * N + arow];
  float xn = fmaxf(tanh_pos(atn), 1e-30f);
  float sart_i = atn / xn;
  float hbv[4];
  float y2v = y2All[b], omyv = omyAll[b];
#pragma unroll
  for (int f = 0; f < 4; ++f) hbv[f] = hbAll[b * 64 + f * 16 + l];
#pragma unroll
  for (int j = 0; j < 4; ++j) {
    int row = r0 + g * 4 + j;
    float sart_row = __shfl(sart_i, g * 4 + j, 64);
    float mx[4] = {acc[0][j], acc[1][j], acc[2][j], acc[3][j]};
    tail_chain(mx, sart_row, hbv, y2v, omyv);
    if (row < N) {
      size_t base = ((size_t)b * N + row) * 64 + l;
      C4[base] = __float2half(mx[0]);
      C4[base + 16] = __float2half(mx[1]);
      C4[base + 32] = __float2half(mx[2]);
      C4[base + 48] = __float2half(mx[3]);
    }
  }
}

// ===================== CSR build: bucketed counting sort ====================
__global__ __launch_bounds__(512) void k_bhist(const int* __restrict__ dst,
                                               int* __restrict__ bcnt, int E,
                                               int nbuck) {
  __shared__ int lcnt[512];
  int tid = threadIdx.x;
  for (int k = tid; k < nbuck; k += 512) lcnt[k] = 0;
  __syncthreads();
  int b = blockIdx.y;
  int e0 = blockIdx.x * 8192;
  const int* db = dst + (size_t)b * E;
#pragma unroll
  for (int i = 0; i < 16; ++i) {
    int e = e0 + i * 512 + tid;
    if (e < E) atomicAdd(&lcnt[db[e] >> 7], 1);
  }
  __syncthreads();
  for (int k = tid; k < nbuck; k += 512) {
    int c = lcnt[k];
    if (c) atomicAdd(&bcnt[b * nbuck + k], c);
  }
}

__global__ __launch_bounds__(256) void k_bscan(const int* __restrict__ bcnt,
                                               int* __restrict__ boff,
                                               int* __restrict__ bcur,
                                               int* __restrict__ rp4, int TB,
                                               int n4, int Etot) {
  __shared__ int wsums[4];
  int t = threadIdx.x;
  int lane = t & 63, wv = t >> 6;
  int vals[8];
  int s = 0;
#pragma unroll
  for (int i = 0; i < 8; ++i) {
    int idx = t * 8 + i;
    int v = (idx < TB) ? bcnt[idx] : 0;
    vals[i] = s;
    s += v;
  }
  int incl = s;
#pragma unroll
  for (int o = 1; o < 64; o <<= 1) {
    int u = __shfl_up(incl, o, 64);
    if (lane >= o) incl += u;
  }
  if (lane == 63) wsums[wv] = incl;
  __syncthreads();
  int woff = 0;
  for (int i = 0; i < wv; ++i) woff += wsums[i];
  int texcl = woff + incl - s;
#pragma unroll
  for (int i = 0; i < 8; ++i) {
    int idx = t * 8 + i;
    if (idx < TB) {
      int o = texcl + vals[i];
      boff[idx] = o;
      bcur[idx] = o;
    }
  }
  if (t == 0) {
    boff[TB] = Etot;
    rp4[n4] = Etot;
  }
}

__global__ __launch_bounds__(512) void k_bpart(const int* __restrict__ src,
                                               const int* __restrict__ dst,
                                               const float* __restrict__ val,
                                               int* __restrict__ bcur,
                                               int2* __restrict__ ebuf, int E,
                                               int nbuck) {
  __shared__ int lcnt[512];
  __shared__ int lbase[512];
  int tid = threadIdx.x;
  for (int k = tid; k < nbuck; k += 512) lcnt[k] = 0;
  __syncthreads();
  int b = blockIdx.y;
  int e0 = blockIdx.x * 8192;
  const int* db = dst + (size_t)b * E;
  const int* sb = src + (size_t)b * E;
  const float* vb = val + (size_t)b * E;
#pragma unroll
  for (int i = 0; i < 16; ++i) {
    int e = e0 + i * 512 + tid;
    if (e < E) atomicAdd(&lcnt[db[e] >> 7], 1);
  }
  __syncthreads();
  for (int k = tid; k < nbuck; k += 512) {
    int c = lcnt[k];
    lbase[k] = c ? atomicAdd(&bcur[b * nbuck + k], c) : 0;
  }
  __syncthreads();
  for (int k = tid; k < nbuck; k += 512) lcnt[k] = 0;
  __syncthreads();
#pragma unroll
  for (int i = 0; i < 16; ++i) {
    int e = e0 + i * 512 + tid;
    if (e < E) {
      int d = db[e];
      int bk = d >> 7;
      int r = atomicAdd(&lcnt[bk], 1);
      int2 ev;
      ev.x = ((d & 127) << 17) | sb[e];
      ev.y = __float_as_int(vb[e]);
      ebuf[(size_t)lbase[bk] + r] = ev;
    }
  }
}

__global__ __launch_bounds__(256) void k_bfine(const int2* __restrict__ ebuf,
                                               const int* __restrict__ boff,
                                               int* __restrict__ rp4,
                                               int2* __restrict__ pvedge,
                                               int N, int nbuck) {
  __shared__ int ncnt[128], noff[128], ncur[128];
  __shared__ int w0tot;
  int tid = threadIdx.x;
  int br = blockIdx.y, bk = blockIdx.x;
  int idx = br * nbuck + bk;
  int ebeg = boff[idx], eend = boff[idx + 1];
  int n0 = bk << 7;
  int nn = min(128, N - n0);
  if (tid < 128) ncnt[tid] = 0;
  __syncthreads();
  for (int j = ebeg + tid; j < eend; j += 256)
    atomicAdd(&ncnt[ebuf[j].x >> 17], 1);
  __syncthreads();
  int v = (tid < 128) ? ncnt[tid] : 0;
  int lane = tid & 63;
  int incl = v;
#pragma unroll
  for (int o = 1; o < 64; o <<= 1) {
    int u = __shfl_up(incl, o, 64);
    if (lane >= o) incl += u;
  }
  if (tid == 63) w0tot = incl;
  __syncthreads();
  if (tid >= 64 && tid < 128) incl += w0tot;
  if (tid < 128) {
    noff[tid] = incl - v;
    ncur[tid] = incl - v;
  }
  __syncthreads();
  if (tid < nn) rp4[(size_t)br * N + n0 + tid] = ebeg + noff[tid];
  for (int j = ebeg + tid; j < eend; j += 256) {
    int2 ev = ebuf[j];
    int dl = ev.x >> 17;
    int pos = ebeg + atomicAdd(&ncur[dl], 1);
    // .x = src*128: byte offset of the f16 row (row = 64 halves = 128 B)
    pvedge[pos] = make_int2((ev.x & 0x1FFFF) << 7, ev.y);
  }
}

// ---- paired f16 gather, 16-edge chunks, records read upfront ---------------
// htb = branch table base; edge .x = src*128 byte offset. Lanes 0-31 take
// even edges, 32-63 odd. One lgkm wait + one vmcnt region per chunk.
__device__ inline float2 gather_row16(const char* __restrict__ htb,
                                      const int2* __restrict__ pvedge,
                                      int beg, int end, int half, int sub) {
  float ax = 0.0f, ay = 0.0f;
  const unsigned subOff = (unsigned)sub * 4u;
  int j = beg;
  for (; j + 16 <= end; j += 16) {
    int2 e[16];
#pragma unroll
    for (int k = 0; k < 16; ++k) e[k] = pvedge[j + k];
#pragma unroll
    for (int k = 0; k < 8; ++k) {
      int2 eh = half ? e[2 * k + 1] : e[2 * k];
      __half2 h =
          *reinterpret_cast<const __half2*>(htb + ((unsigned)eh.x + subOff));
      float v = __int_as_float(eh.y);
      ax = fmaf(v, __half2float(__low2half(h)), ax);
      ay = fmaf(v, __half2float(__high2half(h)), ay);
    }
  }
  if (j < end) {  // clamped+masked final chunk (dummy gathers hit last row)
    int last = end - 1;
    int2 e[16];
#pragma unroll
    for (int k = 0; k < 16; ++k) e[k] = pvedge[min(j + k, last)];
#pragma unroll
    for (int k = 0; k < 8; ++k) {
      int idx = 2 * k + half;
      int2 eh = half ? e[2 * k + 1] : e[2 * k];
      __half2 h =
          *reinterpret_cast<const __half2*>(htb + ((unsigned)eh.x + subOff));
      float v = (j + idx < end) ? __int_as_float(eh.y) : 0.0f;
      ax = fmaf(v, __half2float(__low2half(h)), ax);
      ay = fmaf(v, __half2float(__high2half(h)), ay);
    }
  }
  ax += __shfl_xor(ax, 32, 64);
  ay += __shfl_xor(ay, 32, 64);
  return make_float2(ax, ay);
}

// ---- layer-1: gather SpMM + identity postagg -------------------------------
__global__ __launch_bounds__(256) void k_spmm_post(
    const __half* __restrict__ ht4, const int* __restrict__ rp4,
    const int2* __restrict__ pvedge, float* __restrict__ out4,
    float* __restrict__ aux4, int N) {
  int wave = threadIdx.x >> 6, lane = threadIdx.x & 63;
  int half = lane >> 5, sub = lane & 31;
  int row = blockIdx.x * 4 + wave;
  if (row >= N) return;
  int b = blockIdx.y;
  size_t R = (size_t)b * N + row;
  const char* htb = (const char*)(ht4 + (size_t)b * N * 64);
  int beg = __builtin_amdgcn_readfirstlane(rp4[R]);
  int end = __builtin_amdgcn_readfirstlane(rp4[R + 1]);
  float2 acc = gather_row16(htb, pvedge, beg, end, half, sub);
  float an = fmaxf(sqrtf(wsum32h(acc.x * acc.x + acc.y * acc.y)), 1e-30f);
  float s1 = an > kArtMaxF ? kArtMaxF / an : 1.0f;
  float tx = fmaxf(acc.x * s1, 0.0f), ty = fmaxf(acc.y * s1, 0.0f);
  float tn = fmaxf(sqrtf(wsum32h(tx * tx + ty * ty)), 1e-30f);
  float h2n = tanh_pos(tn);
  float sc = fminf(h2n, kMaxNormF) / tn;   // expmap0 + proj
  if (half == 0) {
    *reinterpret_cast<float2*>(&out4[R * 64 + sub * 2]) =
        make_float2(tx * sc, ty * sc);
    if (sub == 0) aux4[R] = fminf(tn, kArtMaxF);  // artanh(|h2|) exactly
  }
}

// ---- layer-2: SpMM + postagg + COMBINE fused; block=row, wave=branch -------
__global__ __launch_bounds__(256) void k_spmm_comb(
    const __half* __restrict__ ht4, const int* __restrict__ rp4,
    const int2* __restrict__ pvedge, float* __restrict__ out, int N) {
  __shared__ float lf[4][64];
  __shared__ float latn[4], lnb[4];
  int b = threadIdx.x >> 6, lane = threadIdx.x & 63;
  int half = lane >> 5, sub = lane & 31;
  int row = blockIdx.x;
  size_t R = (size_t)b * N + row;
  const char* htb = (const char*)(ht4 + (size_t)b * N * 64);
  int beg = __builtin_amdgcn_readfirstlane(rp4[R]);
  int end = __builtin_amdgcn_readfirstlane(rp4[R + 1]);
  float2 acc = gather_row16(htb, pvedge, beg, end, half, sub);
  float an = fmaxf(sqrtf(wsum32h(acc.x * acc.x + acc.y * acc.y)), 1e-30f);
  float s1 = an > kArtMaxF ? kArtMaxF / an : 1.0f;
  float tx = fmaxf(acc.x * s1, 0.0f), ty = fmaxf(acc.y * s1, 0.0f);
  float tn = fmaxf(sqrtf(wsum32h(tx * tx + ty * ty)), 1e-30f);
  float h2n = tanh_pos(tn);
  float nb = fminf(h2n, kMaxNormF);
  float sc = nb / tn;
  if (half == 0)
    *reinterpret_cast<float2*>(&lf[b][sub * 2]) =
        make_float2(tx * sc, ty * sc);
  if (lane == 0) {
    latn[b] = fminf(tn, kArtMaxF);
    lnb[b] = fmaxf(nb, 1e-30f);
  }
  __syncthreads();
  if (b != 0) return;
  // combine (single wave): mulscaler(1/8) -> mobius chain -> mean logmap0
  float f[4], art[4], nbv[4], w[4], wn2[4], omw[4];
#pragma unroll
  for (int i = 0; i < 4; i++) {
    f[i] = lf[i][lane];
    art[i] = latn[i];
    nbv[i] = lnb[i];
    float wn = tanh_pos(art[i] * 0.125f);
    w[i] = (wn / nbv[i]) * f[i];
    wn2[i] = wn * wn;
    omw[i] = 1.0f - wn2[i];
  }
  float tgt = w[0], tx2 = wn2[0], omt = omw[0];
#pragma unroll
  for (int i = 1; i < 4; i++) {
    float xy = wsum32f(tgt * w[i]);
    float A = 1.f + 2.f * xy + wn2[i];
    float den = fmaxf(1.f + 2.f * xy + tx2 * wn2[i], 1e-15f);
    float rden = 1.0f / den;
    tgt = (A * tgt + omt * w[i]) * rden;
    omt = omt * omw[i] * rden;               // 1-|tgt|^2, stable
    tx2 = 1.0f - omt;
  }
  float tnc = fmaxf(sqrtf(fmaxf(tx2, 0.0f)), 1e-30f);
  float artt = 0.5f * __logf((1.f + tnc) * (1.f + tnc) / fmaxf(omt, 1e-30f));
  float m = (artt / tnc) * tgt;
#pragma unroll
  for (int i = 0; i < 4; i++) m += (art[i] / nbv[i]) * f[i];
  m *= 0.2f;
  float mn = fmaxf(sqrtf(wsum32f(m * m)), 1e-30f);
  float on = tanh_pos(mn);
  float pf = on > kMaxNormF ? kMaxNormF / on : 1.f;
  out[(size_t)row * 64 + lane] = m * (on / mn) * pf;
}

// ---------------------------------------------------------------------------
extern "C" void kernel_launch(void* const* d_in, const int* in_sizes, int n_in,
                              void* d_out, int out_size, void* d_ws,
                              size_t ws_size, hipStream_t stream) {
  const int FIN = 256, NB = 4;
  const int N = in_sizes[0] / FIN;       // 50000
  const int E = in_sizes[5] / NB;        // 800000
  const float* x = (const float*)d_in[0];
  const float* W1 = (const float*)d_in[1];
  const float* b1 = (const float*)d_in[2];
  const float* W2 = (const float*)d_in[3];
  const float* b2 = (const float*)d_in[4];
  const float* vals = (const float*)d_in[5];
  const int* src = (const int*)d_in[6];
  const int* dst = (const int*)d_in[7];
  float* out = (float*)d_out;
  const int n4 = NB * N;
  const int nbuck = (N + 127) >> 7;      // 391
  const int TB = NB * nbuck;

  char* w = (char*)d_ws;
  auto alloc = [&](size_t bytes) -> char* {
    char* p = w;
    w += (bytes + 255) & ~size_t(255);
    return p;
  };
  const int WF1 = NB * (FIN / 32) * 4 * 64 * 8;   // 65536 ushorts
  const int WF2 = NB * (64 / 32) * 4 * 64 * 8;    // 16384 ushorts
  unsigned short* Wf1h = (unsigned short*)alloc((size_t)WF1 * 2);
  unsigned short* Wf1l = (unsigned short*)alloc((size_t)WF1 * 2);
  unsigned short* Wf2h = (unsigned short*)alloc((size_t)WF2 * 2);
  unsigned short* Wf2l = (unsigned short*)alloc((size_t)WF2 * 2);
  float* hb1 = (float*)alloc(NB * 64 * 4);
  float* hb2 = (float*)alloc(NB * 64 * 4);
  float* y21 = (float*)alloc(NB * 4);
  float* y22 = (float*)alloc(NB * 4);
  float* omy1 = (float*)alloc(NB * 4);
  float* omy2 = (float*)alloc(NB * 4);
  float* auxT4 = (float*)alloc((size_t)n4 * 4);
  __half* Cb4 = (__half*)alloc((size_t)n4 * 64 * 2);   // f16 ht table
  float* A4 = (float*)alloc((size_t)n4 * 64 * 4);      // spmm out (f32)
  int* bcnt = (int*)alloc((size_t)TB * 4);
  int* boff = (int*)alloc(((size_t)TB + 1) * 4);
  int* bcur = (int*)alloc((size_t)TB * 4);
  int* rp4 = (int*)alloc(((size_t)n4 + 1) * 4);
  int2* pvedge = (int2*)alloc((size_t)NB * E * 8);
  // ebuf aliases Cb4 (dead until k_gemm1; both exactly 25.6MB)
  int2* ebuf = (int2*)Cb4;

  const int rowBlocks = (N + 3) / 4;
  const int g1Blocks = (N + 15) / 16;      // 3125: 16 rows/block, wave=branch
  const int g2Blocks = (N + 63) / 64;
  const int hBlocks = (E + 8191) / 8192;   // 98

  k_wprep<<<(WF1 / 8 + 255) / 256, 256, 0, stream>>>(W1, Wf1h, Wf1l, FIN, WF1 / 8);
  k_wprep<<<(WF2 / 8 + 255) / 256, 256, 0, stream>>>(W2, Wf2h, Wf2l, 64, WF2 / 8);
  k_bias<<<1, 512, 0, stream>>>(b1, b2, hb1, hb2, y21, y22, omy1, omy2);

  // ---- CSR build: bucketed counting sort over all 4 branches ----
  hipMemsetAsync(bcnt, 0, (size_t)TB * 4, stream);
  k_bhist<<<dim3(hBlocks, NB), 512, 0, stream>>>(dst, bcnt, E, nbuck);
  k_bscan<<<1, 256, 0, stream>>>(bcnt, boff, bcur, rp4, TB, n4, NB * E);
  k_bpart<<<dim3(hBlocks, NB), 512, 0, stream>>>(src, dst, vals, bcur, ebuf, E, nbuck);
  k_bfine<<<dim3(nbuck, NB), 256, 0, stream>>>(ebuf, boff, rp4, pvedge, N, nbuck);

  // ---- layer 1: GEMM(+tail fused) then SpMM(+postagg) ----
  k_gemm1<<<g1Blocks, 256, 0, stream>>>(x, Wf1h, Wf1l, Cb4, hb1, y21, omy1, N);
  k_spmm_post<<<dim3(rowBlocks, NB), 256, 0, stream>>>(Cb4, rp4, pvedge, A4,
                                                       auxT4, N);
  // ---- layer 2: GEMM(+tail fused) then SpMM+combine fused ----
  k_gemm2<<<dim3(g2Blocks, NB), 256, 0, stream>>>(A4, Wf2h, Wf2l, Cb4, auxT4,
                                                  hb2, y22, omy2, N);
  k_spmm_comb<<<N, 256, 0, stream>>>(Cb4, rp4, pvedge, out, N);
}